// Round 1
// baseline (8627.547 us; speedup 1.0000x reference)
//
#include <hip/hip_runtime.h>
#include <hip/hip_bf16.h>
#include <math.h>

#define B_    2
#define S_    8192
#define D_    1024
#define H_N   8
#define DK_   64
#define DV_   64
#define DH_   4096
#define SEG_  2048
#define NSEG_ 4
#define EPS_  1e-5f

typedef __hip_bfloat16 bf16;

__device__ inline float to_f(float v) { return v; }
__device__ inline float to_f(bf16 v)  { return __bfloat162float(v); }

template <typename T> __device__ inline T from_f(float v);
template <> __device__ inline float from_f<float>(float v) { return v; }
template <> __device__ inline bf16  from_f<bf16>(float v)  { return __float2bfloat16(v); }

// ---------------------------------------------------------------------------
// Generic tiled GEMM: C[M,N] = A[M,K] @ W[K,N]  (+bias)(+gelu or +residual)
// EPI: 0 = none, 2 = bias + exact gelu, 3 = bias + residual add
// ---------------------------------------------------------------------------
template <typename AT, typename CT, int EPI>
__global__ __launch_bounds__(256) void gemm_k(
    const AT* __restrict__ A, const float* __restrict__ W, CT* __restrict__ C,
    const float* __restrict__ bias, const float* __restrict__ resid,
    int M, int N, int K)
{
    __shared__ float As[16][64 + 1];
    __shared__ float Ws[16][64 + 1];
    const int t  = threadIdx.x;
    const int tx = t & 15, ty = t >> 4;
    const int m0 = blockIdx.y * 64, n0 = blockIdx.x * 64;

    float acc[4][4] = {};
    const AT*    Ap = A + (size_t)m0 * K;
    const float* Wp = W + n0;

    for (int k0 = 0; k0 < K; k0 += 16) {
        {   // A tile 64x16 -> As[k][m]
            int r = t >> 2;
            int c = (t & 3) * 4;
            const AT* src = Ap + (size_t)r * K + k0 + c;
            #pragma unroll
            for (int i = 0; i < 4; i++) As[c + i][r] = to_f(src[i]);
        }
        {   // W tile 16x64 -> Ws[k][n]
            int r = t >> 4;
            int c = (t & 15) * 4;
            const float* src = Wp + (size_t)(k0 + r) * N + c;
            #pragma unroll
            for (int i = 0; i < 4; i++) Ws[r][c + i] = src[i];
        }
        __syncthreads();
        #pragma unroll
        for (int kk = 0; kk < 16; kk++) {
            float a4[4], w4[4];
            #pragma unroll
            for (int i = 0; i < 4; i++) a4[i] = As[kk][ty * 4 + i];
            #pragma unroll
            for (int j = 0; j < 4; j++) w4[j] = Ws[kk][tx * 4 + j];
            #pragma unroll
            for (int i = 0; i < 4; i++)
                #pragma unroll
                for (int j = 0; j < 4; j++)
                    acc[i][j] += a4[i] * w4[j];
        }
        __syncthreads();
    }

    #pragma unroll
    for (int i = 0; i < 4; i++) {
        int cm = m0 + ty * 4 + i;
        #pragma unroll
        for (int j = 0; j < 4; j++) {
            int cn = n0 + tx * 4 + j;
            float v = acc[i][j];
            if (EPI >= 2) v += bias[cn];
            if (EPI == 2) v = 0.5f * v * (1.0f + erff(v * 0.70710678118654752f));
            if (EPI == 3) v += resid[(size_t)cm * N + cn];
            C[(size_t)cm * N + cn] = from_f<CT>(v);
        }
    }
}

__device__ inline float elu1(float x) { return x > 0.f ? x + 1.f : __expf(x); }

// ---------------------------------------------------------------------------
// Per-segment attention: flash causal SDP + compressive-memory retrieval
// grid: (SEG/64, B*H); block 256.  q/k/v/att layout: (B, S, H*64) row-major.
// ---------------------------------------------------------------------------
__global__ __launch_bounds__(256) void attn_k(
    const float* __restrict__ Q, const float* __restrict__ Kg, const float* __restrict__ Vg,
    const float* __restrict__ mem, const float* __restrict__ z,
    const float* __restrict__ betas, float* __restrict__ att, int seg)
{
    __shared__ float Qs[64][65];
    __shared__ float Ks[64][65];
    __shared__ float Vs[64][65];
    __shared__ float Ps[64][65];
    __shared__ float Zs[64];

    const int t  = threadIdx.x;
    const int tx = t & 15, ty = t >> 4;
    const int bh = blockIdx.y;
    const int b  = bh >> 3, h = bh & 7;
    const int qt = blockIdx.x;
    const int LD = H_N * DK_;  // 512
    const size_t base = ((size_t)b * S_ + (size_t)seg * SEG_) * LD + h * DK_;
    const float* qp = Q + base + (size_t)qt * 64 * LD;
    const float* kp = Kg + base;
    const float* vp = Vg + base;

    #pragma unroll
    for (int i = 0; i < 16; i++) {
        int e = t + i * 256;
        int r = e >> 6, c = e & 63;
        Qs[r][c] = qp[(size_t)r * LD + c];
    }

    float m_r[4], l_r[4], o[4][4];
    #pragma unroll
    for (int i = 0; i < 4; i++) {
        m_r[i] = -1e30f; l_r[i] = 0.f;
        #pragma unroll
        for (int j = 0; j < 4; j++) o[i][j] = 0.f;
    }
    __syncthreads();

    const float scale = 0.125f;  // 1/sqrt(64)
    for (int jt = 0; jt <= qt; jt++) {
        #pragma unroll
        for (int i = 0; i < 16; i++) {
            int e = t + i * 256;
            int r = e >> 6, c = e & 63;
            size_t go = ((size_t)jt * 64 + r) * LD + c;
            Ks[r][c] = kp[go];
            Vs[r][c] = vp[go];
        }
        __syncthreads();

        float s[4][4] = {};
        for (int d = 0; d < 64; d++) {
            float a4[4], b4[4];
            #pragma unroll
            for (int i = 0; i < 4; i++) a4[i] = Qs[ty * 4 + i][d];
            #pragma unroll
            for (int j = 0; j < 4; j++) b4[j] = Ks[tx * 4 + j][d];
            #pragma unroll
            for (int i = 0; i < 4; i++)
                #pragma unroll
                for (int j = 0; j < 4; j++)
                    s[i][j] += a4[i] * b4[j];
        }
        #pragma unroll
        for (int i = 0; i < 4; i++) {
            int qi = qt * 64 + ty * 4 + i;
            #pragma unroll
            for (int j = 0; j < 4; j++) {
                int ki = jt * 64 + tx * 4 + j;
                s[i][j] = (ki <= qi) ? s[i][j] * scale : -1e30f;
            }
        }
        #pragma unroll
        for (int i = 0; i < 4; i++) {
            float mx = fmaxf(fmaxf(s[i][0], s[i][1]), fmaxf(s[i][2], s[i][3]));
            #pragma unroll
            for (int mk = 1; mk < 16; mk <<= 1) mx = fmaxf(mx, __shfl_xor(mx, mk));
            float mnew = fmaxf(m_r[i], mx);
            float corr = __expf(m_r[i] - mnew);
            float rs = 0.f;
            #pragma unroll
            for (int j = 0; j < 4; j++) {
                float p = __expf(s[i][j] - mnew);
                s[i][j] = p; rs += p;
            }
            #pragma unroll
            for (int mk = 1; mk < 16; mk <<= 1) rs += __shfl_xor(rs, mk);
            l_r[i] = l_r[i] * corr + rs;
            m_r[i] = mnew;
            #pragma unroll
            for (int j = 0; j < 4; j++) o[i][j] *= corr;
            #pragma unroll
            for (int j = 0; j < 4; j++) Ps[ty * 4 + i][tx * 4 + j] = s[i][j];
        }
        __syncthreads();
        for (int kk = 0; kk < 64; kk++) {
            float p4[4], v4[4];
            #pragma unroll
            for (int i = 0; i < 4; i++) p4[i] = Ps[ty * 4 + i][kk];
            #pragma unroll
            for (int j = 0; j < 4; j++) v4[j] = Vs[kk][tx * 4 + j];
            #pragma unroll
            for (int i = 0; i < 4; i++)
                #pragma unroll
                for (int j = 0; j < 4; j++)
                    o[i][j] += p4[i] * v4[j];
        }
        __syncthreads();
    }

    // compressive-memory retrieval: (sq @ mem) / (sq @ z); reuse Ks as mem, Ps as sq
    #pragma unroll
    for (int i = 0; i < 16; i++) {
        int e = t + i * 256;
        int r = e >> 6, c = e & 63;
        Ks[r][c] = mem[(size_t)bh * DK_ * DV_ + r * DV_ + c];
        Ps[r][c] = elu1(Qs[r][c]);
    }
    if (t < 64) Zs[t] = z[bh * DK_ + t];
    __syncthreads();

    float num[4][4] = {};
    for (int d = 0; d < 64; d++) {
        float a4[4], w4[4];
        #pragma unroll
        for (int i = 0; i < 4; i++) a4[i] = Ps[ty * 4 + i][d];
        #pragma unroll
        for (int j = 0; j < 4; j++) w4[j] = Ks[d][tx * 4 + j];
        #pragma unroll
        for (int i = 0; i < 4; i++)
            #pragma unroll
            for (int j = 0; j < 4; j++)
                num[i][j] += a4[i] * w4[j];
    }
    float den[4];
    #pragma unroll
    for (int i = 0; i < 4; i++) {
        float dn = 0.f;
        #pragma unroll
        for (int ii = 0; ii < 4; ii++) {
            int d = tx + ii * 16;
            dn += Ps[ty * 4 + i][d] * Zs[d];
        }
        #pragma unroll
        for (int mk = 1; mk < 16; mk <<= 1) dn += __shfl_xor(dn, mk);
        den[i] = dn;
    }

    const size_t ob = base + (size_t)qt * 64 * LD;
    #pragma unroll
    for (int i = 0; i < 4; i++) {
        int r = ty * 4 + i;
        float inv_l = 1.f / l_r[i];
        #pragma unroll
        for (int j = 0; j < 4; j++) {
            int c = tx * 4 + j;
            float g  = 1.f / (1.f + __expf(-betas[h * DV_ + c]));
            float am = num[i][j] / den[i];
            float ad = o[i][j] * inv_l;
            att[ob + (size_t)r * LD + c] = g * am + (1.f - g) * ad;
        }
    }
}

// ---------------------------------------------------------------------------
// Per-segment memory update: mem += sk^T @ v ; z += sum_s sk.  grid: B*H.
// ---------------------------------------------------------------------------
__global__ __launch_bounds__(256) void memupd_k(
    const float* __restrict__ Kg, const float* __restrict__ Vg,
    float* __restrict__ mem, float* __restrict__ z, int seg)
{
    __shared__ float Ks[64][65];  // sk tile [s][d]
    __shared__ float Vs[64][65];  // v  tile [s][c]
    const int t  = threadIdx.x;
    const int tx = t & 15, ty = t >> 4;
    const int bh = blockIdx.x;
    const int b  = bh >> 3, h = bh & 7;
    const int LD = H_N * DK_;
    const size_t base = ((size_t)b * S_ + (size_t)seg * SEG_) * LD + h * DK_;

    float acc[4][4] = {};
    float zacc[4]   = {};
    for (int st = 0; st < SEG_ / 64; st++) {
        #pragma unroll
        for (int i = 0; i < 16; i++) {
            int e = t + i * 256;
            int r = e >> 6, c = e & 63;
            size_t go = base + ((size_t)st * 64 + r) * LD + c;
            Ks[r][c] = elu1(Kg[go]);
            Vs[r][c] = Vg[go];
        }
        __syncthreads();
        for (int s = 0; s < 64; s++) {
            float a4[4], v4[4];
            #pragma unroll
            for (int i = 0; i < 4; i++) a4[i] = Ks[s][ty * 4 + i];
            #pragma unroll
            for (int j = 0; j < 4; j++) v4[j] = Vs[s][tx * 4 + j];
            #pragma unroll
            for (int i = 0; i < 4; i++)
                #pragma unroll
                for (int j = 0; j < 4; j++)
                    acc[i][j] += a4[i] * v4[j];
        }
        #pragma unroll
        for (int ii = 0; ii < 4; ii++) {
            int s = tx + ii * 16;
            #pragma unroll
            for (int i = 0; i < 4; i++) zacc[i] += Ks[s][ty * 4 + i];
        }
        __syncthreads();
    }
    #pragma unroll
    for (int i = 0; i < 4; i++)
        #pragma unroll
        for (int j = 0; j < 4; j++)
            mem[(size_t)bh * (DK_ * DV_) + (ty * 4 + i) * DV_ + tx * 4 + j] += acc[i][j];
    #pragma unroll
    for (int i = 0; i < 4; i++) {
        float zz = zacc[i];
        #pragma unroll
        for (int mk = 1; mk < 16; mk <<= 1) zz += __shfl_xor(zz, mk);
        if (tx == 0) z[bh * DK_ + ty * 4 + i] += zz;
    }
}

__global__ void initmem_k(float* mem, float* z)
{
    int i = blockIdx.x * 256 + threadIdx.x;
    if (i < B_ * H_N * DK_ * DV_) mem[i] = 0.f;
    if (i < B_ * H_N * DK_)       z[i]   = 1.0f / DK_;
}

// ---------------------------------------------------------------------------
// LayerNorm: one block per row of D_=1024
// ---------------------------------------------------------------------------
__global__ __launch_bounds__(256) void ln_k(
    const float* __restrict__ Y, const float* __restrict__ g,
    const float* __restrict__ bta, float* __restrict__ out)
{
    const int row = blockIdx.x;
    const float* yp = Y + (size_t)row * D_;
    const int t = threadIdx.x;
    float v[4];
    float s = 0.f, s2 = 0.f;
    #pragma unroll
    for (int i = 0; i < 4; i++) {
        v[i] = yp[t + i * 256];
        s += v[i]; s2 += v[i] * v[i];
    }
    #pragma unroll
    for (int mk = 1; mk < 64; mk <<= 1) {
        s  += __shfl_xor(s, mk);
        s2 += __shfl_xor(s2, mk);
    }
    __shared__ float ss[4], ss2[4];
    int w = t >> 6;
    if ((t & 63) == 0) { ss[w] = s; ss2[w] = s2; }
    __syncthreads();
    s  = ss[0] + ss[1] + ss[2] + ss[3];
    s2 = ss2[0] + ss2[1] + ss2[2] + ss2[3];
    float mu   = s / D_;
    float var  = s2 / D_ - mu * mu;
    float rstd = rsqrtf(var + EPS_);
    #pragma unroll
    for (int i = 0; i < 4; i++) {
        int c = t + i * 256;
        out[(size_t)row * D_ + c] = (v[i] - mu) * rstd * g[c] + bta[c];
    }
}

// ---------------------------------------------------------------------------
extern "C" void kernel_launch(void* const* d_in, const int* in_sizes, int n_in,
                              void* d_out, int out_size, void* d_ws, size_t ws_size,
                              hipStream_t stream)
{
    const float* x     = (const float*)d_in[0];
    const float* Wq    = (const float*)d_in[1];
    const float* Wk    = (const float*)d_in[2];
    const float* Wv    = (const float*)d_in[3];
    const float* Wo    = (const float*)d_in[4];
    const float* betas = (const float*)d_in[5];
    const float* W1    = (const float*)d_in[6];
    const float* b1    = (const float*)d_in[7];
    const float* W2    = (const float*)d_in[8];
    const float* b2    = (const float*)d_in[9];
    const float* lng   = (const float*)d_in[10];
    const float* lnb   = (const float*)d_in[11];
    float* out = (float*)d_out;

    const size_t NE = (size_t)B_ * S_ * H_N * DK_;  // 8388608 (q/k/v/att elems)
    float* ws  = (float*)d_ws;
    float* Qb  = ws;
    float* Kb  = ws + NE;
    float* Vb  = ws + 2 * NE;
    float* ATT = ws + 3 * NE;
    float* Ab  = ws + 4 * NE;            // region2 (B*S*D f32)
    bf16*  Hb  = (bf16*)ws;              // region1 reuse: B*S*DH bf16 == 4*NE f32 bytes
    float* Yb  = Ab;                     // region2 reuse after Ab dead
    float* MEM = ws + 4 * NE + (size_t)B_ * S_ * D_;
    float* Zb  = MEM + B_ * H_N * DK_ * DV_;

    const int M = B_ * S_;  // 16384
    dim3 blk(256);

    gemm_k<float, float, 0><<<dim3(512 / 64, M / 64), blk, 0, stream>>>(
        x, Wq, Qb, nullptr, nullptr, M, 512, 1024);
    gemm_k<float, float, 0><<<dim3(512 / 64, M / 64), blk, 0, stream>>>(
        x, Wk, Kb, nullptr, nullptr, M, 512, 1024);
    gemm_k<float, float, 0><<<dim3(512 / 64, M / 64), blk, 0, stream>>>(
        x, Wv, Vb, nullptr, nullptr, M, 512, 1024);

    initmem_k<<<dim3((B_ * H_N * DK_ * DV_ + 255) / 256), blk, 0, stream>>>(MEM, Zb);

    for (int seg = 0; seg < NSEG_; seg++) {
        attn_k<<<dim3(SEG_ / 64, B_ * H_N), blk, 0, stream>>>(
            Qb, Kb, Vb, MEM, Zb, betas, ATT, seg);
        memupd_k<<<dim3(B_ * H_N), blk, 0, stream>>>(Kb, Vb, MEM, Zb, seg);
    }

    gemm_k<float, float, 0><<<dim3(1024 / 64, M / 64), blk, 0, stream>>>(
        ATT, Wo, Ab, nullptr, nullptr, M, 1024, 512);
    gemm_k<float, bf16, 2><<<dim3(4096 / 64, M / 64), blk, 0, stream>>>(
        Ab, W1, Hb, b1, nullptr, M, 4096, 1024);
    gemm_k<bf16, float, 3><<<dim3(1024 / 64, M / 64), blk, 0, stream>>>(
        Hb, W2, Yb, b2, x, M, 1024, 4096);
    ln_k<<<dim3(M), blk, 0, stream>>>(Yb, lng, lnb, out);
}

// Round 2
// 2084.104 us; speedup vs baseline: 4.1397x; 4.1397x over previous
//
#include <hip/hip_runtime.h>
#include <hip/hip_bf16.h>
#include <math.h>

#define B_    2
#define S_    8192
#define D_    1024
#define H_N   8
#define DK_   64
#define DV_   64
#define DH_   4096
#define SEG_  2048
#define NSEG_ 4
#define EPS_  1e-5f

typedef __hip_bfloat16 bf16;
typedef unsigned int u32;
typedef __attribute__((ext_vector_type(8))) short bf16x8;
typedef __attribute__((ext_vector_type(4))) float f32x4;

template <typename T> __device__ inline T from_f(float v);
template <> __device__ inline float from_f<float>(float v) { return v; }
template <> __device__ inline bf16  from_f<bf16>(float v)  { return __float2bfloat16(v); }

__device__ __forceinline__ void gld_lds16(const bf16* g, bf16* l) {
    __builtin_amdgcn_global_load_lds(
        (const __attribute__((address_space(1))) u32*)g,
        (__attribute__((address_space(3))) u32*)l, 16, 0, 0);
}

__device__ inline float elu1(float x) { return x > 0.f ? x + 1.f : __expf(x); }

// ---------------------------------------------------------------------------
// MFMA GEMM (m97 structure): C[M,N] = A[M,K] @ BT[N,K]^T
// 128x128 tile, BK=32, 4 waves, 16x16x32 bf16 MFMA, global_load_lds staging.
// EPI: 0 none, 2 bias+exact-gelu, 3 bias+residual
// ---------------------------------------------------------------------------
template <int EPI, typename CT>
__global__ __launch_bounds__(256) void mfma_gemm(
    const bf16* __restrict__ A, const bf16* __restrict__ BT, CT* __restrict__ C,
    const float* __restrict__ bias, const float* __restrict__ resid,
    int M, int N, int K)
{
    __shared__ bf16 As[128 * 32];
    __shared__ bf16 Bs[128 * 32];
    const int t    = threadIdx.x;
    const int lane = t & 63;
    const int wave = t >> 6;

    // bijective XCD swizzle (all grids have nwg % 8 == 0)
    const int nx  = gridDim.x;
    const int nwg = nx * gridDim.y;
    const int lin = blockIdx.y * nx + blockIdx.x;
    const int swz = (lin & 7) * (nwg >> 3) + (lin >> 3);
    const int by  = swz / nx, bx = swz - by * nx;

    const int m0 = by * 128, n0 = bx * 128;
    const int wr = (wave >> 1) * 64, wc = (wave & 1) * 64;

    f32x4 acc[4][4];
    #pragma unroll
    for (int i = 0; i < 4; i++)
        #pragma unroll
        for (int j = 0; j < 4; j++) {
            f32x4 z4 = {0.f, 0.f, 0.f, 0.f};
            acc[i][j] = z4;
        }

    // staging geometry: 512 chunks of 16B per 8KB tile; chunk e -> row e>>2, col8 (e&3)*8
    const int rA  = t >> 2,        cA  = (t & 3) * 8;
    const int rA2 = (t + 256) >> 2, cA2 = ((t + 256) & 3) * 8;
    bf16* ldsA0 = As + (size_t)(wave * 64) * 8;
    bf16* ldsA1 = As + (size_t)(256 + wave * 64) * 8;
    bf16* ldsB0 = Bs + (size_t)(wave * 64) * 8;
    bf16* ldsB1 = Bs + (size_t)(256 + wave * 64) * 8;

    const bf16* Ap = A  + (size_t)m0 * K;
    const bf16* Bp = BT + (size_t)n0 * K;

    const int la = lane & 15, ksel = (lane >> 4) * 8;

    for (int k0 = 0; k0 < K; k0 += 32) {
        gld_lds16(Ap + (size_t)rA  * K + k0 + cA,  ldsA0);
        gld_lds16(Ap + (size_t)rA2 * K + k0 + cA2, ldsA1);
        gld_lds16(Bp + (size_t)rA  * K + k0 + cA,  ldsB0);
        gld_lds16(Bp + (size_t)rA2 * K + k0 + cA2, ldsB1);
        __syncthreads();   // drains vmcnt -> LDS tiles complete
        bf16x8 af[4], bg[4];
        #pragma unroll
        for (int i = 0; i < 4; i++)
            af[i] = *(const bf16x8*)&As[(size_t)(wr + i * 16 + la) * 32 + ksel];
        #pragma unroll
        for (int j = 0; j < 4; j++)
            bg[j] = *(const bf16x8*)&Bs[(size_t)(wc + j * 16 + la) * 32 + ksel];
        #pragma unroll
        for (int i = 0; i < 4; i++)
            #pragma unroll
            for (int j = 0; j < 4; j++)
                acc[i][j] = __builtin_amdgcn_mfma_f32_16x16x32_bf16(
                    af[i], bg[j], acc[i][j], 0, 0, 0);
        __syncthreads();   // all reads done before next stage overwrites
    }

    // C/D layout: col = lane&15, row = (lane>>4)*4 + reg  [verified m89/m91]
    const int row0 = m0 + wr + (lane >> 4) * 4;
    const int col0 = n0 + wc + la;
    #pragma unroll
    for (int i = 0; i < 4; i++) {
        #pragma unroll
        for (int j = 0; j < 4; j++) {
            const int col = col0 + j * 16;
            float bj = (EPI >= 2) ? bias[col] : 0.f;
            #pragma unroll
            for (int r = 0; r < 4; r++) {
                const int row = row0 + i * 16 + r;
                float v = acc[i][j][r];
                if (EPI >= 2) v += bj;
                if (EPI == 2) v = 0.5f * v * (1.0f + erff(v * 0.70710678118654752f));
                if (EPI == 3) v += resid[(size_t)row * N + col];
                C[(size_t)row * N + col] = from_f<CT>(v);
            }
        }
    }
}

// ---------------------------------------------------------------------------
// casts
// ---------------------------------------------------------------------------
__global__ __launch_bounds__(256) void castx_k(const float* __restrict__ X,
                                               bf16* __restrict__ Y)
{
    size_t i = ((size_t)blockIdx.x * 256 + threadIdx.x) * 4;
    float4 v = *(const float4*)(X + i);
    union { bf16 b[4]; unsigned long long u; } o;
    o.b[0] = __float2bfloat16(v.x);
    o.b[1] = __float2bfloat16(v.y);
    o.b[2] = __float2bfloat16(v.z);
    o.b[3] = __float2bfloat16(v.w);
    *(unsigned long long*)(Y + i) = o.u;
}

// W [K][N] f32 -> WT [N][K] bf16 (32x32 LDS tile)
__global__ __launch_bounds__(256) void transcast_k(const float* __restrict__ W,
                                                   bf16* __restrict__ WT, int K, int N)
{
    __shared__ float tile[32][33];
    const int n0 = blockIdx.x * 32, k0 = blockIdx.y * 32;
    const int tx = threadIdx.x & 31, ty = threadIdx.x >> 5;  // ty 0..7
    #pragma unroll
    for (int i = 0; i < 32; i += 8)
        tile[ty + i][tx] = W[(size_t)(k0 + ty + i) * N + n0 + tx];
    __syncthreads();
    #pragma unroll
    for (int i = 0; i < 32; i += 8)
        WT[(size_t)(n0 + ty + i) * K + k0 + tx] = __float2bfloat16(tile[tx][ty + i]);
}

// ---------------------------------------------------------------------------
// Per-(segment,chunk) partial memory: MP[slot] = sum_{s in chunk} elu1(k)^T v
// grid (NSEG*B*H, 4 chunks), block 256
// ---------------------------------------------------------------------------
__global__ __launch_bounds__(256) void memseg_k(
    const float* __restrict__ Kg, const float* __restrict__ Vg,
    float* __restrict__ MP, float* __restrict__ ZP)
{
    __shared__ float Ks[64][65];
    __shared__ float Vs[64][65];
    const int t = threadIdx.x, tx = t & 15, ty = t >> 4;
    const int sb = blockIdx.x;
    const int seg = sb >> 4, bh = sb & 15;
    const int b = bh >> 3, h = bh & 7;
    const int chunk = blockIdx.y;
    const int LD = H_N * DK_;
    const size_t base = ((size_t)b * S_ + (size_t)seg * SEG_ + (size_t)chunk * 512) * LD + h * DK_;

    float acc[4][4] = {};
    float zacc[4]   = {};
    for (int st = 0; st < 8; st++) {
        #pragma unroll
        for (int i = 0; i < 16; i++) {
            int e = t + i * 256;
            int r = e >> 6, c = e & 63;
            size_t go = base + ((size_t)st * 64 + r) * LD + c;
            Ks[r][c] = elu1(Kg[go]);
            Vs[r][c] = Vg[go];
        }
        __syncthreads();
        for (int s = 0; s < 64; s++) {
            float a4[4], v4[4];
            #pragma unroll
            for (int i = 0; i < 4; i++) a4[i] = Ks[s][ty * 4 + i];
            #pragma unroll
            for (int j = 0; j < 4; j++) v4[j] = Vs[s][tx * 4 + j];
            #pragma unroll
            for (int i = 0; i < 4; i++)
                #pragma unroll
                for (int j = 0; j < 4; j++)
                    acc[i][j] += a4[i] * v4[j];
        }
        #pragma unroll
        for (int ii = 0; ii < 4; ii++) {
            int s = tx + ii * 16;
            #pragma unroll
            for (int i = 0; i < 4; i++) zacc[i] += Ks[s][ty * 4 + i];
        }
        __syncthreads();
    }
    const int slot = (seg * 4 + chunk) * 16 + bh;
    #pragma unroll
    for (int i = 0; i < 4; i++)
        #pragma unroll
        for (int j = 0; j < 4; j++)
            MP[(size_t)slot * 4096 + (ty * 4 + i) * 64 + tx * 4 + j] = acc[i][j];
    #pragma unroll
    for (int i = 0; i < 4; i++) {
        float zz = zacc[i];
        #pragma unroll
        for (int mk = 1; mk < 16; mk <<= 1) zz += __shfl_xor(zz, mk);
        if (tx == 0) ZP[slot * 64 + ty * 4 + i] = zz;
    }
}

// exclusive prefix over 16 (seg,chunk) slots -> per-seg start states
__global__ __launch_bounds__(256) void prefix_k(
    const float* __restrict__ MP, const float* __restrict__ ZP,
    float* __restrict__ MS, float* __restrict__ ZS)
{
    const int bh = blockIdx.x, t = threadIdx.x;
    for (int e = t; e < 4096; e += 256) {
        float s = 0.f;
        #pragma unroll
        for (int slot = 0; slot < 16; slot++) {
            if ((slot & 3) == 0) MS[(size_t)((slot >> 2) * 16 + bh) * 4096 + e] = s;
            s += MP[(size_t)(slot * 16 + bh) * 4096 + e];
        }
    }
    if (t < 64) {
        float s = 1.0f / DK_;
        #pragma unroll
        for (int slot = 0; slot < 16; slot++) {
            if ((slot & 3) == 0) ZS[((slot >> 2) * 16 + bh) * 64 + t] = s;
            s += ZP[(slot * 16 + bh) * 64 + t];
        }
    }
}

// ---------------------------------------------------------------------------
// Attention (all segments parallel): flash causal + memory retrieval
// grid (SEG/64, B*H, NSEG); block 256.  Output bf16.
// ---------------------------------------------------------------------------
__global__ __launch_bounds__(256) void attn_k(
    const float* __restrict__ Q, const float* __restrict__ Kg, const float* __restrict__ Vg,
    const float* __restrict__ MS, const float* __restrict__ ZS,
    const float* __restrict__ betas, bf16* __restrict__ att)
{
    __shared__ float Qs[64][65];
    __shared__ float Ks[64][65];
    __shared__ float Vs[64][65];
    __shared__ float Ps[64][65];
    __shared__ float Zs[64];

    const int t  = threadIdx.x;
    const int tx = t & 15, ty = t >> 4;
    const int bh = blockIdx.y;
    const int b  = bh >> 3, h = bh & 7;
    const int qt = blockIdx.x;
    const int seg = blockIdx.z;
    const int LD = H_N * DK_;  // 512
    const size_t base = ((size_t)b * S_ + (size_t)seg * SEG_) * LD + h * DK_;
    const float* qp = Q + base + (size_t)qt * 64 * LD;
    const float* kp = Kg + base;
    const float* vp = Vg + base;
    const float* mem = MS + (size_t)(seg * 16 + bh) * 4096;
    const float* zp  = ZS + (seg * 16 + bh) * 64;

    #pragma unroll
    for (int i = 0; i < 16; i++) {
        int e = t + i * 256;
        int r = e >> 6, c = e & 63;
        Qs[r][c] = qp[(size_t)r * LD + c];
    }

    float m_r[4], l_r[4], o[4][4];
    #pragma unroll
    for (int i = 0; i < 4; i++) {
        m_r[i] = -1e30f; l_r[i] = 0.f;
        #pragma unroll
        for (int j = 0; j < 4; j++) o[i][j] = 0.f;
    }
    __syncthreads();

    const float scale = 0.125f;
    for (int jt = 0; jt <= qt; jt++) {
        #pragma unroll
        for (int i = 0; i < 16; i++) {
            int e = t + i * 256;
            int r = e >> 6, c = e & 63;
            size_t go = ((size_t)jt * 64 + r) * LD + c;
            Ks[r][c] = kp[go];
            Vs[r][c] = vp[go];
        }
        __syncthreads();

        float s[4][4] = {};
        for (int d = 0; d < 64; d++) {
            float a4[4], b4[4];
            #pragma unroll
            for (int i = 0; i < 4; i++) a4[i] = Qs[ty * 4 + i][d];
            #pragma unroll
            for (int j = 0; j < 4; j++) b4[j] = Ks[tx * 4 + j][d];
            #pragma unroll
            for (int i = 0; i < 4; i++)
                #pragma unroll
                for (int j = 0; j < 4; j++)
                    s[i][j] += a4[i] * b4[j];
        }
        #pragma unroll
        for (int i = 0; i < 4; i++) {
            int qi = qt * 64 + ty * 4 + i;
            #pragma unroll
            for (int j = 0; j < 4; j++) {
                int ki = jt * 64 + tx * 4 + j;
                s[i][j] = (ki <= qi) ? s[i][j] * scale : -1e30f;
            }
        }
        #pragma unroll
        for (int i = 0; i < 4; i++) {
            float mx = fmaxf(fmaxf(s[i][0], s[i][1]), fmaxf(s[i][2], s[i][3]));
            #pragma unroll
            for (int mk = 1; mk < 16; mk <<= 1) mx = fmaxf(mx, __shfl_xor(mx, mk));
            float mnew = fmaxf(m_r[i], mx);
            float corr = __expf(m_r[i] - mnew);
            float rs = 0.f;
            #pragma unroll
            for (int j = 0; j < 4; j++) {
                float p = __expf(s[i][j] - mnew);
                s[i][j] = p; rs += p;
            }
            #pragma unroll
            for (int mk = 1; mk < 16; mk <<= 1) rs += __shfl_xor(rs, mk);
            l_r[i] = l_r[i] * corr + rs;
            m_r[i] = mnew;
            #pragma unroll
            for (int j = 0; j < 4; j++) o[i][j] *= corr;
            #pragma unroll
            for (int j = 0; j < 4; j++) Ps[ty * 4 + i][tx * 4 + j] = s[i][j];
        }
        __syncthreads();
        for (int kk = 0; kk < 64; kk++) {
            float p4[4], v4[4];
            #pragma unroll
            for (int i = 0; i < 4; i++) p4[i] = Ps[ty * 4 + i][kk];
            #pragma unroll
            for (int j = 0; j < 4; j++) v4[j] = Vs[kk][tx * 4 + j];
            #pragma unroll
            for (int i = 0; i < 4; i++)
                #pragma unroll
                for (int j = 0; j < 4; j++)
                    o[i][j] += p4[i] * v4[j];
        }
        __syncthreads();
    }

    // retrieval: (elu1(q) @ mem) / (elu1(q) @ z)
    #pragma unroll
    for (int i = 0; i < 16; i++) {
        int e = t + i * 256;
        int r = e >> 6, c = e & 63;
        Ks[r][c] = mem[r * 64 + c];
        Ps[r][c] = elu1(Qs[r][c]);
    }
    if (t < 64) Zs[t] = zp[t];
    __syncthreads();

    float num[4][4] = {};
    for (int d = 0; d < 64; d++) {
        float a4[4], w4[4];
        #pragma unroll
        for (int i = 0; i < 4; i++) a4[i] = Ps[ty * 4 + i][d];
        #pragma unroll
        for (int j = 0; j < 4; j++) w4[j] = Ks[d][tx * 4 + j];
        #pragma unroll
        for (int i = 0; i < 4; i++)
            #pragma unroll
            for (int j = 0; j < 4; j++)
                num[i][j] += a4[i] * w4[j];
    }
    float den[4];
    #pragma unroll
    for (int i = 0; i < 4; i++) {
        float dn = 0.f;
        #pragma unroll
        for (int ii = 0; ii < 4; ii++) {
            int d = tx + ii * 16;
            dn += Ps[ty * 4 + i][d] * Zs[d];
        }
        #pragma unroll
        for (int mk = 1; mk < 16; mk <<= 1) dn += __shfl_xor(dn, mk);
        den[i] = dn;
    }

    const size_t ob = base + (size_t)qt * 64 * LD;
    #pragma unroll
    for (int i = 0; i < 4; i++) {
        int r = ty * 4 + i;
        float inv_l = 1.f / l_r[i];
        #pragma unroll
        for (int j = 0; j < 4; j++) {
            int c = tx * 4 + j;
            float g  = 1.f / (1.f + __expf(-betas[h * DV_ + c]));
            float am = num[i][j] / den[i];
            float ad = o[i][j] * inv_l;
            att[ob + (size_t)r * LD + c] = __float2bfloat16(g * am + (1.f - g) * ad);
        }
    }
}

// ---------------------------------------------------------------------------
// LayerNorm, in-place safe (each thread reads/writes only its own columns)
// ---------------------------------------------------------------------------
__global__ __launch_bounds__(256) void ln_k(
    const float* __restrict__ Y, const float* __restrict__ g,
    const float* __restrict__ bta, float* __restrict__ out)
{
    const int row = blockIdx.x;
    const float* yp = Y + (size_t)row * D_;
    const int t = threadIdx.x;
    float v[4];
    float s = 0.f, s2 = 0.f;
    #pragma unroll
    for (int i = 0; i < 4; i++) {
        v[i] = yp[t + i * 256];
        s += v[i]; s2 += v[i] * v[i];
    }
    #pragma unroll
    for (int mk = 1; mk < 64; mk <<= 1) {
        s  += __shfl_xor(s, mk);
        s2 += __shfl_xor(s2, mk);
    }
    __shared__ float ss[4], ss2[4];
    int w = t >> 6;
    if ((t & 63) == 0) { ss[w] = s; ss2[w] = s2; }
    __syncthreads();
    s  = ss[0] + ss[1] + ss[2] + ss[3];
    s2 = ss2[0] + ss2[1] + ss2[2] + ss2[3];
    float mu   = s / D_;
    float var  = s2 / D_ - mu * mu;
    float rstd = rsqrtf(var + EPS_);
    #pragma unroll
    for (int i = 0; i < 4; i++) {
        int c = t + i * 256;
        out[(size_t)row * D_ + c] = (v[i] - mu) * rstd * g[c] + bta[c];
    }
}

// ---------------------------------------------------------------------------
extern "C" void kernel_launch(void* const* d_in, const int* in_sizes, int n_in,
                              void* d_out, int out_size, void* d_ws, size_t ws_size,
                              hipStream_t stream)
{
    const float* x     = (const float*)d_in[0];
    const float* Wq    = (const float*)d_in[1];
    const float* Wk    = (const float*)d_in[2];
    const float* Wv    = (const float*)d_in[3];
    const float* Wo    = (const float*)d_in[4];
    const float* betas = (const float*)d_in[5];
    const float* W1    = (const float*)d_in[6];
    const float* b1    = (const float*)d_in[7];
    const float* W2    = (const float*)d_in[8];
    const float* b2    = (const float*)d_in[9];
    const float* lng   = (const float*)d_in[10];
    const float* lnb   = (const float*)d_in[11];
    float* out = (float*)d_out;

    const int M = B_ * S_;                    // 16384
    char* base = (char*)d_ws;
    const size_t MB = 1024 * 1024;

    // region A [0,128MB): Qb/Kb/Vb f32 (96MB) + Xbf (32MB); reused later as Hb
    float* Qb  = (float*)(base);
    float* Kb  = (float*)(base + 32 * MB);
    float* Vb  = (float*)(base + 64 * MB);
    bf16*  Xbf = (bf16*)(base + 96 * MB);
    bf16*  Hb  = (bf16*)(base);              // [16384][4096] bf16 = 128MB
    bf16*  ATT = (bf16*)(base + 128 * MB);   // 16MB
    bf16*  Ab  = (bf16*)(base + 144 * MB);   // 32MB
    bf16*  WqT = (bf16*)(base + 176 * MB);   // [512][1024]  1MB
    bf16*  WkT = (bf16*)(base + 177 * MB);
    bf16*  WvT = (bf16*)(base + 178 * MB);
    bf16*  WoT = (bf16*)(base + 179 * MB);   // [1024][512]  1MB
    bf16*  W1T = (bf16*)(base + 180 * MB);   // [4096][1024] 8MB
    bf16*  W2T = (bf16*)(base + 188 * MB);   // [1024][4096] 8MB
    float* MP  = (float*)(base + 196 * MB);  // 16 slots x 16 bh x 4096 = 4MB
    float* MS  = (float*)(base + 200 * MB);  // 4 x 16 x 4096 = 1MB
    float* ZP  = (float*)(base + 201 * MB + 0);
    float* ZS  = (float*)(base + 201 * MB + 256 * 1024);

    dim3 blk(256);

    // casts
    castx_k<<<dim3((M * D_) / 1024), blk, 0, stream>>>(x, Xbf);
    transcast_k<<<dim3(512 / 32, 1024 / 32), blk, 0, stream>>>(Wq, WqT, 1024, 512);
    transcast_k<<<dim3(512 / 32, 1024 / 32), blk, 0, stream>>>(Wk, WkT, 1024, 512);
    transcast_k<<<dim3(512 / 32, 1024 / 32), blk, 0, stream>>>(Wv, WvT, 1024, 512);
    transcast_k<<<dim3(1024 / 32, 512 / 32), blk, 0, stream>>>(Wo, WoT, 512, 1024);
    transcast_k<<<dim3(4096 / 32, 1024 / 32), blk, 0, stream>>>(W1, W1T, 1024, 4096);
    transcast_k<<<dim3(1024 / 32, 4096 / 32), blk, 0, stream>>>(W2, W2T, 4096, 1024);

    // projections (bf16 MFMA, f32 out for attention)
    mfma_gemm<0, float><<<dim3(512 / 128, M / 128), blk, 0, stream>>>(
        Xbf, WqT, Qb, nullptr, nullptr, M, 512, 1024);
    mfma_gemm<0, float><<<dim3(512 / 128, M / 128), blk, 0, stream>>>(
        Xbf, WkT, Kb, nullptr, nullptr, M, 512, 1024);
    mfma_gemm<0, float><<<dim3(512 / 128, M / 128), blk, 0, stream>>>(
        Xbf, WvT, Vb, nullptr, nullptr, M, 512, 1024);

    // parallel segment memories + exclusive prefix
    memseg_k<<<dim3(NSEG_ * 16, 4), blk, 0, stream>>>(Kb, Vb, MP, ZP);
    prefix_k<<<dim3(16), blk, 0, stream>>>(MP, ZP, MS, ZS);

    // attention, all segments at once
    attn_k<<<dim3(SEG_ / 64, 16, NSEG_), blk, 0, stream>>>(
        Qb, Kb, Vb, MS, ZS, betas, ATT);

    // output projection + FFN (bf16 MFMA)
    mfma_gemm<0, bf16><<<dim3(1024 / 128, M / 128), blk, 0, stream>>>(
        ATT, WoT, Ab, nullptr, nullptr, M, 1024, 512);
    mfma_gemm<2, bf16><<<dim3(4096 / 128, M / 128), blk, 0, stream>>>(
        Ab, W1T, Hb, b1, nullptr, M, 4096, 1024);
    mfma_gemm<3, float><<<dim3(1024 / 128, M / 128), blk, 0, stream>>>(
        Hb, W2T, out, b2, x, M, 1024, 4096);

    ln_k<<<dim3(M), blk, 0, stream>>>(out, lng, lnb, out);
}

// Round 3
// 947.022 us; speedup vs baseline: 9.1102x; 2.2007x over previous
//
#include <hip/hip_runtime.h>
#include <hip/hip_bf16.h>
#include <math.h>

#define B_    2
#define S_    8192
#define D_    1024
#define H_N   8
#define DK_   64
#define DV_   64
#define DH_   4096
#define SEG_  2048
#define NSEG_ 4
#define EPS_  1e-5f

typedef __hip_bfloat16 bf16;
typedef unsigned int u32;
typedef __attribute__((ext_vector_type(8))) short bf16x8;
typedef __attribute__((ext_vector_type(4))) float f32x4;

union bvec { bf16x8 v; bf16 e[8]; };

template <typename T> __device__ inline T from_f(float v);
template <> __device__ inline float from_f<float>(float v) { return v; }
template <> __device__ inline bf16  from_f<bf16>(float v)  { return __float2bfloat16(v); }

__device__ __forceinline__ void gld_lds16(const bf16* g, bf16* l) {
    __builtin_amdgcn_global_load_lds(
        (const __attribute__((address_space(1))) u32*)g,
        (__attribute__((address_space(3))) u32*)l, 16, 0, 0);
}

__device__ inline float elu1(float x) { return x > 0.f ? x + 1.f : __expf(x); }

// ---------------------------------------------------------------------------
// MFMA GEMM (m97 structure): C[M,N] = A[M,K] @ BT[N,K]^T
// ---------------------------------------------------------------------------
template <int EPI, typename CT>
__global__ __launch_bounds__(256) void mfma_gemm(
    const bf16* __restrict__ A, const bf16* __restrict__ BT, CT* __restrict__ C,
    const float* __restrict__ bias, const float* __restrict__ resid,
    int M, int N, int K)
{
    __shared__ bf16 As[128 * 32];
    __shared__ bf16 Bs[128 * 32];
    const int t    = threadIdx.x;
    const int lane = t & 63;
    const int wave = t >> 6;

    const int nx  = gridDim.x;
    const int nwg = nx * gridDim.y;
    const int lin = blockIdx.y * nx + blockIdx.x;
    const int swz = (lin & 7) * (nwg >> 3) + (lin >> 3);
    const int by  = swz / nx, bx = swz - by * nx;

    const int m0 = by * 128, n0 = bx * 128;
    const int wr = (wave >> 1) * 64, wc = (wave & 1) * 64;

    f32x4 acc[4][4];
    #pragma unroll
    for (int i = 0; i < 4; i++)
        #pragma unroll
        for (int j = 0; j < 4; j++) {
            f32x4 z4 = {0.f, 0.f, 0.f, 0.f};
            acc[i][j] = z4;
        }

    const int rA  = t >> 2,         cA  = (t & 3) * 8;
    const int rA2 = (t + 256) >> 2, cA2 = ((t + 256) & 3) * 8;
    bf16* ldsA0 = As + (size_t)(wave * 64) * 8;
    bf16* ldsA1 = As + (size_t)(256 + wave * 64) * 8;
    bf16* ldsB0 = Bs + (size_t)(wave * 64) * 8;
    bf16* ldsB1 = Bs + (size_t)(256 + wave * 64) * 8;

    const bf16* Ap = A  + (size_t)m0 * K;
    const bf16* Bp = BT + (size_t)n0 * K;

    const int la = lane & 15, ksel = (lane >> 4) * 8;

    for (int k0 = 0; k0 < K; k0 += 32) {
        gld_lds16(Ap + (size_t)rA  * K + k0 + cA,  ldsA0);
        gld_lds16(Ap + (size_t)rA2 * K + k0 + cA2, ldsA1);
        gld_lds16(Bp + (size_t)rA  * K + k0 + cA,  ldsB0);
        gld_lds16(Bp + (size_t)rA2 * K + k0 + cA2, ldsB1);
        __syncthreads();
        bf16x8 af[4], bg[4];
        #pragma unroll
        for (int i = 0; i < 4; i++)
            af[i] = *(const bf16x8*)&As[(size_t)(wr + i * 16 + la) * 32 + ksel];
        #pragma unroll
        for (int j = 0; j < 4; j++)
            bg[j] = *(const bf16x8*)&Bs[(size_t)(wc + j * 16 + la) * 32 + ksel];
        #pragma unroll
        for (int i = 0; i < 4; i++)
            #pragma unroll
            for (int j = 0; j < 4; j++)
                acc[i][j] = __builtin_amdgcn_mfma_f32_16x16x32_bf16(
                    af[i], bg[j], acc[i][j], 0, 0, 0);
        __syncthreads();
    }

    const int row0 = m0 + wr + (lane >> 4) * 4;
    const int col0 = n0 + wc + la;
    #pragma unroll
    for (int i = 0; i < 4; i++) {
        #pragma unroll
        for (int j = 0; j < 4; j++) {
            const int col = col0 + j * 16;
            float bj = (EPI >= 2) ? bias[col] : 0.f;
            #pragma unroll
            for (int r = 0; r < 4; r++) {
                const int row = row0 + i * 16 + r;
                float v = acc[i][j][r];
                if (EPI >= 2) v += bj;
                if (EPI == 2) v = 0.5f * v * (1.0f + erff(v * 0.70710678118654752f));
                if (EPI == 3) v += resid[(size_t)row * N + col];
                C[(size_t)row * N + col] = from_f<CT>(v);
            }
        }
    }
}

// ---------------------------------------------------------------------------
// casts
// ---------------------------------------------------------------------------
__global__ __launch_bounds__(256) void castx_k(const float* __restrict__ X,
                                               bf16* __restrict__ Y)
{
    size_t i = ((size_t)blockIdx.x * 256 + threadIdx.x) * 4;
    float4 v = *(const float4*)(X + i);
    union { bf16 b[4]; unsigned long long u; } o;
    o.b[0] = __float2bfloat16(v.x);
    o.b[1] = __float2bfloat16(v.y);
    o.b[2] = __float2bfloat16(v.z);
    o.b[3] = __float2bfloat16(v.w);
    *(unsigned long long*)(Y + i) = o.u;
}

__global__ __launch_bounds__(256) void transcast_k(const float* __restrict__ W,
                                                   bf16* __restrict__ WT, int K, int N)
{
    __shared__ float tile[32][33];
    const int n0 = blockIdx.x * 32, k0 = blockIdx.y * 32;
    const int tx = threadIdx.x & 31, ty = threadIdx.x >> 5;
    #pragma unroll
    for (int i = 0; i < 32; i += 8)
        tile[ty + i][tx] = W[(size_t)(k0 + ty + i) * N + n0 + tx];
    __syncthreads();
    #pragma unroll
    for (int i = 0; i < 32; i += 8)
        WT[(size_t)(n0 + ty + i) * K + k0 + tx] = __float2bfloat16(tile[tx][ty + i]);
}

// V [b][s][h*64+dv] bf16 -> Vt [ (b*8+h)*64+dv ][ s ] bf16
__global__ __launch_bounds__(256) void vtrans_k(const bf16* __restrict__ V,
                                                bf16* __restrict__ Vt)
{
    __shared__ bf16 t_[64 * 64];
    const int t = threadIdx.x;
    const int sblk = blockIdx.x & 127;
    const int b = blockIdx.x >> 7;
    const int h = blockIdx.y;
    const bf16* src = V + ((size_t)b * S_ + sblk * 64) * 512 + h * 64;
    #pragma unroll
    for (int k = 0; k < 2; k++) {
        int e = t + k * 256;
        int r = e >> 3, c8 = (e & 7) * 8;
        *(bf16x8*)&t_[r * 64 + c8] = *(const bf16x8*)&src[(size_t)r * 512 + c8];
    }
    __syncthreads();
    const int dv = t & 63, s0 = (t >> 6) * 16;
    bf16* dst = Vt + ((size_t)(b * 8 + h) * 64 + dv) * (size_t)S_ + sblk * 64 + s0;
    bvec o0, o1;
    #pragma unroll
    for (int i = 0; i < 8; i++) {
        o0.e[i] = t_[(s0 + i) * 64 + dv];
        o1.e[i] = t_[(s0 + 8 + i) * 64 + dv];
    }
    *(bf16x8*)dst = o0.v;
    *(bf16x8*)(dst + 8) = o1.v;
}

// ---------------------------------------------------------------------------
// Per-(segment,chunk) partial memory (bf16 in, f32 accumulate)
// ---------------------------------------------------------------------------
__global__ __launch_bounds__(256) void memseg_k(
    const bf16* __restrict__ Kg, const bf16* __restrict__ Vg,
    float* __restrict__ MP, float* __restrict__ ZP)
{
    __shared__ float Ks[64][65];
    __shared__ float Vs[64][65];
    const int t = threadIdx.x, tx = t & 15, ty = t >> 4;
    const int sb = blockIdx.x;
    const int seg = sb >> 4, bh = sb & 15;
    const int b = bh >> 3, h = bh & 7;
    const int chunk = blockIdx.y;
    const size_t base = ((size_t)b * S_ + (size_t)seg * SEG_ + (size_t)chunk * 512) * 512 + h * 64;

    float acc[4][4] = {};
    float zacc[4]   = {};
    for (int st = 0; st < 8; st++) {
        #pragma unroll
        for (int kk = 0; kk < 2; kk++) {
            int e = t + kk * 256;
            int r = e >> 3, c8 = (e & 7) * 8;
            size_t go = base + ((size_t)st * 64 + r) * 512 + c8;
            bvec kv_, vv_;
            kv_.v = *(const bf16x8*)&Kg[go];
            vv_.v = *(const bf16x8*)&Vg[go];
            #pragma unroll
            for (int i = 0; i < 8; i++) {
                Ks[r][c8 + i] = elu1(__bfloat162float(kv_.e[i]));
                Vs[r][c8 + i] = __bfloat162float(vv_.e[i]);
            }
        }
        __syncthreads();
        for (int s = 0; s < 64; s++) {
            float a4[4], v4[4];
            #pragma unroll
            for (int i = 0; i < 4; i++) a4[i] = Ks[s][ty * 4 + i];
            #pragma unroll
            for (int j = 0; j < 4; j++) v4[j] = Vs[s][tx * 4 + j];
            #pragma unroll
            for (int i = 0; i < 4; i++)
                #pragma unroll
                for (int j = 0; j < 4; j++)
                    acc[i][j] += a4[i] * v4[j];
        }
        #pragma unroll
        for (int ii = 0; ii < 4; ii++) {
            int s = tx + ii * 16;
            #pragma unroll
            for (int i = 0; i < 4; i++) zacc[i] += Ks[s][ty * 4 + i];
        }
        __syncthreads();
    }
    const int slot = (seg * 4 + chunk) * 16 + bh;
    #pragma unroll
    for (int i = 0; i < 4; i++)
        #pragma unroll
        for (int j = 0; j < 4; j++)
            MP[(size_t)slot * 4096 + (ty * 4 + i) * 64 + tx * 4 + j] = acc[i][j];
    #pragma unroll
    for (int i = 0; i < 4; i++) {
        float zz = zacc[i];
        #pragma unroll
        for (int mk = 1; mk < 16; mk <<= 1) zz += __shfl_xor(zz, mk);
        if (tx == 0) ZP[slot * 64 + ty * 4 + i] = zz;
    }
}

// exclusive prefix -> per-seg start states: MST transposed bf16 [dv][dk], ZS f32
__global__ __launch_bounds__(256) void prefix_k(
    const float* __restrict__ MP, const float* __restrict__ ZP,
    bf16* __restrict__ MST, float* __restrict__ ZS)
{
    const int bh = blockIdx.x, t = threadIdx.x;
    for (int e = t; e < 4096; e += 256) {
        int dk = e >> 6, dv = e & 63;
        float s = 0.f;
        #pragma unroll
        for (int slot = 0; slot < 16; slot++) {
            if ((slot & 3) == 0)
                MST[(size_t)((slot >> 2) * 16 + bh) * 4096 + dv * 64 + dk] = __float2bfloat16(s);
            s += MP[(size_t)(slot * 16 + bh) * 4096 + e];
        }
    }
    if (t < 64) {
        float s = 1.0f / DK_;
        #pragma unroll
        for (int slot = 0; slot < 16; slot++) {
            if ((slot & 3) == 0) ZS[((slot >> 2) * 16 + bh) * 64 + t] = s;
            s += ZP[(slot * 16 + bh) * 64 + t];
        }
    }
}

// ---------------------------------------------------------------------------
// MFMA flash attention + compressive-memory retrieval
// grid (32 qt, 16 bh, 4 seg); block 256 (4 waves x 16 q rows)
// ---------------------------------------------------------------------------
__global__ __launch_bounds__(256) void attn_k(
    const bf16* __restrict__ Qg, const bf16* __restrict__ Kg, const bf16* __restrict__ Vt,
    const bf16* __restrict__ MsT, const float* __restrict__ ZS,
    const float* __restrict__ betas, bf16* __restrict__ att)
{
    __shared__ bf16 Qs[64 * 64];     // reused as Ps after Q-frag load
    __shared__ bf16 Ks[64 * 64];     // reused for mem^T tile in retrieval
    __shared__ bf16 Vts[64 * 64];
    __shared__ float Zs[64];
    __shared__ float denL[64];

    const int t    = threadIdx.x;
    const int lane = t & 63;
    const int w    = t >> 6;       // wave: q rows [w*16, w*16+16)
    const int la   = lane & 15;
    const int g    = lane >> 4;
    const int qt   = blockIdx.x;
    const int bh   = blockIdx.y;
    const int seg  = blockIdx.z;
    const int b    = bh >> 3, h = bh & 7;

    const size_t srow = (size_t)b * S_ + (size_t)seg * SEG_;
    const bf16* qp  = Qg + (srow + (size_t)qt * 64) * 512 + h * 64;
    const bf16* kp  = Kg + srow * 512 + h * 64;
    const bf16* vtp = Vt + (size_t)bh * 64 * (size_t)S_ + (size_t)seg * SEG_;

    // stage Q tile (once)
    #pragma unroll
    for (int ii = 0; ii < 2; ii++) {
        int i = w * 2 + ii;
        gld_lds16(qp + (size_t)(8 * i + (lane >> 3)) * 512 + (lane & 7) * 8, Qs + i * 512);
    }
    __syncthreads();

    // Q A-frags (row = la, k = 32s + 8g + [0..8))
    bf16x8 aq[2];
    aq[0] = *(const bf16x8*)&Qs[(w * 16 + la) * 64 + g * 8];
    aq[1] = *(const bf16x8*)&Qs[(w * 16 + la) * 64 + 32 + g * 8];

    bf16* Ps = Qs;  // alias: Qs no longer needed (aq held in regs; barrier order is safe)

    float m_r[4], l_r[4];
    f32x4 Oa[4];
    #pragma unroll
    for (int r = 0; r < 4; r++) { m_r[r] = -1e30f; l_r[r] = 0.f; }
    #pragma unroll
    for (int j = 0; j < 4; j++) { f32x4 z4 = {0.f,0.f,0.f,0.f}; Oa[j] = z4; }

    const int qg_base = qt * 64 + w * 16 + g * 4;   // segment-local q row of reg r

    for (int jt = 0; jt <= qt; jt++) {
        #pragma unroll
        for (int ii = 0; ii < 2; ii++) {
            int i = w * 2 + ii;
            gld_lds16(kp  + (size_t)(jt * 64 + 8 * i + (lane >> 3)) * 512 + (lane & 7) * 8,
                      Ks + i * 512);
            gld_lds16(vtp + (size_t)(8 * i + (lane >> 3)) * (size_t)S_ + jt * 64 + (lane & 7) * 8,
                      Vts + i * 512);
        }
        __syncthreads();

        // S = Q @ K^T  (strip 16q x 64kv)
        f32x4 sc[4];
        #pragma unroll
        for (int j = 0; j < 4; j++) { f32x4 z4 = {0.f,0.f,0.f,0.f}; sc[j] = z4; }
        #pragma unroll
        for (int s = 0; s < 2; s++) {
            #pragma unroll
            for (int j = 0; j < 4; j++) {
                bf16x8 bk = *(const bf16x8*)&Ks[(j * 16 + la) * 64 + 32 * s + g * 8];
                sc[j] = __builtin_amdgcn_mfma_f32_16x16x32_bf16(aq[s], bk, sc[j], 0, 0, 0);
            }
        }

        // online softmax (rows = g*4+r, cols = j*16+la)
        const int kv_base = jt * 64;
        #pragma unroll
        for (int r = 0; r < 4; r++) {
            float sv[4];
            float mx = -1e30f;
            #pragma unroll
            for (int j = 0; j < 4; j++) {
                float v = sc[j][r] * 0.125f;
                if (jt == qt && (kv_base + j * 16 + la) > (qg_base + r)) v = -1e30f;
                sv[j] = v;
                mx = fmaxf(mx, v);
            }
            #pragma unroll
            for (int mk = 1; mk < 16; mk <<= 1) mx = fmaxf(mx, __shfl_xor(mx, mk));
            float mnew = fmaxf(m_r[r], mx);
            float corr = __expf(m_r[r] - mnew);
            float rs = 0.f;
            float pv[4];
            #pragma unroll
            for (int j = 0; j < 4; j++) { pv[j] = __expf(sv[j] - mnew); rs += pv[j]; }
            #pragma unroll
            for (int mk = 1; mk < 16; mk <<= 1) rs += __shfl_xor(rs, mk);
            l_r[r] = l_r[r] * corr + rs;
            m_r[r] = mnew;
            #pragma unroll
            for (int j = 0; j < 4; j++) Oa[j][r] *= corr;
            #pragma unroll
            for (int j = 0; j < 4; j++)
                Ps[(w * 16 + g * 4 + r) * 64 + j * 16 + la] = __float2bfloat16(pv[j]);
        }
        __syncthreads();

        // O += P @ V   (P[q][kv] x Vt[dv][kv])
        bf16x8 ap0 = *(const bf16x8*)&Ps[(w * 16 + la) * 64 + g * 8];
        bf16x8 ap1 = *(const bf16x8*)&Ps[(w * 16 + la) * 64 + 32 + g * 8];
        #pragma unroll
        for (int j = 0; j < 4; j++) {
            bf16x8 bv0 = *(const bf16x8*)&Vts[(j * 16 + la) * 64 + g * 8];
            bf16x8 bv1 = *(const bf16x8*)&Vts[(j * 16 + la) * 64 + 32 + g * 8];
            Oa[j] = __builtin_amdgcn_mfma_f32_16x16x32_bf16(ap0, bv0, Oa[j], 0, 0, 0);
            Oa[j] = __builtin_amdgcn_mfma_f32_16x16x32_bf16(ap1, bv1, Oa[j], 0, 0, 0);
        }
        __syncthreads();
    }

    // ---- retrieval: num = elu1(Q) @ mem, den = elu1(Q) @ z ----
    #pragma unroll
    for (int ii = 0; ii < 2; ii++) {
        int i = w * 2 + ii;
        gld_lds16(MsT + (size_t)(seg * 16 + bh) * 4096 + i * 512 + lane * 8, Ks + i * 512);
    }
    if (t < 64) Zs[t] = ZS[(seg * 16 + bh) * 64 + t];
    __syncthreads();

    bf16x8 sq[2];
    float den_part = 0.f;
    #pragma unroll
    for (int s = 0; s < 2; s++) {
        bvec in, outv;
        in.v = aq[s];
        #pragma unroll
        for (int e = 0; e < 8; e++) {
            float f = elu1(__bfloat162float(in.e[e]));
            outv.e[e] = __float2bfloat16(f);
            den_part += f * Zs[32 * s + 8 * g + e];
        }
        sq[s] = outv.v;
    }
    den_part += __shfl_xor(den_part, 16);
    den_part += __shfl_xor(den_part, 32);
    if (g == 0) denL[w * 16 + la] = den_part;

    f32x4 num[4];
    #pragma unroll
    for (int j = 0; j < 4; j++) { f32x4 z4 = {0.f,0.f,0.f,0.f}; num[j] = z4; }
    #pragma unroll
    for (int s = 0; s < 2; s++)
        #pragma unroll
        for (int j = 0; j < 4; j++) {
            bf16x8 bm = *(const bf16x8*)&Ks[(j * 16 + la) * 64 + 32 * s + g * 8];
            num[j] = __builtin_amdgcn_mfma_f32_16x16x32_bf16(sq[s], bm, num[j], 0, 0, 0);
        }
    __syncthreads();

    const size_t ob = (srow + (size_t)qt * 64 + w * 16 + g * 4) * 512 + h * 64;
    #pragma unroll
    for (int j = 0; j < 4; j++) {
        int dv = j * 16 + la;
        float gate = 1.f / (1.f + __expf(-betas[h * 64 + dv]));
        #pragma unroll
        for (int r = 0; r < 4; r++) {
            float den = denL[w * 16 + g * 4 + r];
            float am = num[j][r] / den;
            float ad = Oa[j][r] / l_r[r];
            att[ob + (size_t)r * 512 + dv] = __float2bfloat16(gate * am + (1.f - gate) * ad);
        }
    }
}

// ---------------------------------------------------------------------------
// LayerNorm (in-place safe)
// ---------------------------------------------------------------------------
__global__ __launch_bounds__(256) void ln_k(
    const float* __restrict__ Y, const float* __restrict__ g,
    const float* __restrict__ bta, float* __restrict__ out)
{
    const int row = blockIdx.x;
    const float* yp = Y + (size_t)row * D_;
    const int t = threadIdx.x;
    float v[4];
    float s = 0.f, s2 = 0.f;
    #pragma unroll
    for (int i = 0; i < 4; i++) {
        v[i] = yp[t + i * 256];
        s += v[i]; s2 += v[i] * v[i];
    }
    #pragma unroll
    for (int mk = 1; mk < 64; mk <<= 1) {
        s  += __shfl_xor(s, mk);
        s2 += __shfl_xor(s2, mk);
    }
    __shared__ float ss[4], ss2[4];
    int w = t >> 6;
    if ((t & 63) == 0) { ss[w] = s; ss2[w] = s2; }
    __syncthreads();
    s  = ss[0] + ss[1] + ss[2] + ss[3];
    s2 = ss2[0] + ss2[1] + ss2[2] + ss2[3];
    float mu   = s / D_;
    float var  = s2 / D_ - mu * mu;
    float rstd = rsqrtf(var + EPS_);
    #pragma unroll
    for (int i = 0; i < 4; i++) {
        int c = t + i * 256;
        out[(size_t)row * D_ + c] = (v[i] - mu) * rstd * g[c] + bta[c];
    }
}

// ---------------------------------------------------------------------------
extern "C" void kernel_launch(void* const* d_in, const int* in_sizes, int n_in,
                              void* d_out, int out_size, void* d_ws, size_t ws_size,
                              hipStream_t stream)
{
    const float* x     = (const float*)d_in[0];
    const float* Wq    = (const float*)d_in[1];
    const float* Wk    = (const float*)d_in[2];
    const float* Wv    = (const float*)d_in[3];
    const float* Wo    = (const float*)d_in[4];
    const float* betas = (const float*)d_in[5];
    const float* W1    = (const float*)d_in[6];
    const float* b1    = (const float*)d_in[7];
    const float* W2    = (const float*)d_in[8];
    const float* b2    = (const float*)d_in[9];
    const float* lng   = (const float*)d_in[10];
    const float* lnb   = (const float*)d_in[11];
    float* out = (float*)d_out;

    const int M = B_ * S_;                    // 16384
    char* base = (char*)d_ws;
    const size_t MB = 1024 * 1024;

    bf16*  Xbf = (bf16*)(base);              // 32MB
    bf16*  Qb  = (bf16*)(base + 32 * MB);    // 16MB
    bf16*  Kb  = (bf16*)(base + 48 * MB);
    bf16*  Vb  = (bf16*)(base + 64 * MB);
    bf16*  Vt  = (bf16*)(base + 80 * MB);
    bf16*  ATT = (bf16*)(base + 96 * MB);
    bf16*  Hb  = (bf16*)(base);              // reuse [0,128MB) during FFN
    bf16*  Ab  = (bf16*)(base + 128 * MB);   // 32MB
    bf16*  WqT = (bf16*)(base + 160 * MB);
    bf16*  WkT = (bf16*)(base + 161 * MB);
    bf16*  WvT = (bf16*)(base + 162 * MB);
    bf16*  WoT = (bf16*)(base + 163 * MB);
    bf16*  W1T = (bf16*)(base + 164 * MB);   // 8MB
    bf16*  W2T = (bf16*)(base + 172 * MB);   // 8MB
    float* MP  = (float*)(base + 180 * MB);  // 4MB
    bf16*  MST = (bf16*)(base + 184 * MB);   // 512KB
    float* ZP  = (float*)(base + 185 * MB);
    float* ZS  = (float*)(base + 185 * MB + 256 * 1024);

    dim3 blk(256);

    castx_k<<<dim3((M * D_) / 1024), blk, 0, stream>>>(x, Xbf);
    transcast_k<<<dim3(512 / 32, 1024 / 32), blk, 0, stream>>>(Wq, WqT, 1024, 512);
    transcast_k<<<dim3(512 / 32, 1024 / 32), blk, 0, stream>>>(Wk, WkT, 1024, 512);
    transcast_k<<<dim3(512 / 32, 1024 / 32), blk, 0, stream>>>(Wv, WvT, 1024, 512);
    transcast_k<<<dim3(1024 / 32, 512 / 32), blk, 0, stream>>>(Wo, WoT, 512, 1024);
    transcast_k<<<dim3(4096 / 32, 1024 / 32), blk, 0, stream>>>(W1, W1T, 1024, 4096);
    transcast_k<<<dim3(1024 / 32, 4096 / 32), blk, 0, stream>>>(W2, W2T, 4096, 1024);

    mfma_gemm<0, bf16><<<dim3(512 / 128, M / 128), blk, 0, stream>>>(
        Xbf, WqT, Qb, nullptr, nullptr, M, 512, 1024);
    mfma_gemm<0, bf16><<<dim3(512 / 128, M / 128), blk, 0, stream>>>(
        Xbf, WkT, Kb, nullptr, nullptr, M, 512, 1024);
    mfma_gemm<0, bf16><<<dim3(512 / 128, M / 128), blk, 0, stream>>>(
        Xbf, WvT, Vb, nullptr, nullptr, M, 512, 1024);

    vtrans_k<<<dim3(256, 8), blk, 0, stream>>>(Vb, Vt);

    memseg_k<<<dim3(NSEG_ * 16, 4), blk, 0, stream>>>(Kb, Vb, MP, ZP);
    prefix_k<<<dim3(16), blk, 0, stream>>>(MP, ZP, MST, ZS);

    attn_k<<<dim3(SEG_ / 64, 16, NSEG_), blk, 0, stream>>>(
        Qb, Kb, Vt, MST, ZS, betas, ATT);

    mfma_gemm<0, bf16><<<dim3(1024 / 128, M / 128), blk, 0, stream>>>(
        ATT, WoT, Ab, nullptr, nullptr, M, 1024, 512);
    mfma_gemm<2, bf16><<<dim3(4096 / 128, M / 128), blk, 0, stream>>>(
        Ab, W1T, Hb, b1, nullptr, M, 4096, 1024);
    mfma_gemm<3, float><<<dim3(1024 / 128, M / 128), blk, 0, stream>>>(
        Hb, W2T, out, b2, x, M, 1024, 4096);

    ln_k<<<dim3(M), blk, 0, stream>>>(out, lng, lnb, out);
}

// Round 4
// 830.906 us; speedup vs baseline: 10.3833x; 1.1397x over previous
//
#include <hip/hip_runtime.h>
#include <hip/hip_bf16.h>
#include <math.h>

#define B_    2
#define S_    8192
#define D_    1024
#define H_N   8
#define DK_   64
#define DV_   64
#define DH_   4096
#define SEG_  2048
#define NSEG_ 4
#define EPS_  1e-5f

typedef __hip_bfloat16 bf16;
typedef unsigned int u32;
typedef __attribute__((ext_vector_type(8))) short bf16x8;
typedef __attribute__((ext_vector_type(4))) float f32x4;

union bvec { bf16x8 v; bf16 e[8]; };

template <typename T> __device__ inline T from_f(float v);
template <> __device__ inline float from_f<float>(float v) { return v; }
template <> __device__ inline bf16  from_f<bf16>(float v)  { return __float2bfloat16(v); }

__device__ __forceinline__ void gld_lds16(const bf16* g, bf16* l) {
    __builtin_amdgcn_global_load_lds(
        (const __attribute__((address_space(1))) u32*)g,
        (__attribute__((address_space(3))) u32*)l, 16, 0, 0);
}

__device__ inline float elu1(float x) { return x > 0.f ? x + 1.f : __expf(x); }

// ---------------------------------------------------------------------------
// MFMA GEMM (m97 structure): C[M,N] = A[M,K] @ BT[N,K]^T
// ---------------------------------------------------------------------------
template <int EPI, typename CT>
__global__ __launch_bounds__(256) void mfma_gemm(
    const bf16* __restrict__ A, const bf16* __restrict__ BT, CT* __restrict__ C,
    const float* __restrict__ bias, const float* __restrict__ resid,
    int M, int N, int K)
{
    __shared__ bf16 As[128 * 32];
    __shared__ bf16 Bs[128 * 32];
    const int t    = threadIdx.x;
    const int lane = t & 63;
    const int wave = t >> 6;

    const int nx  = gridDim.x;
    const int nwg = nx * gridDim.y;
    const int lin = blockIdx.y * nx + blockIdx.x;
    const int swz = (lin & 7) * (nwg >> 3) + (lin >> 3);
    const int by  = swz / nx, bx = swz - by * nx;

    const int m0 = by * 128, n0 = bx * 128;
    const int wr = (wave >> 1) * 64, wc = (wave & 1) * 64;

    f32x4 acc[4][4];
    #pragma unroll
    for (int i = 0; i < 4; i++)
        #pragma unroll
        for (int j = 0; j < 4; j++) {
            f32x4 z4 = {0.f, 0.f, 0.f, 0.f};
            acc[i][j] = z4;
        }

    const int rA  = t >> 2,         cA  = (t & 3) * 8;
    const int rA2 = (t + 256) >> 2, cA2 = ((t + 256) & 3) * 8;
    bf16* ldsA0 = As + (size_t)(wave * 64) * 8;
    bf16* ldsA1 = As + (size_t)(256 + wave * 64) * 8;
    bf16* ldsB0 = Bs + (size_t)(wave * 64) * 8;
    bf16* ldsB1 = Bs + (size_t)(256 + wave * 64) * 8;

    const bf16* Ap = A  + (size_t)m0 * K;
    const bf16* Bp = BT + (size_t)n0 * K;

    const int la = lane & 15, ksel = (lane >> 4) * 8;

    for (int k0 = 0; k0 < K; k0 += 32) {
        gld_lds16(Ap + (size_t)rA  * K + k0 + cA,  ldsA0);
        gld_lds16(Ap + (size_t)rA2 * K + k0 + cA2, ldsA1);
        gld_lds16(Bp + (size_t)rA  * K + k0 + cA,  ldsB0);
        gld_lds16(Bp + (size_t)rA2 * K + k0 + cA2, ldsB1);
        __syncthreads();
        bf16x8 af[4], bg[4];
        #pragma unroll
        for (int i = 0; i < 4; i++)
            af[i] = *(const bf16x8*)&As[(size_t)(wr + i * 16 + la) * 32 + ksel];
        #pragma unroll
        for (int j = 0; j < 4; j++)
            bg[j] = *(const bf16x8*)&Bs[(size_t)(wc + j * 16 + la) * 32 + ksel];
        #pragma unroll
        for (int i = 0; i < 4; i++)
            #pragma unroll
            for (int j = 0; j < 4; j++)
                acc[i][j] = __builtin_amdgcn_mfma_f32_16x16x32_bf16(
                    af[i], bg[j], acc[i][j], 0, 0, 0);
        __syncthreads();
    }

    const int row0 = m0 + wr + (lane >> 4) * 4;
    const int col0 = n0 + wc + la;
    #pragma unroll
    for (int i = 0; i < 4; i++) {
        #pragma unroll
        for (int j = 0; j < 4; j++) {
            const int col = col0 + j * 16;
            float bj = (EPI >= 2) ? bias[col] : 0.f;
            #pragma unroll
            for (int r = 0; r < 4; r++) {
                const int row = row0 + i * 16 + r;
                float v = acc[i][j][r];
                if (EPI >= 2) v += bj;
                if (EPI == 2) v = 0.5f * v * (1.0f + erff(v * 0.70710678118654752f));
                if (EPI == 3) v += resid[(size_t)row * N + col];
                C[(size_t)row * N + col] = from_f<CT>(v);
            }
        }
    }
}

// ---------------------------------------------------------------------------
// casts
// ---------------------------------------------------------------------------
__global__ __launch_bounds__(256) void castx_k(const float* __restrict__ X,
                                               bf16* __restrict__ Y)
{
    size_t i = ((size_t)blockIdx.x * 256 + threadIdx.x) * 4;
    float4 v = *(const float4*)(X + i);
    union { bf16 b[4]; unsigned long long u; } o;
    o.b[0] = __float2bfloat16(v.x);
    o.b[1] = __float2bfloat16(v.y);
    o.b[2] = __float2bfloat16(v.z);
    o.b[3] = __float2bfloat16(v.w);
    *(unsigned long long*)(Y + i) = o.u;
}

__global__ __launch_bounds__(256) void transcast_k(const float* __restrict__ W,
                                                   bf16* __restrict__ WT, int K, int N)
{
    __shared__ float tile[32][33];
    const int n0 = blockIdx.x * 32, k0 = blockIdx.y * 32;
    const int tx = threadIdx.x & 31, ty = threadIdx.x >> 5;
    #pragma unroll
    for (int i = 0; i < 32; i += 8)
        tile[ty + i][tx] = W[(size_t)(k0 + ty + i) * N + n0 + tx];
    __syncthreads();
    #pragma unroll
    for (int i = 0; i < 32; i += 8)
        WT[(size_t)(n0 + ty + i) * K + k0 + tx] = __float2bfloat16(tile[tx][ty + i]);
}

// V [b][s][h*64+dv] bf16 -> Vt [ (b*8+h)*64+dv ][ s ] bf16
__global__ __launch_bounds__(256) void vtrans_k(const bf16* __restrict__ V,
                                                bf16* __restrict__ Vt)
{
    __shared__ bf16 t_[64 * 64];
    const int t = threadIdx.x;
    const int sblk = blockIdx.x & 127;
    const int b = blockIdx.x >> 7;
    const int h = blockIdx.y;
    const bf16* src = V + ((size_t)b * S_ + sblk * 64) * 512 + h * 64;
    #pragma unroll
    for (int k = 0; k < 2; k++) {
        int e = t + k * 256;
        int r = e >> 3, c8 = (e & 7) * 8;
        *(bf16x8*)&t_[r * 64 + c8] = *(const bf16x8*)&src[(size_t)r * 512 + c8];
    }
    __syncthreads();
    const int dv = t & 63, s0 = (t >> 6) * 16;
    bf16* dst = Vt + ((size_t)(b * 8 + h) * 64 + dv) * (size_t)S_ + sblk * 64 + s0;
    bvec o0, o1;
    #pragma unroll
    for (int i = 0; i < 8; i++) {
        o0.e[i] = t_[(s0 + i) * 64 + dv];
        o1.e[i] = t_[(s0 + 8 + i) * 64 + dv];
    }
    *(bf16x8*)dst = o0.v;
    *(bf16x8*)(dst + 8) = o1.v;
}

// ---------------------------------------------------------------------------
// Per-(segment,chunk) partial memory (bf16 in, f32 accumulate)
// ---------------------------------------------------------------------------
__global__ __launch_bounds__(256) void memseg_k(
    const bf16* __restrict__ Kg, const bf16* __restrict__ Vg,
    float* __restrict__ MP, float* __restrict__ ZP)
{
    __shared__ float Ks[64][65];
    __shared__ float Vs[64][65];
    const int t = threadIdx.x, tx = t & 15, ty = t >> 4;
    const int sb = blockIdx.x;
    const int seg = sb >> 4, bh = sb & 15;
    const int b = bh >> 3, h = bh & 7;
    const int chunk = blockIdx.y;
    const size_t base = ((size_t)b * S_ + (size_t)seg * SEG_ + (size_t)chunk * 512) * 512 + h * 64;

    float acc[4][4] = {};
    float zacc[4]   = {};
    for (int st = 0; st < 8; st++) {
        #pragma unroll
        for (int kk = 0; kk < 2; kk++) {
            int e = t + kk * 256;
            int r = e >> 3, c8 = (e & 7) * 8;
            size_t go = base + ((size_t)st * 64 + r) * 512 + c8;
            bvec kv_, vv_;
            kv_.v = *(const bf16x8*)&Kg[go];
            vv_.v = *(const bf16x8*)&Vg[go];
            #pragma unroll
            for (int i = 0; i < 8; i++) {
                Ks[r][c8 + i] = elu1(__bfloat162float(kv_.e[i]));
                Vs[r][c8 + i] = __bfloat162float(vv_.e[i]);
            }
        }
        __syncthreads();
        for (int s = 0; s < 64; s++) {
            float a4[4], v4[4];
            #pragma unroll
            for (int i = 0; i < 4; i++) a4[i] = Ks[s][ty * 4 + i];
            #pragma unroll
            for (int j = 0; j < 4; j++) v4[j] = Vs[s][tx * 4 + j];
            #pragma unroll
            for (int i = 0; i < 4; i++)
                #pragma unroll
                for (int j = 0; j < 4; j++)
                    acc[i][j] += a4[i] * v4[j];
        }
        #pragma unroll
        for (int ii = 0; ii < 4; ii++) {
            int s = tx + ii * 16;
            #pragma unroll
            for (int i = 0; i < 4; i++) zacc[i] += Ks[s][ty * 4 + i];
        }
        __syncthreads();
    }
    const int slot = (seg * 4 + chunk) * 16 + bh;
    #pragma unroll
    for (int i = 0; i < 4; i++)
        #pragma unroll
        for (int j = 0; j < 4; j++)
            MP[(size_t)slot * 4096 + (ty * 4 + i) * 64 + tx * 4 + j] = acc[i][j];
    #pragma unroll
    for (int i = 0; i < 4; i++) {
        float zz = zacc[i];
        #pragma unroll
        for (int mk = 1; mk < 16; mk <<= 1) zz += __shfl_xor(zz, mk);
        if (tx == 0) ZP[slot * 64 + ty * 4 + i] = zz;
    }
}

// exclusive prefix -> per-seg start states: MST transposed bf16 [dv][dk], ZS f32
__global__ __launch_bounds__(256) void prefix_k(
    const float* __restrict__ MP, const float* __restrict__ ZP,
    bf16* __restrict__ MST, float* __restrict__ ZS)
{
    const int bh = blockIdx.x, t = threadIdx.x;
    for (int e = t; e < 4096; e += 256) {
        int dk = e >> 6, dv = e & 63;
        float s = 0.f;
        #pragma unroll
        for (int slot = 0; slot < 16; slot++) {
            if ((slot & 3) == 0)
                MST[(size_t)((slot >> 2) * 16 + bh) * 4096 + dv * 64 + dk] = __float2bfloat16(s);
            s += MP[(size_t)(slot * 16 + bh) * 4096 + e];
        }
    }
    if (t < 64) {
        float s = 1.0f / DK_;
        #pragma unroll
        for (int slot = 0; slot < 16; slot++) {
            if ((slot & 3) == 0) ZS[((slot >> 2) * 16 + bh) * 64 + t] = s;
            s += ZP[(slot * 16 + bh) * 64 + t];
        }
    }
}

// ---------------------------------------------------------------------------
// attn helpers: swizzled staging / reads.  LDS tile: element (row,col) at byte
// row*128 + ((col*2) ^ ((row&7)<<4)).  Staged via linear gld_lds with the
// global column-chunk pre-swizzled: chunk' = (lane&7) ^ (lane>>3).
// ---------------------------------------------------------------------------
template <int NG>
__device__ __forceinline__ void stageT(const bf16* gsrc, size_t stride, bf16* lds,
                                       int wave, int lane)
{
    #pragma unroll
    for (int ii = 0; ii < NG; ii++) {
        int i = wave * NG + ii;
        gld_lds16(gsrc + (size_t)(8 * i + (lane >> 3)) * stride
                        + (size_t)(((lane & 7) ^ (lane >> 3)) * 8),
                  lds + i * 512);
    }
}

__device__ __forceinline__ bf16x8 ldsw128(const bf16* base, int row, int colE)
{
    int off = row * 128 + ((colE * 2) ^ ((row & 7) << 4));
    return *(const bf16x8*)((const char*)base + off);
}

// ---------------------------------------------------------------------------
// MFMA flash attention (swapped QK^T, swizzled LDS, double-buffered K/V,
// 1 barrier per kv-tile) + compressive-memory retrieval.
// grid (16 qt [reversed], 16 bh, 4 seg); block 256 = 4 waves x 32 q rows.
// ---------------------------------------------------------------------------
__global__ __launch_bounds__(256) void attn_k(
    const bf16* __restrict__ Qg, const bf16* __restrict__ Kg, const bf16* __restrict__ Vt,
    const bf16* __restrict__ MsT, const float* __restrict__ ZS,
    const float* __restrict__ betas, bf16* __restrict__ att)
{
    __shared__ bf16 KT[2][4096];
    __shared__ bf16 VTs[2][4096];
    __shared__ bf16 QP[8192];       // Q tile 128x64; per-wave rows reused as P
    __shared__ float Zsm[64];

    const int t    = threadIdx.x;
    const int lane = t & 63;
    const int w    = t >> 6;
    const int la   = lane & 15;
    const int g    = lane >> 4;
    const int qt   = (int)gridDim.x - 1 - (int)blockIdx.x;   // big blocks first
    const int bh   = blockIdx.y;
    const int seg  = blockIdx.z;
    const int b    = bh >> 3, h = bh & 7;

    const size_t srow = (size_t)b * S_ + (size_t)seg * SEG_;
    const bf16* qp  = Qg + (srow + (size_t)qt * 128) * 512 + h * 64;
    const bf16* kp  = Kg + srow * 512 + h * 64;
    const bf16* vtp = Vt + (size_t)bh * 64 * (size_t)S_ + (size_t)seg * SEG_;

    // prologue: stage Q (each wave its own 32 rows) + K/V tile 0
    stageT<4>(qp, 512, QP, w, lane);
    stageT<2>(kp, 512, KT[0], w, lane);
    stageT<2>(vtp, S_, VTs[0], w, lane);
    if (t < 64) Zsm[t] = ZS[(seg * 16 + bh) * 64 + t];
    __syncthreads();

    // Q A/B-frags: row = la (strip-local), k-chunk = s*32 + g*8
    bf16x8 aq[2][2];
    #pragma unroll
    for (int st = 0; st < 2; st++)
        #pragma unroll
        for (int s = 0; s < 2; s++)
            aq[st][s] = ldsw128(QP, w * 32 + st * 16 + la, s * 32 + g * 8);

    float m_[2] = {-1e30f, -1e30f};
    float l_[2] = {0.f, 0.f};
    f32x4 Oa[2][4];
    #pragma unroll
    for (int st = 0; st < 2; st++)
        #pragma unroll
        for (int j = 0; j < 4; j++) { f32x4 z4 = {0.f,0.f,0.f,0.f}; Oa[st][j] = z4; }

    const int jtmax = 2 * qt + 1;
    int cur = 0;
    for (int jt = 0; jt <= jtmax; jt++, cur ^= 1) {
        if (jt < jtmax) {   // stage next tile into other buffer (latency hidden)
            stageT<2>(kp + (size_t)(jt + 1) * 64 * 512, 512, KT[cur ^ 1], w, lane);
            stageT<2>(vtp + (size_t)(jt + 1) * 64, S_, VTs[cur ^ 1], w, lane);
        }

        // K frags: row kv = j*16+la, k-chunk s*32+g*8
        bf16x8 kf[2][4];
        #pragma unroll
        for (int s = 0; s < 2; s++)
            #pragma unroll
            for (int j = 0; j < 4; j++)
                kf[s][j] = ldsw128(KT[cur], j * 16 + la, s * 32 + g * 8);

        const int jtkv = jt * 64;
        #pragma unroll
        for (int st = 0; st < 2; st++) {
            // swapped QK^T: D[kv][q] -> lane la owns q-row la,
            // kv = jtkv + j*16 + g*4 + r
            f32x4 sc[4];
            #pragma unroll
            for (int j = 0; j < 4; j++) { f32x4 z4 = {0.f,0.f,0.f,0.f}; sc[j] = z4; }
            #pragma unroll
            for (int j = 0; j < 4; j++) {
                sc[j] = __builtin_amdgcn_mfma_f32_16x16x32_bf16(kf[0][j], aq[st][0], sc[j], 0, 0, 0);
                sc[j] = __builtin_amdgcn_mfma_f32_16x16x32_bf16(kf[1][j], aq[st][1], sc[j], 0, 0, 0);
            }

            const int q_abs = qt * 128 + w * 32 + st * 16 + la;
            float sv[4][4];
            float mx = -1e30f;
            #pragma unroll
            for (int j = 0; j < 4; j++)
                #pragma unroll
                for (int r = 0; r < 4; r++) {
                    float v = sc[j][r] * 0.125f;
                    int kv = jtkv + j * 16 + g * 4 + r;
                    v = (kv <= q_abs) ? v : -1e30f;
                    sv[j][r] = v;
                    mx = fmaxf(mx, v);
                }
            mx = fmaxf(mx, __shfl_xor(mx, 16));
            mx = fmaxf(mx, __shfl_xor(mx, 32));
            float mnew = fmaxf(m_[st], mx);
            float corr = __expf(m_[st] - mnew);
            float rs = 0.f;
            #pragma unroll
            for (int j = 0; j < 4; j++)
                #pragma unroll
                for (int r = 0; r < 4; r++) {
                    float p = __expf(sv[j][r] - mnew);
                    sv[j][r] = p;
                    rs += p;
                }
            rs += __shfl_xor(rs, 16);
            rs += __shfl_xor(rs, 32);
            l_[st] = l_[st] * corr + rs;
            m_[st] = mnew;

            // P write (wave-local rows): row = w*32+st*16+la, col = j*16+g*4+[0,4)
            const int R = w * 32 + st * 16 + la;
            #pragma unroll
            for (int j = 0; j < 4; j++) {
                union { bf16 e[4]; uint2 u; } pk;
                #pragma unroll
                for (int r = 0; r < 4; r++) pk.e[r] = __float2bfloat16(sv[j][r]);
                int off = R * 128 + ((j * 32 + g * 8) ^ ((la & 7) << 4));
                *(uint2*)((char*)QP + off) = pk.u;
            }

            // rescale O (rows g*4+r): corr for that row lives in lane (g*16 + g*4+r)
            #pragma unroll
            for (int r = 0; r < 4; r++) {
                float corr_r = __shfl(corr, (lane & 48) | (g * 4 + r));
                #pragma unroll
                for (int j = 0; j < 4; j++) Oa[st][j][r] *= corr_r;
            }
        }

        asm volatile("s_waitcnt lgkmcnt(0)" ::: "memory");
        __builtin_amdgcn_sched_barrier(0);

        // PV: O[q][dv] += P[q][kv] @ Vt[dv][kv]
        bf16x8 bv[2][4];
        #pragma unroll
        for (int s = 0; s < 2; s++)
            #pragma unroll
            for (int j = 0; j < 4; j++)
                bv[s][j] = ldsw128(VTs[cur], j * 16 + la, s * 32 + g * 8);
        #pragma unroll
        for (int st = 0; st < 2; st++) {
            bf16x8 ap0 = ldsw128(QP, w * 32 + st * 16 + la, g * 8);
            bf16x8 ap1 = ldsw128(QP, w * 32 + st * 16 + la, 32 + g * 8);
            #pragma unroll
            for (int j = 0; j < 4; j++) {
                Oa[st][j] = __builtin_amdgcn_mfma_f32_16x16x32_bf16(ap0, bv[0][j], Oa[st][j], 0, 0, 0);
                Oa[st][j] = __builtin_amdgcn_mfma_f32_16x16x32_bf16(ap1, bv[1][j], Oa[st][j], 0, 0, 0);
            }
        }
        __syncthreads();   // drains vmcnt (staged tile ready) + buffer handoff
    }

    // ---- retrieval: num = elu1(Q) @ mem, den = elu1(Q) @ z ----
    stageT<2>(MsT + (size_t)(seg * 16 + bh) * 4096, 64, KT[0], w, lane);
    __syncthreads();

    bf16x8 sq[2][2];
    float den[2] = {0.f, 0.f};
    #pragma unroll
    for (int st = 0; st < 2; st++) {
        #pragma unroll
        for (int s = 0; s < 2; s++) {
            bvec in, outv;
            in.v = aq[st][s];
            #pragma unroll
            for (int e = 0; e < 8; e++) {
                float f = elu1(__bfloat162float(in.e[e]));
                outv.e[e] = __float2bfloat16(f);
                den[st] += f * Zsm[s * 32 + g * 8 + e];
            }
            sq[st][s] = outv.v;
        }
        den[st] += __shfl_xor(den[st], 16);
        den[st] += __shfl_xor(den[st], 32);
    }

    bf16x8 bm[2][4];
    #pragma unroll
    for (int s = 0; s < 2; s++)
        #pragma unroll
        for (int j = 0; j < 4; j++)
            bm[s][j] = ldsw128(KT[0], j * 16 + la, s * 32 + g * 8);

    float gate[4];
    #pragma unroll
    for (int j = 0; j < 4; j++)
        gate[j] = 1.f / (1.f + __expf(-betas[h * 64 + j * 16 + la]));

    #pragma unroll
    for (int st = 0; st < 2; st++) {
        f32x4 num[4];
        #pragma unroll
        for (int j = 0; j < 4; j++) { f32x4 z4 = {0.f,0.f,0.f,0.f}; num[j] = z4; }
        #pragma unroll
        for (int j = 0; j < 4; j++) {
            num[j] = __builtin_amdgcn_mfma_f32_16x16x32_bf16(sq[st][0], bm[0][j], num[j], 0, 0, 0);
            num[j] = __builtin_amdgcn_mfma_f32_16x16x32_bf16(sq[st][1], bm[1][j], num[j], 0, 0, 0);
        }
        #pragma unroll
        for (int r = 0; r < 4; r++) {
            float den_r = __shfl(den[st], (lane & 48) | (g * 4 + r));
            float l_r   = __shfl(l_[st],  (lane & 48) | (g * 4 + r));
            float linv  = 1.f / l_r;
            float dinv  = 1.f / den_r;
            size_t orow = srow + (size_t)qt * 128 + w * 32 + st * 16 + g * 4 + r;
            #pragma unroll
            for (int j = 0; j < 4; j++) {
                float am = num[j][r] * dinv;
                float ad = Oa[st][j][r] * linv;
                att[orow * 512 + h * 64 + j * 16 + la] =
                    __float2bfloat16(gate[j] * am + (1.f - gate[j]) * ad);
            }
        }
    }
}

// ---------------------------------------------------------------------------
// LayerNorm (in-place safe)
// ---------------------------------------------------------------------------
__global__ __launch_bounds__(256) void ln_k(
    const float* __restrict__ Y, const float* __restrict__ g,
    const float* __restrict__ bta, float* __restrict__ out)
{
    const int row = blockIdx.x;
    const float* yp = Y + (size_t)row * D_;
    const int t = threadIdx.x;
    float v[4];
    float s = 0.f, s2 = 0.f;
    #pragma unroll
    for (int i = 0; i < 4; i++) {
        v[i] = yp[t + i * 256];
        s += v[i]; s2 += v[i] * v[i];
    }
    #pragma unroll
    for (int mk = 1; mk < 64; mk <<= 1) {
        s  += __shfl_xor(s, mk);
        s2 += __shfl_xor(s2, mk);
    }
    __shared__ float ss[4], ss2[4];
    int w = t >> 6;
    if ((t & 63) == 0) { ss[w] = s; ss2[w] = s2; }
    __syncthreads();
    s  = ss[0] + ss[1] + ss[2] + ss[3];
    s2 = ss2[0] + ss2[1] + ss2[2] + ss2[3];
    float mu   = s / D_;
    float var  = s2 / D_ - mu * mu;
    float rstd = rsqrtf(var + EPS_);
    #pragma unroll
    for (int i = 0; i < 4; i++) {
        int c = t + i * 256;
        out[(size_t)row * D_ + c] = (v[i] - mu) * rstd * g[c] + bta[c];
    }
}

// ---------------------------------------------------------------------------
extern "C" void kernel_launch(void* const* d_in, const int* in_sizes, int n_in,
                              void* d_out, int out_size, void* d_ws, size_t ws_size,
                              hipStream_t stream)
{
    const float* x     = (const float*)d_in[0];
    const float* Wq    = (const float*)d_in[1];
    const float* Wk    = (const float*)d_in[2];
    const float* Wv    = (const float*)d_in[3];
    const float* Wo    = (const float*)d_in[4];
    const float* betas = (const float*)d_in[5];
    const float* W1    = (const float*)d_in[6];
    const float* b1    = (const float*)d_in[7];
    const float* W2    = (const float*)d_in[8];
    const float* b2    = (const float*)d_in[9];
    const float* lng   = (const float*)d_in[10];
    const float* lnb   = (const float*)d_in[11];
    float* out = (float*)d_out;

    const int M = B_ * S_;                    // 16384
    char* base = (char*)d_ws;
    const size_t MB = 1024 * 1024;

    bf16*  Xbf = (bf16*)(base);              // 32MB
    bf16*  Qb  = (bf16*)(base + 32 * MB);    // 16MB
    bf16*  Kb  = (bf16*)(base + 48 * MB);
    bf16*  Vb  = (bf16*)(base + 64 * MB);
    bf16*  Vt  = (bf16*)(base + 80 * MB);
    bf16*  ATT = (bf16*)(base + 96 * MB);
    bf16*  Hb  = (bf16*)(base);              // reuse [0,128MB) during FFN
    bf16*  Ab  = (bf16*)(base + 128 * MB);   // 32MB
    bf16*  WqT = (bf16*)(base + 160 * MB);
    bf16*  WkT = (bf16*)(base + 161 * MB);
    bf16*  WvT = (bf16*)(base + 162 * MB);
    bf16*  WoT = (bf16*)(base + 163 * MB);
    bf16*  W1T = (bf16*)(base + 164 * MB);   // 8MB
    bf16*  W2T = (bf16*)(base + 172 * MB);   // 8MB
    float* MP  = (float*)(base + 180 * MB);  // 4MB
    bf16*  MST = (bf16*)(base + 184 * MB);   // 512KB
    float* ZP  = (float*)(base + 185 * MB);
    float* ZS  = (float*)(base + 185 * MB + 256 * 1024);

    dim3 blk(256);

    castx_k<<<dim3((M * D_) / 1024), blk, 0, stream>>>(x, Xbf);
    transcast_k<<<dim3(512 / 32, 1024 / 32), blk, 0, stream>>>(Wq, WqT, 1024, 512);
    transcast_k<<<dim3(512 / 32, 1024 / 32), blk, 0, stream>>>(Wk, WkT, 1024, 512);
    transcast_k<<<dim3(512 / 32, 1024 / 32), blk, 0, stream>>>(Wv, WvT, 1024, 512);
    transcast_k<<<dim3(1024 / 32, 512 / 32), blk, 0, stream>>>(Wo, WoT, 512, 1024);
    transcast_k<<<dim3(4096 / 32, 1024 / 32), blk, 0, stream>>>(W1, W1T, 1024, 4096);
    transcast_k<<<dim3(1024 / 32, 4096 / 32), blk, 0, stream>>>(W2, W2T, 4096, 1024);

    mfma_gemm<0, bf16><<<dim3(512 / 128, M / 128), blk, 0, stream>>>(
        Xbf, WqT, Qb, nullptr, nullptr, M, 512, 1024);
    mfma_gemm<0, bf16><<<dim3(512 / 128, M / 128), blk, 0, stream>>>(
        Xbf, WkT, Kb, nullptr, nullptr, M, 512, 1024);
    mfma_gemm<0, bf16><<<dim3(512 / 128, M / 128), blk, 0, stream>>>(
        Xbf, WvT, Vb, nullptr, nullptr, M, 512, 1024);

    vtrans_k<<<dim3(256, 8), blk, 0, stream>>>(Vb, Vt);

    memseg_k<<<dim3(NSEG_ * 16, 4), blk, 0, stream>>>(Kb, Vb, MP, ZP);
    prefix_k<<<dim3(16), blk, 0, stream>>>(MP, ZP, MST, ZS);

    attn_k<<<dim3(SEG_ / 128, 16, NSEG_), blk, 0, stream>>>(
        Qb, Kb, Vt, MST, ZS, betas, ATT);

    mfma_gemm<0, bf16><<<dim3(1024 / 128, M / 128), blk, 0, stream>>>(
        ATT, WoT, Ab, nullptr, nullptr, M, 1024, 512);
    mfma_gemm<2, bf16><<<dim3(4096 / 128, M / 128), blk, 0, stream>>>(
        Ab, W1T, Hb, b1, nullptr, M, 4096, 1024);
    mfma_gemm<3, float><<<dim3(1024 / 128, M / 128), blk, 0, stream>>>(
        Hb, W2T, out, b2, x, M, 1024, 4096);

    ln_k<<<dim3(M), blk, 0, stream>>>(out, lng, lnb, out);
}

// Round 5
// 714.932 us; speedup vs baseline: 12.0677x; 1.1622x over previous
//
#include <hip/hip_runtime.h>
#include <hip/hip_bf16.h>
#include <math.h>

#define B_    2
#define S_    8192
#define D_    1024
#define H_N   8
#define DK_   64
#define DV_   64
#define DH_   4096
#define SEG_  2048
#define NSEG_ 4
#define EPS_  1e-5f
#define LDQKV 1536

typedef __hip_bfloat16 bf16;
typedef unsigned int u32;
typedef __attribute__((ext_vector_type(8))) short bf16x8;
typedef __attribute__((ext_vector_type(4))) float f32x4;

union bvec { bf16x8 v; bf16 e[8]; };

template <typename T> __device__ inline T from_f(float v);
template <> __device__ inline float from_f<float>(float v) { return v; }
template <> __device__ inline bf16  from_f<bf16>(float v)  { return __float2bfloat16(v); }

__device__ __forceinline__ void gld_lds16(const bf16* g, bf16* l) {
    __builtin_amdgcn_global_load_lds(
        (const __attribute__((address_space(1))) u32*)g,
        (__attribute__((address_space(3))) u32*)l, 16, 0, 0);
}

__device__ inline float elu1(float x) { return x > 0.f ? x + 1.f : __expf(x); }

// ---------------------------------------------------------------------------
// 256x256-tile GEMM, 8 waves, BK=32, 4 LDS buffers, counted vmcnt(4) pipeline.
// C[M,N] = A[M,K] @ BT[N,K]^T.  EPI: 0 none, 2 bias+gelu, 3 bias+residual.
// LDS element (row, chunk c of 8 elems): off = row*32 + 8*(c ^ ((row>>1)&3)).
// Staged with identically pre-swizzled global source chunks (involution).
// ---------------------------------------------------------------------------
template <int EPI, typename CT>
__global__ __launch_bounds__(512, 2) void gemm256(
    const bf16* __restrict__ A, const bf16* __restrict__ BT, CT* __restrict__ C,
    const float* __restrict__ bias, const float* __restrict__ resid,
    int M, int N, int K)
{
    __shared__ bf16 L[4][16384];   // per buffer: A tile [256][32] | B tile [256][32]
    const int t    = threadIdx.x;
    const int lane = t & 63;
    const int w    = t >> 6;          // 8 waves
    const int la   = lane & 15;
    const int g    = lane >> 4;

    // bijective XCD swizzle (all grids have nwg % 8 == 0)
    const int nx  = gridDim.x;
    const int nwg = nx * gridDim.y;
    const int lin = blockIdx.y * nx + blockIdx.x;
    const int swz = (lin & 7) * (nwg >> 3) + (lin >> 3);
    const int by  = swz / nx, bx = swz - by * nx;

    const int m0 = by * 256, n0 = bx * 256;
    const int wm = w >> 2, wn = w & 3;   // wave tile: rows [wm*128,+128), cols [wn*64,+64)

    f32x4 acc[8][4];
    #pragma unroll
    for (int m = 0; m < 8; m++)
        #pragma unroll
        for (int n = 0; n < 4; n++) {
            f32x4 z4 = {0.f, 0.f, 0.f, 0.f};
            acc[m][n] = z4;
        }

    // staging: per wave 4 gld_lds (A rows w*32..+32, B rows w*32..+32; 2 issues each)
    const bf16* Aw = A  + (size_t)(m0 + w * 32) * K;
    const bf16* Bw = BT + (size_t)(n0 + w * 32) * K;
    const int rl = lane >> 2;                          // 0..15 row-in-issue
    const int co = (((lane & 3) ^ ((lane >> 3) & 3))) * 8;  // pre-swizzled chunk

    const int nt = K >> 5;

    auto stage = [&](int kt) {
        const int buf = kt & 3;
        const int k0 = kt << 5;
        #pragma unroll
        for (int i = 0; i < 2; i++) {
            gld_lds16(Aw + (size_t)(i * 16 + rl) * K + k0 + co,
                      &L[buf][(w * 32 + i * 16) * 32]);
            gld_lds16(Bw + (size_t)(i * 16 + rl) * K + k0 + co,
                      &L[buf][8192 + (w * 32 + i * 16) * 32]);
        }
    };

    stage(0);
    stage(1);
    asm volatile("s_waitcnt vmcnt(4)" ::: "memory");
    __builtin_amdgcn_s_barrier();

    for (int kt = 0; kt < nt; kt++) {
        const int buf = kt & 3;
        if (kt + 2 < nt) stage(kt + 2);

        const bf16* Ab_ = &L[buf][0];
        const bf16* Bb_ = &L[buf][8192];
        const int rsw = (la >> 1) & 3;    // (row>>1)&3 for row = 16m + la
        bf16x8 af[8], bg[4];
        #pragma unroll
        for (int m = 0; m < 8; m++) {
            int row = wm * 128 + m * 16 + la;
            af[m] = *(const bf16x8*)&Ab_[row * 32 + 8 * (g ^ rsw)];
        }
        #pragma unroll
        for (int n = 0; n < 4; n++) {
            int row = wn * 64 + n * 16 + la;
            bg[n] = *(const bf16x8*)&Bb_[row * 32 + 8 * (g ^ rsw)];
        }

        __builtin_amdgcn_s_setprio(1);
        #pragma unroll
        for (int m = 0; m < 8; m++)
            #pragma unroll
            for (int n = 0; n < 4; n++)
                acc[m][n] = __builtin_amdgcn_mfma_f32_16x16x32_bf16(
                    af[m], bg[n], acc[m][n], 0, 0, 0);
        __builtin_amdgcn_s_setprio(0);

        if (kt + 1 < nt) {
            if (kt + 2 < nt) asm volatile("s_waitcnt vmcnt(4)" ::: "memory");
            else             asm volatile("s_waitcnt vmcnt(0)" ::: "memory");
            __builtin_amdgcn_sched_barrier(0);
            __builtin_amdgcn_s_barrier();
        }
    }

    // C/D layout: col = lane&15, row = (lane>>4)*4 + reg
    const int row0 = m0 + wm * 128 + g * 4;
    const int col0 = n0 + wn * 64 + la;
    #pragma unroll
    for (int n = 0; n < 4; n++) {
        const int col = col0 + n * 16;
        const float bj = (EPI >= 2) ? bias[col] : 0.f;
        #pragma unroll
        for (int m = 0; m < 8; m++) {
            #pragma unroll
            for (int r = 0; r < 4; r++) {
                const int row = row0 + m * 16 + r;
                float v = acc[m][n][r];
                if (EPI >= 2) v += bj;
                if (EPI == 2) v = 0.5f * v * (1.0f + erff(v * 0.70710678118654752f));
                if (EPI == 3) v += resid[(size_t)row * N + col];
                C[(size_t)row * N + col] = from_f<CT>(v);
            }
        }
    }
}

// ---------------------------------------------------------------------------
// casts
// ---------------------------------------------------------------------------
__global__ __launch_bounds__(256) void castx_k(const float* __restrict__ X,
                                               bf16* __restrict__ Y)
{
    size_t i = ((size_t)blockIdx.x * 256 + threadIdx.x) * 4;
    float4 v = *(const float4*)(X + i);
    union { bf16 b[4]; unsigned long long u; } o;
    o.b[0] = __float2bfloat16(v.x);
    o.b[1] = __float2bfloat16(v.y);
    o.b[2] = __float2bfloat16(v.z);
    o.b[3] = __float2bfloat16(v.w);
    *(unsigned long long*)(Y + i) = o.u;
}

__global__ __launch_bounds__(256) void transcast_k(const float* __restrict__ W,
                                                   bf16* __restrict__ WT, int K, int N)
{
    __shared__ float tile[32][33];
    const int n0 = blockIdx.x * 32, k0 = blockIdx.y * 32;
    const int tx = threadIdx.x & 31, ty = threadIdx.x >> 5;
    #pragma unroll
    for (int i = 0; i < 32; i += 8)
        tile[ty + i][tx] = W[(size_t)(k0 + ty + i) * N + n0 + tx];
    __syncthreads();
    #pragma unroll
    for (int i = 0; i < 32; i += 8)
        WT[(size_t)(n0 + ty + i) * K + k0 + tx] = __float2bfloat16(tile[tx][ty + i]);
}

// V (stride LDQKV) -> Vt [ (b*8+h)*64+dv ][ s ]
__global__ __launch_bounds__(256) void vtrans_k(const bf16* __restrict__ V,
                                                bf16* __restrict__ Vt)
{
    __shared__ bf16 t_[64 * 64];
    const int t = threadIdx.x;
    const int sblk = blockIdx.x & 127;
    const int b = blockIdx.x >> 7;
    const int h = blockIdx.y;
    const bf16* src = V + ((size_t)b * S_ + sblk * 64) * LDQKV + h * 64;
    #pragma unroll
    for (int k = 0; k < 2; k++) {
        int e = t + k * 256;
        int r = e >> 3, c8 = (e & 7) * 8;
        *(bf16x8*)&t_[r * 64 + c8] = *(const bf16x8*)&src[(size_t)r * LDQKV + c8];
    }
    __syncthreads();
    const int dv = t & 63, s0 = (t >> 6) * 16;
    bf16* dst = Vt + ((size_t)(b * 8 + h) * 64 + dv) * (size_t)S_ + sblk * 64 + s0;
    bvec o0, o1;
    #pragma unroll
    for (int i = 0; i < 8; i++) {
        o0.e[i] = t_[(s0 + i) * 64 + dv];
        o1.e[i] = t_[(s0 + 8 + i) * 64 + dv];
    }
    *(bf16x8*)dst = o0.v;
    *(bf16x8*)(dst + 8) = o1.v;
}

// ---------------------------------------------------------------------------
// Per-(segment,chunk) partial memory (bf16 in @ stride LDQKV, f32 accumulate)
// ---------------------------------------------------------------------------
__global__ __launch_bounds__(256) void memseg_k(
    const bf16* __restrict__ Kg, const bf16* __restrict__ Vg,
    float* __restrict__ MP, float* __restrict__ ZP)
{
    __shared__ float Ks[64][65];
    __shared__ float Vs[64][65];
    const int t = threadIdx.x, tx = t & 15, ty = t >> 4;
    const int sb = blockIdx.x;
    const int seg = sb >> 4, bh = sb & 15;
    const int b = bh >> 3, h = bh & 7;
    const int chunk = blockIdx.y;
    const size_t base = ((size_t)b * S_ + (size_t)seg * SEG_ + (size_t)chunk * 512) * LDQKV + h * 64;

    float acc[4][4] = {};
    float zacc[4]   = {};
    for (int st = 0; st < 8; st++) {
        #pragma unroll
        for (int kk = 0; kk < 2; kk++) {
            int e = t + kk * 256;
            int r = e >> 3, c8 = (e & 7) * 8;
            size_t go = base + ((size_t)st * 64 + r) * LDQKV + c8;
            bvec kv_, vv_;
            kv_.v = *(const bf16x8*)&Kg[go];
            vv_.v = *(const bf16x8*)&Vg[go];
            #pragma unroll
            for (int i = 0; i < 8; i++) {
                Ks[r][c8 + i] = elu1(__bfloat162float(kv_.e[i]));
                Vs[r][c8 + i] = __bfloat162float(vv_.e[i]);
            }
        }
        __syncthreads();
        for (int s = 0; s < 64; s++) {
            float a4[4], v4[4];
            #pragma unroll
            for (int i = 0; i < 4; i++) a4[i] = Ks[s][ty * 4 + i];
            #pragma unroll
            for (int j = 0; j < 4; j++) v4[j] = Vs[s][tx * 4 + j];
            #pragma unroll
            for (int i = 0; i < 4; i++)
                #pragma unroll
                for (int j = 0; j < 4; j++)
                    acc[i][j] += a4[i] * v4[j];
        }
        #pragma unroll
        for (int ii = 0; ii < 4; ii++) {
            int s = tx + ii * 16;
            #pragma unroll
            for (int i = 0; i < 4; i++) zacc[i] += Ks[s][ty * 4 + i];
        }
        __syncthreads();
    }
    const int slot = (seg * 4 + chunk) * 16 + bh;
    #pragma unroll
    for (int i = 0; i < 4; i++)
        #pragma unroll
        for (int j = 0; j < 4; j++)
            MP[(size_t)slot * 4096 + (ty * 4 + i) * 64 + tx * 4 + j] = acc[i][j];
    #pragma unroll
    for (int i = 0; i < 4; i++) {
        float zz = zacc[i];
        #pragma unroll
        for (int mk = 1; mk < 16; mk <<= 1) zz += __shfl_xor(zz, mk);
        if (tx == 0) ZP[slot * 64 + ty * 4 + i] = zz;
    }
}

// exclusive prefix -> per-seg start states: MST transposed bf16 [dv][dk], ZS f32
__global__ __launch_bounds__(256) void prefix_k(
    const float* __restrict__ MP, const float* __restrict__ ZP,
    bf16* __restrict__ MST, float* __restrict__ ZS)
{
    const int bh = blockIdx.x, t = threadIdx.x;
    for (int e = t; e < 4096; e += 256) {
        int dk = e >> 6, dv = e & 63;
        float s = 0.f;
        #pragma unroll
        for (int slot = 0; slot < 16; slot++) {
            if ((slot & 3) == 0)
                MST[(size_t)((slot >> 2) * 16 + bh) * 4096 + dv * 64 + dk] = __float2bfloat16(s);
            s += MP[(size_t)(slot * 16 + bh) * 4096 + e];
        }
    }
    if (t < 64) {
        float s = 1.0f / DK_;
        #pragma unroll
        for (int slot = 0; slot < 16; slot++) {
            if ((slot & 3) == 0) ZS[((slot >> 2) * 16 + bh) * 64 + t] = s;
            s += ZP[(slot * 16 + bh) * 64 + t];
        }
    }
}

// ---------------------------------------------------------------------------
// attn helpers: swizzled staging / reads (row stride 128B, XOR (row&7)<<4)
// ---------------------------------------------------------------------------
template <int NG>
__device__ __forceinline__ void stageT(const bf16* gsrc, size_t stride, bf16* lds,
                                       int wave, int lane)
{
    #pragma unroll
    for (int ii = 0; ii < NG; ii++) {
        int i = wave * NG + ii;
        gld_lds16(gsrc + (size_t)(8 * i + (lane >> 3)) * stride
                        + (size_t)(((lane & 7) ^ (lane >> 3)) * 8),
                  lds + i * 512);
    }
}

__device__ __forceinline__ bf16x8 ldsw128(const bf16* base, int row, int colE)
{
    int off = row * 128 + ((colE * 2) ^ ((row & 7) << 4));
    return *(const bf16x8*)((const char*)base + off);
}

// ---------------------------------------------------------------------------
// MFMA flash attention (swapped QK^T, swizzled LDS, double-buffered K/V,
// 1 barrier per kv-tile) + compressive-memory retrieval.
// grid (16 qt [reversed], 16 bh, 4 seg); block 256 = 4 waves x 32 q rows.
// ---------------------------------------------------------------------------
__global__ __launch_bounds__(256) void attn_k(
    const bf16* __restrict__ Qg, const bf16* __restrict__ Kg, const bf16* __restrict__ Vt,
    const bf16* __restrict__ MsT, const float* __restrict__ ZS,
    const float* __restrict__ betas, bf16* __restrict__ att)
{
    __shared__ bf16 KT[2][4096];
    __shared__ bf16 VTs[2][4096];
    __shared__ bf16 QP[8192];       // Q tile 128x64; per-wave rows reused as P
    __shared__ float Zsm[64];

    const int t    = threadIdx.x;
    const int lane = t & 63;
    const int w    = t >> 6;
    const int la   = lane & 15;
    const int g    = lane >> 4;
    const int qt   = (int)gridDim.x - 1 - (int)blockIdx.x;
    const int bh   = blockIdx.y;
    const int seg  = blockIdx.z;
    const int b    = bh >> 3, h = bh & 7;

    const size_t srow = (size_t)b * S_ + (size_t)seg * SEG_;
    const bf16* qp  = Qg + (srow + (size_t)qt * 128) * LDQKV + h * 64;
    const bf16* kp  = Kg + srow * LDQKV + h * 64;
    const bf16* vtp = Vt + (size_t)bh * 64 * (size_t)S_ + (size_t)seg * SEG_;

    stageT<4>(qp, LDQKV, QP, w, lane);
    stageT<2>(kp, LDQKV, KT[0], w, lane);
    stageT<2>(vtp, S_, VTs[0], w, lane);
    if (t < 64) Zsm[t] = ZS[(seg * 16 + bh) * 64 + t];
    __syncthreads();

    bf16x8 aq[2][2];
    #pragma unroll
    for (int st = 0; st < 2; st++)
        #pragma unroll
        for (int s = 0; s < 2; s++)
            aq[st][s] = ldsw128(QP, w * 32 + st * 16 + la, s * 32 + g * 8);

    float m_[2] = {-1e30f, -1e30f};
    float l_[2] = {0.f, 0.f};
    f32x4 Oa[2][4];
    #pragma unroll
    for (int st = 0; st < 2; st++)
        #pragma unroll
        for (int j = 0; j < 4; j++) { f32x4 z4 = {0.f,0.f,0.f,0.f}; Oa[st][j] = z4; }

    const int jtmax = 2 * qt + 1;
    int cur = 0;
    for (int jt = 0; jt <= jtmax; jt++, cur ^= 1) {
        if (jt < jtmax) {
            stageT<2>(kp + (size_t)(jt + 1) * 64 * LDQKV, LDQKV, KT[cur ^ 1], w, lane);
            stageT<2>(vtp + (size_t)(jt + 1) * 64, S_, VTs[cur ^ 1], w, lane);
        }

        bf16x8 kf[2][4];
        #pragma unroll
        for (int s = 0; s < 2; s++)
            #pragma unroll
            for (int j = 0; j < 4; j++)
                kf[s][j] = ldsw128(KT[cur], j * 16 + la, s * 32 + g * 8);

        const int jtkv = jt * 64;
        #pragma unroll
        for (int st = 0; st < 2; st++) {
            f32x4 sc[4];
            #pragma unroll
            for (int j = 0; j < 4; j++) { f32x4 z4 = {0.f,0.f,0.f,0.f}; sc[j] = z4; }
            #pragma unroll
            for (int j = 0; j < 4; j++) {
                sc[j] = __builtin_amdgcn_mfma_f32_16x16x32_bf16(kf[0][j], aq[st][0], sc[j], 0, 0, 0);
                sc[j] = __builtin_amdgcn_mfma_f32_16x16x32_bf16(kf[1][j], aq[st][1], sc[j], 0, 0, 0);
            }

            const int q_abs = qt * 128 + w * 32 + st * 16 + la;
            float sv[4][4];
            float mx = -1e30f;
            #pragma unroll
            for (int j = 0; j < 4; j++)
                #pragma unroll
                for (int r = 0; r < 4; r++) {
                    float v = sc[j][r] * 0.125f;
                    int kv = jtkv + j * 16 + g * 4 + r;
                    v = (kv <= q_abs) ? v : -1e30f;
                    sv[j][r] = v;
                    mx = fmaxf(mx, v);
                }
            mx = fmaxf(mx, __shfl_xor(mx, 16));
            mx = fmaxf(mx, __shfl_xor(mx, 32));
            float mnew = fmaxf(m_[st], mx);
            float corr = __expf(m_[st] - mnew);
            float rs = 0.f;
            #pragma unroll
            for (int j = 0; j < 4; j++)
                #pragma unroll
                for (int r = 0; r < 4; r++) {
                    float p = __expf(sv[j][r] - mnew);
                    sv[j][r] = p;
                    rs += p;
                }
            rs += __shfl_xor(rs, 16);
            rs += __shfl_xor(rs, 32);
            l_[st] = l_[st] * corr + rs;
            m_[st] = mnew;

            const int R = w * 32 + st * 16 + la;
            #pragma unroll
            for (int j = 0; j < 4; j++) {
                union { bf16 e[4]; uint2 u; } pk;
                #pragma unroll
                for (int r = 0; r < 4; r++) pk.e[r] = __float2bfloat16(sv[j][r]);
                int off = R * 128 + ((j * 32 + g * 8) ^ ((la & 7) << 4));
                *(uint2*)((char*)QP + off) = pk.u;
            }

            #pragma unroll
            for (int r = 0; r < 4; r++) {
                float corr_r = __shfl(corr, (lane & 48) | (g * 4 + r));
                #pragma unroll
                for (int j = 0; j < 4; j++) Oa[st][j][r] *= corr_r;
            }
        }

        asm volatile("s_waitcnt lgkmcnt(0)" ::: "memory");
        __builtin_amdgcn_sched_barrier(0);

        bf16x8 bv[2][4];
        #pragma unroll
        for (int s = 0; s < 2; s++)
            #pragma unroll
            for (int j = 0; j < 4; j++)
                bv[s][j] = ldsw128(VTs[cur], j * 16 + la, s * 32 + g * 8);
        #pragma unroll
        for (int st = 0; st < 2; st++) {
            bf16x8 ap0 = ldsw128(QP, w * 32 + st * 16 + la, g * 8);
            bf16x8 ap1 = ldsw128(QP, w * 32 + st * 16 + la, 32 + g * 8);
            #pragma unroll
            for (int j = 0; j < 4; j++) {
                Oa[st][j] = __builtin_amdgcn_mfma_f32_16x16x32_bf16(ap0, bv[0][j], Oa[st][j], 0, 0, 0);
                Oa[st][j] = __builtin_amdgcn_mfma_f32_16x16x32_bf16(ap1, bv[1][j], Oa[st][j], 0, 0, 0);
            }
        }
        __syncthreads();
    }

    // ---- retrieval ----
    stageT<2>(MsT + (size_t)(seg * 16 + bh) * 4096, 64, KT[0], w, lane);
    __syncthreads();

    bf16x8 sq[2][2];
    float den[2] = {0.f, 0.f};
    #pragma unroll
    for (int st = 0; st < 2; st++) {
        #pragma unroll
        for (int s = 0; s < 2; s++) {
            bvec in, outv;
            in.v = aq[st][s];
            #pragma unroll
            for (int e = 0; e < 8; e++) {
                float f = elu1(__bfloat162float(in.e[e]));
                outv.e[e] = __float2bfloat16(f);
                den[st] += f * Zsm[s * 32 + g * 8 + e];
            }
            sq[st][s] = outv.v;
        }
        den[st] += __shfl_xor(den[st], 16);
        den[st] += __shfl_xor(den[st], 32);
    }

    bf16x8 bm[2][4];
    #pragma unroll
    for (int s = 0; s < 2; s++)
        #pragma unroll
        for (int j = 0; j < 4; j++)
            bm[s][j] = ldsw128(KT[0], j * 16 + la, s * 32 + g * 8);

    float gate[4];
    #pragma unroll
    for (int j = 0; j < 4; j++)
        gate[j] = 1.f / (1.f + __expf(-betas[h * 64 + j * 16 + la]));

    #pragma unroll
    for (int st = 0; st < 2; st++) {
        f32x4 num[4];
        #pragma unroll
        for (int j = 0; j < 4; j++) { f32x4 z4 = {0.f,0.f,0.f,0.f}; num[j] = z4; }
        #pragma unroll
        for (int j = 0; j < 4; j++) {
            num[j] = __builtin_amdgcn_mfma_f32_16x16x32_bf16(sq[st][0], bm[0][j], num[j], 0, 0, 0);
            num[j] = __builtin_amdgcn_mfma_f32_16x16x32_bf16(sq[st][1], bm[1][j], num[j], 0, 0, 0);
        }
        #pragma unroll
        for (int r = 0; r < 4; r++) {
            float den_r = __shfl(den[st], (lane & 48) | (g * 4 + r));
            float l_r   = __shfl(l_[st],  (lane & 48) | (g * 4 + r));
            float linv  = 1.f / l_r;
            float dinv  = 1.f / den_r;
            size_t orow = srow + (size_t)qt * 128 + w * 32 + st * 16 + g * 4 + r;
            #pragma unroll
            for (int j = 0; j < 4; j++) {
                float am = num[j][r] * dinv;
                float ad = Oa[st][j][r] * linv;
                att[orow * 512 + h * 64 + j * 16 + la] =
                    __float2bfloat16(gate[j] * am + (1.f - gate[j]) * ad);
            }
        }
    }
}

// ---------------------------------------------------------------------------
// LayerNorm (in-place safe)
// ---------------------------------------------------------------------------
__global__ __launch_bounds__(256) void ln_k(
    const float* __restrict__ Y, const float* __restrict__ g,
    const float* __restrict__ bta, float* __restrict__ out)
{
    const int row = blockIdx.x;
    const float* yp = Y + (size_t)row * D_;
    const int t = threadIdx.x;
    float v[4];
    float s = 0.f, s2 = 0.f;
    #pragma unroll
    for (int i = 0; i < 4; i++) {
        v[i] = yp[t + i * 256];
        s += v[i]; s2 += v[i] * v[i];
    }
    #pragma unroll
    for (int mk = 1; mk < 64; mk <<= 1) {
        s  += __shfl_xor(s, mk);
        s2 += __shfl_xor(s2, mk);
    }
    __shared__ float ss[4], ss2[4];
    int w = t >> 6;
    if ((t & 63) == 0) { ss[w] = s; ss2[w] = s2; }
    __syncthreads();
    s  = ss[0] + ss[1] + ss[2] + ss[3];
    s2 = ss2[0] + ss2[1] + ss2[2] + ss2[3];
    float mu   = s / D_;
    float var  = s2 / D_ - mu * mu;
    float rstd = rsqrtf(var + EPS_);
    #pragma unroll
    for (int i = 0; i < 4; i++) {
        int c = t + i * 256;
        out[(size_t)row * D_ + c] = (v[i] - mu) * rstd * g[c] + bta[c];
    }
}

// ---------------------------------------------------------------------------
extern "C" void kernel_launch(void* const* d_in, const int* in_sizes, int n_in,
                              void* d_out, int out_size, void* d_ws, size_t ws_size,
                              hipStream_t stream)
{
    const float* x     = (const float*)d_in[0];
    const float* Wq    = (const float*)d_in[1];
    const float* Wk    = (const float*)d_in[2];
    const float* Wv    = (const float*)d_in[3];
    const float* Wo    = (const float*)d_in[4];
    const float* betas = (const float*)d_in[5];
    const float* W1    = (const float*)d_in[6];
    const float* b1    = (const float*)d_in[7];
    const float* W2    = (const float*)d_in[8];
    const float* b2    = (const float*)d_in[9];
    const float* lng   = (const float*)d_in[10];
    const float* lnb   = (const float*)d_in[11];
    float* out = (float*)d_out;

    const int M = B_ * S_;                    // 16384
    char* base = (char*)d_ws;
    const size_t MB = 1024 * 1024;

    // [0,32): Ab | [32,160): Hb, aliasing {Xbf 32-64, QKV 64-112, Vt 112-128,
    // ATT 128-144, spare 144-160} | weights/state at 160+
    bf16*  Ab    = (bf16*)(base);
    bf16*  Hb    = (bf16*)(base + 32 * MB);
    bf16*  Xbf   = (bf16*)(base + 32 * MB);
    bf16*  QKV   = (bf16*)(base + 64 * MB);   // [M][1536]
    bf16*  Vt    = (bf16*)(base + 112 * MB);
    bf16*  ATT   = (bf16*)(base + 128 * MB);  // [M][512]
    bf16*  WqkvT = (bf16*)(base + 160 * MB);  // [1536][1024] = 3MB
    bf16*  WoT   = (bf16*)(base + 163 * MB);
    bf16*  W1T   = (bf16*)(base + 164 * MB);  // 8MB
    bf16*  W2T   = (bf16*)(base + 172 * MB);  // 8MB
    float* MP    = (float*)(base + 180 * MB);
    bf16*  MST   = (bf16*)(base + 184 * MB);
    float* ZP    = (float*)(base + 185 * MB);
    float* ZS    = (float*)(base + 185 * MB + 256 * 1024);

    dim3 blk(256);
    dim3 blk512(512);

    castx_k<<<dim3((M * D_) / 1024), blk, 0, stream>>>(x, Xbf);
    transcast_k<<<dim3(512 / 32, 1024 / 32), blk, 0, stream>>>(Wq, WqkvT, 1024, 512);
    transcast_k<<<dim3(512 / 32, 1024 / 32), blk, 0, stream>>>(Wk, WqkvT + 512 * 1024, 1024, 512);
    transcast_k<<<dim3(512 / 32, 1024 / 32), blk, 0, stream>>>(Wv, WqkvT + 1024 * 1024, 1024, 512);
    transcast_k<<<dim3(1024 / 32, 512 / 32), blk, 0, stream>>>(Wo, WoT, 512, 1024);
    transcast_k<<<dim3(4096 / 32, 1024 / 32), blk, 0, stream>>>(W1, W1T, 1024, 4096);
    transcast_k<<<dim3(1024 / 32, 4096 / 32), blk, 0, stream>>>(W2, W2T, 4096, 1024);

    // fused QKV projection: [M][1536]
    gemm256<0, bf16><<<dim3(1536 / 256, M / 256), blk512, 0, stream>>>(
        Xbf, WqkvT, QKV, nullptr, nullptr, M, 1536, 1024);

    vtrans_k<<<dim3(256, 8), blk, 0, stream>>>(QKV + 1024, Vt);

    memseg_k<<<dim3(NSEG_ * 16, 4), blk, 0, stream>>>(QKV + 512, QKV + 1024, MP, ZP);
    prefix_k<<<dim3(16), blk, 0, stream>>>(MP, ZP, MST, ZS);

    attn_k<<<dim3(SEG_ / 128, 16, NSEG_), blk, 0, stream>>>(
        QKV, QKV + 512, Vt, MST, ZS, betas, ATT);

    gemm256<0, bf16><<<dim3(1024 / 256, M / 256), blk512, 0, stream>>>(
        ATT, WoT, Ab, nullptr, nullptr, M, 1024, 512);
    gemm256<2, bf16><<<dim3(4096 / 256, M / 256), blk512, 0, stream>>>(
        Ab, W1T, Hb, b1, nullptr, M, 4096, 1024);
    gemm256<3, float><<<dim3(1024 / 256, M / 256), blk512, 0, stream>>>(
        Hb, W2T, out, b2, x, M, 1024, 4096);

    ln_k<<<dim3(M), blk, 0, stream>>>(out, lng, lnb, out);
}

// Round 6
// 702.430 us; speedup vs baseline: 12.2824x; 1.0178x over previous
//
#include <hip/hip_runtime.h>
#include <hip/hip_bf16.h>
#include <math.h>

#define B_    2
#define S_    8192
#define D_    1024
#define H_N   8
#define DK_   64
#define DV_   64
#define DH_   4096
#define SEG_  2048
#define NSEG_ 4
#define EPS_  1e-5f
#define LDQKV 1536

typedef __hip_bfloat16 bf16;
typedef unsigned int u32;
typedef __attribute__((ext_vector_type(8))) short bf16x8;
typedef __attribute__((ext_vector_type(4))) float f32x4;

union bvec { bf16x8 v; bf16 e[8]; };

template <typename T> __device__ inline T from_f(float v);
template <> __device__ inline float from_f<float>(float v) { return v; }
template <> __device__ inline bf16  from_f<bf16>(float v)  { return __float2bfloat16(v); }

__device__ __forceinline__ void gld_lds16(const bf16* g, bf16* l) {
    __builtin_amdgcn_global_load_lds(
        (const __attribute__((address_space(1))) u32*)g,
        (__attribute__((address_space(3))) u32*)l, 16, 0, 0);
}

__device__ inline float elu1(float x) { return x > 0.f ? x + 1.f : __expf(x); }

// ---------------------------------------------------------------------------
// 256x256-tile GEMM, 8 waves, BK=64, 2 LDS buffers (64KB each), stage-early /
// single vmcnt(0)+barrier per K-tile (T3 minimum-2-phase).  4 MFMA clusters
// of 16 per tile with per-cluster fragment reads.
// LDS element (row, chunk c of 8): byte = row*128 + 16*(c ^ (row&7)); staged
// with identically pre-swizzled global source chunks (involution).
// ---------------------------------------------------------------------------
template <int EPI, typename CT>
__global__ __launch_bounds__(512, 2) void gemm256(
    const bf16* __restrict__ A, const bf16* __restrict__ BT, CT* __restrict__ C,
    const float* __restrict__ bias, const float* __restrict__ resid,
    int M, int N, int K)
{
    __shared__ bf16 L[2][32768];   // per buffer: A [256][64] | B [256][64]
    const int t    = threadIdx.x;
    const int lane = t & 63;
    const int w    = t >> 6;          // 8 waves
    const int la   = lane & 15;
    const int g    = lane >> 4;

    // bijective XCD swizzle (all grids have nwg % 8 == 0)
    const int nx  = gridDim.x;
    const int nwg = nx * gridDim.y;
    const int lin = blockIdx.y * nx + blockIdx.x;
    const int swz = (lin & 7) * (nwg >> 3) + (lin >> 3);
    const int by  = swz / nx, bx = swz - by * nx;

    const int m0 = by * 256, n0 = bx * 256;
    const int wm = w >> 2, wn = w & 3;   // wave tile: rows [wm*128,+128), cols [wn*64,+64)

    f32x4 acc[8][4];
    #pragma unroll
    for (int m = 0; m < 8; m++)
        #pragma unroll
        for (int n = 0; n < 4; n++) {
            f32x4 z4 = {0.f, 0.f, 0.f, 0.f};
            acc[m][n] = z4;
        }

    // staging: wave w covers A rows [w*32,+32) and B rows [w*32,+32), 4+4 loads
    const bf16* Aw = A  + (size_t)(m0 + w * 32) * K;
    const bf16* Bw = BT + (size_t)(n0 + w * 32) * K;
    const int sr = lane >> 3;                 // row within 8-row group
    const int sc = ((lane & 7) ^ sr) * 8;     // pre-swizzled col chunk

    const int nt = K >> 6;

    auto stage = [&](int kt) {
        const int buf = kt & 1;
        const size_t k0 = (size_t)kt << 6;
        #pragma unroll
        for (int i = 0; i < 4; i++) {
            gld_lds16(Aw + (size_t)(i * 8 + sr) * K + k0 + sc,
                      &L[buf][(w * 32 + i * 8) * 64]);
            gld_lds16(Bw + (size_t)(i * 8 + sr) * K + k0 + sc,
                      &L[buf][16384 + (w * 32 + i * 8) * 64]);
        }
    };

    auto rd = [&](const bf16* base, int row, int chunk) -> bf16x8 {
        return *(const bf16x8*)((const char*)base + row * 128 + ((chunk ^ (row & 7)) << 4));
    };

    stage(0);
    asm volatile("s_waitcnt vmcnt(0)" ::: "memory");
    __builtin_amdgcn_sched_barrier(0);
    __builtin_amdgcn_s_barrier();
    __builtin_amdgcn_sched_barrier(0);

    for (int kt = 0; kt < nt; kt++) {
        const bf16* Abuf = &L[kt & 1][0];
        const bf16* Bbuf = &L[kt & 1][16384];
        if (kt + 1 < nt) stage(kt + 1);   // into buf^1: safe, last read ended at t-1's barrier

        #pragma unroll
        for (int ks = 0; ks < 2; ks++) {
            bf16x8 bg[4];
            #pragma unroll
            for (int n = 0; n < 4; n++)
                bg[n] = rd(Bbuf, wn * 64 + n * 16 + la, ks * 4 + g);
            #pragma unroll
            for (int mh = 0; mh < 2; mh++) {
                bf16x8 af[4];
                #pragma unroll
                for (int m = 0; m < 4; m++)
                    af[m] = rd(Abuf, wm * 128 + mh * 64 + m * 16 + la, ks * 4 + g);
                __builtin_amdgcn_s_setprio(1);
                #pragma unroll
                for (int m = 0; m < 4; m++)
                    #pragma unroll
                    for (int n = 0; n < 4; n++)
                        acc[mh * 4 + m][n] = __builtin_amdgcn_mfma_f32_16x16x32_bf16(
                            af[m], bg[n], acc[mh * 4 + m][n], 0, 0, 0);
                __builtin_amdgcn_s_setprio(0);
            }
        }

        if (kt + 1 < nt) {
            asm volatile("s_waitcnt vmcnt(0)" ::: "memory");  // t+1 loads issued ~full tile ago
            __builtin_amdgcn_sched_barrier(0);
            __builtin_amdgcn_s_barrier();
            __builtin_amdgcn_sched_barrier(0);
        }
    }

    // C/D layout: col = lane&15, row = (lane>>4)*4 + reg
    const int row0 = m0 + wm * 128 + g * 4;
    const int col0 = n0 + wn * 64 + la;
    #pragma unroll
    for (int n = 0; n < 4; n++) {
        const int col = col0 + n * 16;
        const float bj = (EPI >= 2) ? bias[col] : 0.f;
        #pragma unroll
        for (int m = 0; m < 8; m++) {
            #pragma unroll
            for (int r = 0; r < 4; r++) {
                const int row = row0 + m * 16 + r;
                float v = acc[m][n][r];
                if (EPI >= 2) v += bj;
                if (EPI == 2) v = 0.5f * v * (1.0f + erff(v * 0.70710678118654752f));
                if (EPI == 3) v += resid[(size_t)row * N + col];
                C[(size_t)row * N + col] = from_f<CT>(v);
            }
        }
    }
}

// ---------------------------------------------------------------------------
// casts
// ---------------------------------------------------------------------------
__global__ __launch_bounds__(256) void castx_k(const float* __restrict__ X,
                                               bf16* __restrict__ Y)
{
    size_t i = ((size_t)blockIdx.x * 256 + threadIdx.x) * 4;
    float4 v = *(const float4*)(X + i);
    union { bf16 b[4]; unsigned long long u; } o;
    o.b[0] = __float2bfloat16(v.x);
    o.b[1] = __float2bfloat16(v.y);
    o.b[2] = __float2bfloat16(v.z);
    o.b[3] = __float2bfloat16(v.w);
    *(unsigned long long*)(Y + i) = o.u;
}

__global__ __launch_bounds__(256) void transcast_k(const float* __restrict__ W,
                                                   bf16* __restrict__ WT, int K, int N)
{
    __shared__ float tile[32][33];
    const int n0 = blockIdx.x * 32, k0 = blockIdx.y * 32;
    const int tx = threadIdx.x & 31, ty = threadIdx.x >> 5;
    #pragma unroll
    for (int i = 0; i < 32; i += 8)
        tile[ty + i][tx] = W[(size_t)(k0 + ty + i) * N + n0 + tx];
    __syncthreads();
    #pragma unroll
    for (int i = 0; i < 32; i += 8)
        WT[(size_t)(n0 + ty + i) * K + k0 + tx] = __float2bfloat16(tile[tx][ty + i]);
}

// V (stride LDQKV) -> Vt [ (b*8+h)*64+dv ][ s ]
__global__ __launch_bounds__(256) void vtrans_k(const bf16* __restrict__ V,
                                                bf16* __restrict__ Vt)
{
    __shared__ bf16 t_[64 * 64];
    const int t = threadIdx.x;
    const int sblk = blockIdx.x & 127;
    const int b = blockIdx.x >> 7;
    const int h = blockIdx.y;
    const bf16* src = V + ((size_t)b * S_ + sblk * 64) * LDQKV + h * 64;
    #pragma unroll
    for (int k = 0; k < 2; k++) {
        int e = t + k * 256;
        int r = e >> 3, c8 = (e & 7) * 8;
        *(bf16x8*)&t_[r * 64 + c8] = *(const bf16x8*)&src[(size_t)r * LDQKV + c8];
    }
    __syncthreads();
    const int dv = t & 63, s0 = (t >> 6) * 16;
    bf16* dst = Vt + ((size_t)(b * 8 + h) * 64 + dv) * (size_t)S_ + sblk * 64 + s0;
    bvec o0, o1;
    #pragma unroll
    for (int i = 0; i < 8; i++) {
        o0.e[i] = t_[(s0 + i) * 64 + dv];
        o1.e[i] = t_[(s0 + 8 + i) * 64 + dv];
    }
    *(bf16x8*)dst = o0.v;
    *(bf16x8*)(dst + 8) = o1.v;
}

// ---------------------------------------------------------------------------
// Per-(segment,chunk) partial memory (bf16 in @ stride LDQKV, f32 accumulate)
// ---------------------------------------------------------------------------
__global__ __launch_bounds__(256) void memseg_k(
    const bf16* __restrict__ Kg, const bf16* __restrict__ Vg,
    float* __restrict__ MP, float* __restrict__ ZP)
{
    __shared__ float Ks[64][65];
    __shared__ float Vs[64][65];
    const int t = threadIdx.x, tx = t & 15, ty = t >> 4;
    const int sb = blockIdx.x;
    const int seg = sb >> 4, bh = sb & 15;
    const int b = bh >> 3, h = bh & 7;
    const int chunk = blockIdx.y;
    const size_t base = ((size_t)b * S_ + (size_t)seg * SEG_ + (size_t)chunk * 512) * LDQKV + h * 64;

    float acc[4][4] = {};
    float zacc[4]   = {};
    for (int st = 0; st < 8; st++) {
        #pragma unroll
        for (int kk = 0; kk < 2; kk++) {
            int e = t + kk * 256;
            int r = e >> 3, c8 = (e & 7) * 8;
            size_t go = base + ((size_t)st * 64 + r) * LDQKV + c8;
            bvec kv_, vv_;
            kv_.v = *(const bf16x8*)&Kg[go];
            vv_.v = *(const bf16x8*)&Vg[go];
            #pragma unroll
            for (int i = 0; i < 8; i++) {
                Ks[r][c8 + i] = elu1(__bfloat162float(kv_.e[i]));
                Vs[r][c8 + i] = __bfloat162float(vv_.e[i]);
            }
        }
        __syncthreads();
        for (int s = 0; s < 64; s++) {
            float a4[4], v4[4];
            #pragma unroll
            for (int i = 0; i < 4; i++) a4[i] = Ks[s][ty * 4 + i];
            #pragma unroll
            for (int j = 0; j < 4; j++) v4[j] = Vs[s][tx * 4 + j];
            #pragma unroll
            for (int i = 0; i < 4; i++)
                #pragma unroll
                for (int j = 0; j < 4; j++)
                    acc[i][j] += a4[i] * v4[j];
        }
        #pragma unroll
        for (int ii = 0; ii < 4; ii++) {
            int s = tx + ii * 16;
            #pragma unroll
            for (int i = 0; i < 4; i++) zacc[i] += Ks[s][ty * 4 + i];
        }
        __syncthreads();
    }
    const int slot = (seg * 4 + chunk) * 16 + bh;
    #pragma unroll
    for (int i = 0; i < 4; i++)
        #pragma unroll
        for (int j = 0; j < 4; j++)
            MP[(size_t)slot * 4096 + (ty * 4 + i) * 64 + tx * 4 + j] = acc[i][j];
    #pragma unroll
    for (int i = 0; i < 4; i++) {
        float zz = zacc[i];
        #pragma unroll
        for (int mk = 1; mk < 16; mk <<= 1) zz += __shfl_xor(zz, mk);
        if (tx == 0) ZP[slot * 64 + ty * 4 + i] = zz;
    }
}

// exclusive prefix -> per-seg start states: MST transposed bf16 [dv][dk], ZS f32
__global__ __launch_bounds__(256) void prefix_k(
    const float* __restrict__ MP, const float* __restrict__ ZP,
    bf16* __restrict__ MST, float* __restrict__ ZS)
{
    const int bh = blockIdx.x, t = threadIdx.x;
    for (int e = t; e < 4096; e += 256) {
        int dk = e >> 6, dv = e & 63;
        float s = 0.f;
        #pragma unroll
        for (int slot = 0; slot < 16; slot++) {
            if ((slot & 3) == 0)
                MST[(size_t)((slot >> 2) * 16 + bh) * 4096 + dv * 64 + dk] = __float2bfloat16(s);
            s += MP[(size_t)(slot * 16 + bh) * 4096 + e];
        }
    }
    if (t < 64) {
        float s = 1.0f / DK_;
        #pragma unroll
        for (int slot = 0; slot < 16; slot++) {
            if ((slot & 3) == 0) ZS[((slot >> 2) * 16 + bh) * 64 + t] = s;
            s += ZP[(slot * 16 + bh) * 64 + t];
        }
    }
}

// ---------------------------------------------------------------------------
// attn helpers: swizzled staging / reads (row stride 128B, XOR (row&7)<<4)
// ---------------------------------------------------------------------------
template <int NG>
__device__ __forceinline__ void stageT(const bf16* gsrc, size_t stride, bf16* lds,
                                       int wave, int lane)
{
    #pragma unroll
    for (int ii = 0; ii < NG; ii++) {
        int i = wave * NG + ii;
        gld_lds16(gsrc + (size_t)(8 * i + (lane >> 3)) * stride
                        + (size_t)(((lane & 7) ^ (lane >> 3)) * 8),
                  lds + i * 512);
    }
}

__device__ __forceinline__ bf16x8 ldsw128(const bf16* base, int row, int colE)
{
    int off = row * 128 + ((colE * 2) ^ ((row & 7) << 4));
    return *(const bf16x8*)((const char*)base + off);
}

// ---------------------------------------------------------------------------
// MFMA flash attention (swapped QK^T, swizzled LDS, double-buffered K/V,
// 1 barrier per kv-tile) + compressive-memory retrieval.
// grid (16 qt [reversed], 16 bh, 4 seg); block 256 = 4 waves x 32 q rows.
// ---------------------------------------------------------------------------
__global__ __launch_bounds__(256) void attn_k(
    const bf16* __restrict__ Qg, const bf16* __restrict__ Kg, const bf16* __restrict__ Vt,
    const bf16* __restrict__ MsT, const float* __restrict__ ZS,
    const float* __restrict__ betas, bf16* __restrict__ att)
{
    __shared__ bf16 KT[2][4096];
    __shared__ bf16 VTs[2][4096];
    __shared__ bf16 QP[8192];       // Q tile 128x64; per-wave rows reused as P
    __shared__ float Zsm[64];

    const int t    = threadIdx.x;
    const int lane = t & 63;
    const int w    = t >> 6;
    const int la   = lane & 15;
    const int g    = lane >> 4;
    const int qt   = (int)gridDim.x - 1 - (int)blockIdx.x;
    const int bh   = blockIdx.y;
    const int seg  = blockIdx.z;
    const int b    = bh >> 3, h = bh & 7;

    const size_t srow = (size_t)b * S_ + (size_t)seg * SEG_;
    const bf16* qp  = Qg + (srow + (size_t)qt * 128) * LDQKV + h * 64;
    const bf16* kp  = Kg + srow * LDQKV + h * 64;
    const bf16* vtp = Vt + (size_t)bh * 64 * (size_t)S_ + (size_t)seg * SEG_;

    stageT<4>(qp, LDQKV, QP, w, lane);
    stageT<2>(kp, LDQKV, KT[0], w, lane);
    stageT<2>(vtp, S_, VTs[0], w, lane);
    if (t < 64) Zsm[t] = ZS[(seg * 16 + bh) * 64 + t];
    __syncthreads();

    bf16x8 aq[2][2];
    #pragma unroll
    for (int st = 0; st < 2; st++)
        #pragma unroll
        for (int s = 0; s < 2; s++)
            aq[st][s] = ldsw128(QP, w * 32 + st * 16 + la, s * 32 + g * 8);

    float m_[2] = {-1e30f, -1e30f};
    float l_[2] = {0.f, 0.f};
    f32x4 Oa[2][4];
    #pragma unroll
    for (int st = 0; st < 2; st++)
        #pragma unroll
        for (int j = 0; j < 4; j++) { f32x4 z4 = {0.f,0.f,0.f,0.f}; Oa[st][j] = z4; }

    const int jtmax = 2 * qt + 1;
    int cur = 0;
    for (int jt = 0; jt <= jtmax; jt++, cur ^= 1) {
        if (jt < jtmax) {
            stageT<2>(kp + (size_t)(jt + 1) * 64 * LDQKV, LDQKV, KT[cur ^ 1], w, lane);
            stageT<2>(vtp + (size_t)(jt + 1) * 64, S_, VTs[cur ^ 1], w, lane);
        }

        bf16x8 kf[2][4];
        #pragma unroll
        for (int s = 0; s < 2; s++)
            #pragma unroll
            for (int j = 0; j < 4; j++)
                kf[s][j] = ldsw128(KT[cur], j * 16 + la, s * 32 + g * 8);

        const int jtkv = jt * 64;
        #pragma unroll
        for (int st = 0; st < 2; st++) {
            f32x4 sc[4];
            #pragma unroll
            for (int j = 0; j < 4; j++) { f32x4 z4 = {0.f,0.f,0.f,0.f}; sc[j] = z4; }
            #pragma unroll
            for (int j = 0; j < 4; j++) {
                sc[j] = __builtin_amdgcn_mfma_f32_16x16x32_bf16(kf[0][j], aq[st][0], sc[j], 0, 0, 0);
                sc[j] = __builtin_amdgcn_mfma_f32_16x16x32_bf16(kf[1][j], aq[st][1], sc[j], 0, 0, 0);
            }

            const int q_abs = qt * 128 + w * 32 + st * 16 + la;
            float sv[4][4];
            float mx = -1e30f;
            #pragma unroll
            for (int j = 0; j < 4; j++)
                #pragma unroll
                for (int r = 0; r < 4; r++) {
                    float v = sc[j][r] * 0.125f;
                    int kv = jtkv + j * 16 + g * 4 + r;
                    v = (kv <= q_abs) ? v : -1e30f;
                    sv[j][r] = v;
                    mx = fmaxf(mx, v);
                }
            mx = fmaxf(mx, __shfl_xor(mx, 16));
            mx = fmaxf(mx, __shfl_xor(mx, 32));
            float mnew = fmaxf(m_[st], mx);
            float corr = __expf(m_[st] - mnew);
            float rs = 0.f;
            #pragma unroll
            for (int j = 0; j < 4; j++)
                #pragma unroll
                for (int r = 0; r < 4; r++) {
                    float p = __expf(sv[j][r] - mnew);
                    sv[j][r] = p;
                    rs += p;
                }
            rs += __shfl_xor(rs, 16);
            rs += __shfl_xor(rs, 32);
            l_[st] = l_[st] * corr + rs;
            m_[st] = mnew;

            const int R = w * 32 + st * 16 + la;
            #pragma unroll
            for (int j = 0; j < 4; j++) {
                union { bf16 e[4]; uint2 u; } pk;
                #pragma unroll
                for (int r = 0; r < 4; r++) pk.e[r] = __float2bfloat16(sv[j][r]);
                int off = R * 128 + ((j * 32 + g * 8) ^ ((la & 7) << 4));
                *(uint2*)((char*)QP + off) = pk.u;
            }

            #pragma unroll
            for (int r = 0; r < 4; r++) {
                float corr_r = __shfl(corr, (lane & 48) | (g * 4 + r));
                #pragma unroll
                for (int j = 0; j < 4; j++) Oa[st][j][r] *= corr_r;
            }
        }

        asm volatile("s_waitcnt lgkmcnt(0)" ::: "memory");
        __builtin_amdgcn_sched_barrier(0);

        bf16x8 bv[2][4];
        #pragma unroll
        for (int s = 0; s < 2; s++)
            #pragma unroll
            for (int j = 0; j < 4; j++)
                bv[s][j] = ldsw128(VTs[cur], j * 16 + la, s * 32 + g * 8);
        #pragma unroll
        for (int st = 0; st < 2; st++) {
            bf16x8 ap0 = ldsw128(QP, w * 32 + st * 16 + la, g * 8);
            bf16x8 ap1 = ldsw128(QP, w * 32 + st * 16 + la, 32 + g * 8);
            #pragma unroll
            for (int j = 0; j < 4; j++) {
                Oa[st][j] = __builtin_amdgcn_mfma_f32_16x16x32_bf16(ap0, bv[0][j], Oa[st][j], 0, 0, 0);
                Oa[st][j] = __builtin_amdgcn_mfma_f32_16x16x32_bf16(ap1, bv[1][j], Oa[st][j], 0, 0, 0);
            }
        }
        __syncthreads();
    }

    // ---- retrieval ----
    stageT<2>(MsT + (size_t)(seg * 16 + bh) * 4096, 64, KT[0], w, lane);
    __syncthreads();

    bf16x8 sq[2][2];
    float den[2] = {0.f, 0.f};
    #pragma unroll
    for (int st = 0; st < 2; st++) {
        #pragma unroll
        for (int s = 0; s < 2; s++) {
            bvec in, outv;
            in.v = aq[st][s];
            #pragma unroll
            for (int e = 0; e < 8; e++) {
                float f = elu1(__bfloat162float(in.e[e]));
                outv.e[e] = __float2bfloat16(f);
                den[st] += f * Zsm[s * 32 + 8 * g + e];
            }
            sq[st][s] = outv.v;
        }
        den[st] += __shfl_xor(den[st], 16);
        den[st] += __shfl_xor(den[st], 32);
    }

    bf16x8 bm[2][4];
    #pragma unroll
    for (int s = 0; s < 2; s++)
        #pragma unroll
        for (int j = 0; j < 4; j++)
            bm[s][j] = ldsw128(KT[0], j * 16 + la, s * 32 + g * 8);

    float gate[4];
    #pragma unroll
    for (int j = 0; j < 4; j++)
        gate[j] = 1.f / (1.f + __expf(-betas[h * 64 + j * 16 + la]));

    #pragma unroll
    for (int st = 0; st < 2; st++) {
        f32x4 num[4];
        #pragma unroll
        for (int j = 0; j < 4; j++) { f32x4 z4 = {0.f,0.f,0.f,0.f}; num[j] = z4; }
        #pragma unroll
        for (int j = 0; j < 4; j++) {
            num[j] = __builtin_amdgcn_mfma_f32_16x16x32_bf16(sq[st][0], bm[0][j], num[j], 0, 0, 0);
            num[j] = __builtin_amdgcn_mfma_f32_16x16x32_bf16(sq[st][1], bm[1][j], num[j], 0, 0, 0);
        }
        #pragma unroll
        for (int r = 0; r < 4; r++) {
            float den_r = __shfl(den[st], (lane & 48) | (g * 4 + r));
            float l_r   = __shfl(l_[st],  (lane & 48) | (g * 4 + r));
            float linv  = 1.f / l_r;
            float dinv  = 1.f / den_r;
            size_t orow = srow + (size_t)qt * 128 + w * 32 + st * 16 + g * 4 + r;
            #pragma unroll
            for (int j = 0; j < 4; j++) {
                float am = num[j][r] * dinv;
                float ad = Oa[st][j][r] * linv;
                att[orow * 512 + h * 64 + j * 16 + la] =
                    __float2bfloat16(gate[j] * am + (1.f - gate[j]) * ad);
            }
        }
    }
}

// ---------------------------------------------------------------------------
// LayerNorm (in-place safe)
// ---------------------------------------------------------------------------
__global__ __launch_bounds__(256) void ln_k(
    const float* __restrict__ Y, const float* __restrict__ g,
    const float* __restrict__ bta, float* __restrict__ out)
{
    const int row = blockIdx.x;
    const float* yp = Y + (size_t)row * D_;
    const int t = threadIdx.x;
    float v[4];
    float s = 0.f, s2 = 0.f;
    #pragma unroll
    for (int i = 0; i < 4; i++) {
        v[i] = yp[t + i * 256];
        s += v[i]; s2 += v[i] * v[i];
    }
    #pragma unroll
    for (int mk = 1; mk < 64; mk <<= 1) {
        s  += __shfl_xor(s, mk);
        s2 += __shfl_xor(s2, mk);
    }
    __shared__ float ss[4], ss2[4];
    int w = t >> 6;
    if ((t & 63) == 0) { ss[w] = s; ss2[w] = s2; }
    __syncthreads();
    s  = ss[0] + ss[1] + ss[2] + ss[3];
    s2 = ss2[0] + ss2[1] + ss2[2] + ss2[3];
    float mu   = s / D_;
    float var  = s2 / D_ - mu * mu;
    float rstd = rsqrtf(var + EPS_);
    #pragma unroll
    for (int i = 0; i < 4; i++) {
        int c = t + i * 256;
        out[(size_t)row * D_ + c] = (v[i] - mu) * rstd * g[c] + bta[c];
    }
}

// ---------------------------------------------------------------------------
extern "C" void kernel_launch(void* const* d_in, const int* in_sizes, int n_in,
                              void* d_out, int out_size, void* d_ws, size_t ws_size,
                              hipStream_t stream)
{
    const float* x     = (const float*)d_in[0];
    const float* Wq    = (const float*)d_in[1];
    const float* Wk    = (const float*)d_in[2];
    const float* Wv    = (const float*)d_in[3];
    const float* Wo    = (const float*)d_in[4];
    const float* betas = (const float*)d_in[5];
    const float* W1    = (const float*)d_in[6];
    const float* b1    = (const float*)d_in[7];
    const float* W2    = (const float*)d_in[8];
    const float* b2    = (const float*)d_in[9];
    const float* lng   = (const float*)d_in[10];
    const float* lnb   = (const float*)d_in[11];
    float* out = (float*)d_out;

    const int M = B_ * S_;                    // 16384
    char* base = (char*)d_ws;
    const size_t MB = 1024 * 1024;

    bf16*  Ab    = (bf16*)(base);
    bf16*  Hb    = (bf16*)(base + 32 * MB);
    bf16*  Xbf   = (bf16*)(base + 32 * MB);
    bf16*  QKV   = (bf16*)(base + 64 * MB);   // [M][1536]
    bf16*  Vt    = (bf16*)(base + 112 * MB);
    bf16*  ATT   = (bf16*)(base + 128 * MB);  // [M][512]
    bf16*  WqkvT = (bf16*)(base + 160 * MB);  // [1536][1024] = 3MB
    bf16*  WoT   = (bf16*)(base + 163 * MB);
    bf16*  W1T   = (bf16*)(base + 164 * MB);  // 8MB
    bf16*  W2T   = (bf16*)(base + 172 * MB);  // 8MB
    float* MP    = (float*)(base + 180 * MB);
    bf16*  MST   = (bf16*)(base + 184 * MB);
    float* ZP    = (float*)(base + 185 * MB);
    float* ZS    = (float*)(base + 185 * MB + 256 * 1024);

    dim3 blk(256);
    dim3 blk512(512);

    castx_k<<<dim3((M * D_) / 1024), blk, 0, stream>>>(x, Xbf);
    transcast_k<<<dim3(512 / 32, 1024 / 32), blk, 0, stream>>>(Wq, WqkvT, 1024, 512);
    transcast_k<<<dim3(512 / 32, 1024 / 32), blk, 0, stream>>>(Wk, WqkvT + 512 * 1024, 1024, 512);
    transcast_k<<<dim3(512 / 32, 1024 / 32), blk, 0, stream>>>(Wv, WqkvT + 1024 * 1024, 1024, 512);
    transcast_k<<<dim3(1024 / 32, 512 / 32), blk, 0, stream>>>(Wo, WoT, 512, 1024);
    transcast_k<<<dim3(4096 / 32, 1024 / 32), blk, 0, stream>>>(W1, W1T, 1024, 4096);
    transcast_k<<<dim3(1024 / 32, 4096 / 32), blk, 0, stream>>>(W2, W2T, 4096, 1024);

    // fused QKV projection: [M][1536]
    gemm256<0, bf16><<<dim3(1536 / 256, M / 256), blk512, 0, stream>>>(
        Xbf, WqkvT, QKV, nullptr, nullptr, M, 1536, 1024);

    vtrans_k<<<dim3(256, 8), blk, 0, stream>>>(QKV + 1024, Vt);

    memseg_k<<<dim3(NSEG_ * 16, 4), blk, 0, stream>>>(QKV + 512, QKV + 1024, MP, ZP);
    prefix_k<<<dim3(16), blk, 0, stream>>>(MP, ZP, MST, ZS);

    attn_k<<<dim3(SEG_ / 128, 16, NSEG_), blk, 0, stream>>>(
        QKV, QKV + 512, Vt, MST, ZS, betas, ATT);

    gemm256<0, bf16><<<dim3(1024 / 256, M / 256), blk512, 0, stream>>>(
        ATT, WoT, Ab, nullptr, nullptr, M, 1024, 512);
    gemm256<2, bf16><<<dim3(4096 / 256, M / 256), blk512, 0, stream>>>(
        Ab, W1T, Hb, b1, nullptr, M, 4096, 1024);
    gemm256<3, float><<<dim3(1024 / 256, M / 256), blk512, 0, stream>>>(
        Hb, W2T, out, b2, x, M, 1024, 4096);

    ln_k<<<dim3(M), blk, 0, stream>>>(out, lng, lnb, out);
}

// Round 7
// 701.136 us; speedup vs baseline: 12.3051x; 1.0018x over previous
//
#include <hip/hip_runtime.h>
#include <hip/hip_bf16.h>
#include <math.h>

#define B_    2
#define S_    8192
#define D_    1024
#define H_N   8
#define DK_   64
#define DV_   64
#define DH_   4096
#define SEG_  2048
#define NSEG_ 4
#define EPS_  1e-5f
#define LDQKV 1536

typedef __hip_bfloat16 bf16;
typedef unsigned int u32;
typedef __attribute__((ext_vector_type(8))) short bf16x8;
typedef __attribute__((ext_vector_type(4))) float f32x4;

union bvec { bf16x8 v; bf16 e[8]; };

template <typename T> __device__ inline T from_f(float v);
template <> __device__ inline float from_f<float>(float v) { return v; }
template <> __device__ inline bf16  from_f<bf16>(float v)  { return __float2bfloat16(v); }

__device__ __forceinline__ void gld_lds16(const bf16* g, bf16* l) {
    __builtin_amdgcn_global_load_lds(
        (const __attribute__((address_space(1))) u32*)g,
        (__attribute__((address_space(3))) u32*)l, 16, 0, 0);
}

__device__ inline float elu1(float x) { return x > 0.f ? x + 1.f : __expf(x); }

// ---------------------------------------------------------------------------
// 256x256-tile GEMM, 8 waves, BK=64, 2 LDS buffers, 4-phase-per-tile schedule
// (T3+T4+T5): each phase = {ds_read quadrant frags | stage 1/4 of next tile |
// barrier | lgkmcnt(0) | setprio(1) 16xMFMA setprio(0) | barrier}; vmcnt(0)
// once per tile at phase 3.  LDS rows 128B, chunk swizzle c^(row&7) staged
// via pre-swizzled global source (involution).
// ---------------------------------------------------------------------------
template <int EPI, typename CT>
__global__ __launch_bounds__(512, 1) void gemm256(
    const bf16* __restrict__ A, const bf16* __restrict__ BT, CT* __restrict__ C,
    const float* __restrict__ bias, const float* __restrict__ resid,
    int M, int N, int K)
{
    __shared__ bf16 L[2][32768];   // per buffer: A [256][64] | B [256][64]
    const int t    = threadIdx.x;
    const int lane = t & 63;
    const int w    = t >> 6;          // 8 waves
    const int la   = lane & 15;
    const int g    = lane >> 4;

    // bijective XCD swizzle (all grids have nwg % 8 == 0)
    const int nx  = gridDim.x;
    const int nwg = nx * gridDim.y;
    const int lin = blockIdx.y * nx + blockIdx.x;
    const int swz = (lin & 7) * (nwg >> 3) + (lin >> 3);
    const int by  = swz / nx, bx = swz - by * nx;

    const int m0 = by * 256, n0 = bx * 256;
    const int wm = w >> 2, wn = w & 3;   // wave tile: rows [wm*128,+128), cols [wn*64,+64)

    f32x4 acc[8][4];
    #pragma unroll
    for (int m = 0; m < 8; m++)
        #pragma unroll
        for (int n = 0; n < 4; n++) {
            f32x4 z4 = {0.f, 0.f, 0.f, 0.f};
            acc[m][n] = z4;
        }

    const int nt = K >> 6;

    // stage quarter q (A rows q*64..+64, B rows q*64..+64) of tile kt_
    auto stageQ = [&](int kt_, int q) {
        const int buf = kt_ & 1;
        const size_t k0 = (size_t)kt_ << 6;
        const int rq = w * 8 + (lane >> 3);
        const int c8 = ((lane & 7) ^ (lane >> 3)) * 8;
        gld_lds16(A  + (size_t)(m0 + q * 64 + rq) * K + k0 + c8,
                  &L[buf][q * 4096 + w * 512]);
        gld_lds16(BT + (size_t)(n0 + q * 64 + rq) * K + k0 + c8,
                  &L[buf][16384 + q * 4096 + w * 512]);
    };

    stageQ(0, 0); stageQ(0, 1); stageQ(0, 2); stageQ(0, 3);
    asm volatile("s_waitcnt vmcnt(0)" ::: "memory");
    __builtin_amdgcn_sched_barrier(0);
    __builtin_amdgcn_s_barrier();
    __builtin_amdgcn_sched_barrier(0);

    for (int kt = 0; kt < nt; kt++) {
        const bf16* Ab_ = &L[kt & 1][0];
        const bf16* Bb_ = &L[kt & 1][16384];
        const bool pre = (kt + 1 < nt);
        bf16x8 af[4], bg[4];

        auto rdA = [&](int m, int ks) -> bf16x8 {
            int row = wm * 128 + m * 16 + la;
            return *(const bf16x8*)((const char*)Ab_ + row * 128
                                    + (((ks * 4 + g) ^ (row & 7)) << 4));
        };
        auto rdB = [&](int n, int ks) -> bf16x8 {
            int row = wn * 64 + n * 16 + la;
            return *(const bf16x8*)((const char*)Bb_ + row * 128
                                    + (((ks * 4 + g) ^ (row & 7)) << 4));
        };

        // ---- phase 0: m0-3 x ks0 (reads bg ks0)
        #pragma unroll
        for (int n = 0; n < 4; n++) bg[n] = rdB(n, 0);
        #pragma unroll
        for (int m = 0; m < 4; m++) af[m] = rdA(m, 0);
        if (pre) stageQ(kt + 1, 0);
        __builtin_amdgcn_s_barrier();
        asm volatile("s_waitcnt lgkmcnt(0)" ::: "memory");
        __builtin_amdgcn_sched_barrier(0);
        __builtin_amdgcn_s_setprio(1);
        #pragma unroll
        for (int m = 0; m < 4; m++)
            #pragma unroll
            for (int n = 0; n < 4; n++)
                acc[m][n] = __builtin_amdgcn_mfma_f32_16x16x32_bf16(
                    af[m], bg[n], acc[m][n], 0, 0, 0);
        __builtin_amdgcn_s_setprio(0);
        __builtin_amdgcn_s_barrier();

        // ---- phase 1: m4-7 x ks0 (bg kept)
        #pragma unroll
        for (int m = 0; m < 4; m++) af[m] = rdA(4 + m, 0);
        if (pre) stageQ(kt + 1, 1);
        __builtin_amdgcn_s_barrier();
        asm volatile("s_waitcnt lgkmcnt(0)" ::: "memory");
        __builtin_amdgcn_sched_barrier(0);
        __builtin_amdgcn_s_setprio(1);
        #pragma unroll
        for (int m = 0; m < 4; m++)
            #pragma unroll
            for (int n = 0; n < 4; n++)
                acc[4 + m][n] = __builtin_amdgcn_mfma_f32_16x16x32_bf16(
                    af[m], bg[n], acc[4 + m][n], 0, 0, 0);
        __builtin_amdgcn_s_setprio(0);
        __builtin_amdgcn_s_barrier();

        // ---- phase 2: m0-3 x ks1 (reads bg ks1)
        #pragma unroll
        for (int n = 0; n < 4; n++) bg[n] = rdB(n, 1);
        #pragma unroll
        for (int m = 0; m < 4; m++) af[m] = rdA(m, 1);
        if (pre) stageQ(kt + 1, 2);
        __builtin_amdgcn_s_barrier();
        asm volatile("s_waitcnt lgkmcnt(0)" ::: "memory");
        __builtin_amdgcn_sched_barrier(0);
        __builtin_amdgcn_s_setprio(1);
        #pragma unroll
        for (int m = 0; m < 4; m++)
            #pragma unroll
            for (int n = 0; n < 4; n++)
                acc[m][n] = __builtin_amdgcn_mfma_f32_16x16x32_bf16(
                    af[m], bg[n], acc[m][n], 0, 0, 0);
        __builtin_amdgcn_s_setprio(0);
        __builtin_amdgcn_s_barrier();

        // ---- phase 3: m4-7 x ks1; tile-boundary vmcnt after MFMA
        #pragma unroll
        for (int m = 0; m < 4; m++) af[m] = rdA(4 + m, 1);
        if (pre) stageQ(kt + 1, 3);
        __builtin_amdgcn_s_barrier();
        asm volatile("s_waitcnt lgkmcnt(0)" ::: "memory");
        __builtin_amdgcn_sched_barrier(0);
        __builtin_amdgcn_s_setprio(1);
        #pragma unroll
        for (int m = 0; m < 4; m++)
            #pragma unroll
            for (int n = 0; n < 4; n++)
                acc[4 + m][n] = __builtin_amdgcn_mfma_f32_16x16x32_bf16(
                    af[m], bg[n], acc[4 + m][n], 0, 0, 0);
        __builtin_amdgcn_s_setprio(0);
        if (pre) asm volatile("s_waitcnt vmcnt(0)" ::: "memory");
        __builtin_amdgcn_sched_barrier(0);
        __builtin_amdgcn_s_barrier();
        __builtin_amdgcn_sched_barrier(0);
    }

    // C/D layout: col = lane&15, row = (lane>>4)*4 + reg
    // line-friendly store order: the 4 n-chunks of a 128B row line back-to-back
    const int row0 = m0 + wm * 128 + g * 4;
    const int col0 = n0 + wn * 64 + la;
    float bj[4];
    if (EPI >= 2) {
        #pragma unroll
        for (int n = 0; n < 4; n++) bj[n] = bias[col0 + n * 16];
    }
    #pragma unroll
    for (int m = 0; m < 8; m++) {
        #pragma unroll
        for (int r = 0; r < 4; r++) {
            const int row = row0 + m * 16 + r;
            #pragma unroll
            for (int n = 0; n < 4; n++) {
                const int col = col0 + n * 16;
                float v = acc[m][n][r];
                if (EPI >= 2) v += bj[n];
                if (EPI == 2) v = 0.5f * v * (1.0f + erff(v * 0.70710678118654752f));
                if (EPI == 3) v += resid[(size_t)row * N + col];
                C[(size_t)row * N + col] = from_f<CT>(v);
            }
        }
    }
}

// ---------------------------------------------------------------------------
// casts
// ---------------------------------------------------------------------------
__global__ __launch_bounds__(256) void castx_k(const float* __restrict__ X,
                                               bf16* __restrict__ Y)
{
    size_t i = ((size_t)blockIdx.x * 256 + threadIdx.x) * 4;
    float4 v = *(const float4*)(X + i);
    union { bf16 b[4]; unsigned long long u; } o;
    o.b[0] = __float2bfloat16(v.x);
    o.b[1] = __float2bfloat16(v.y);
    o.b[2] = __float2bfloat16(v.z);
    o.b[3] = __float2bfloat16(v.w);
    *(unsigned long long*)(Y + i) = o.u;
}

__global__ __launch_bounds__(256) void transcast_k(const float* __restrict__ W,
                                                   bf16* __restrict__ WT, int K, int N)
{
    __shared__ float tile[32][33];
    const int n0 = blockIdx.x * 32, k0 = blockIdx.y * 32;
    const int tx = threadIdx.x & 31, ty = threadIdx.x >> 5;
    #pragma unroll
    for (int i = 0; i < 32; i += 8)
        tile[ty + i][tx] = W[(size_t)(k0 + ty + i) * N + n0 + tx];
    __syncthreads();
    #pragma unroll
    for (int i = 0; i < 32; i += 8)
        WT[(size_t)(n0 + ty + i) * K + k0 + tx] = __float2bfloat16(tile[tx][ty + i]);
}

// V (stride LDQKV) -> Vt [ (b*8+h)*64+dv ][ s ]
__global__ __launch_bounds__(256) void vtrans_k(const bf16* __restrict__ V,
                                                bf16* __restrict__ Vt)
{
    __shared__ bf16 t_[64 * 64];
    const int t = threadIdx.x;
    const int sblk = blockIdx.x & 127;
    const int b = blockIdx.x >> 7;
    const int h = blockIdx.y;
    const bf16* src = V + ((size_t)b * S_ + sblk * 64) * LDQKV + h * 64;
    #pragma unroll
    for (int k = 0; k < 2; k++) {
        int e = t + k * 256;
        int r = e >> 3, c8 = (e & 7) * 8;
        *(bf16x8*)&t_[r * 64 + c8] = *(const bf16x8*)&src[(size_t)r * LDQKV + c8];
    }
    __syncthreads();
    const int dv = t & 63, s0 = (t >> 6) * 16;
    bf16* dst = Vt + ((size_t)(b * 8 + h) * 64 + dv) * (size_t)S_ + sblk * 64 + s0;
    bvec o0, o1;
    #pragma unroll
    for (int i = 0; i < 8; i++) {
        o0.e[i] = t_[(s0 + i) * 64 + dv];
        o1.e[i] = t_[(s0 + 8 + i) * 64 + dv];
    }
    *(bf16x8*)dst = o0.v;
    *(bf16x8*)(dst + 8) = o1.v;
}

// ---------------------------------------------------------------------------
// Per-(segment,chunk) partial memory (bf16 in @ stride LDQKV, f32 accumulate)
// ---------------------------------------------------------------------------
__global__ __launch_bounds__(256) void memseg_k(
    const bf16* __restrict__ Kg, const bf16* __restrict__ Vg,
    float* __restrict__ MP, float* __restrict__ ZP)
{
    __shared__ float Ks[64][65];
    __shared__ float Vs[64][65];
    const int t = threadIdx.x, tx = t & 15, ty = t >> 4;
    const int sb = blockIdx.x;
    const int seg = sb >> 4, bh = sb & 15;
    const int b = bh >> 3, h = bh & 7;
    const int chunk = blockIdx.y;
    const size_t base = ((size_t)b * S_ + (size_t)seg * SEG_ + (size_t)chunk * 512) * LDQKV + h * 64;

    float acc[4][4] = {};
    float zacc[4]   = {};
    for (int st = 0; st < 8; st++) {
        #pragma unroll
        for (int kk = 0; kk < 2; kk++) {
            int e = t + kk * 256;
            int r = e >> 3, c8 = (e & 7) * 8;
            size_t go = base + ((size_t)st * 64 + r) * LDQKV + c8;
            bvec kv_, vv_;
            kv_.v = *(const bf16x8*)&Kg[go];
            vv_.v = *(const bf16x8*)&Vg[go];
            #pragma unroll
            for (int i = 0; i < 8; i++) {
                Ks[r][c8 + i] = elu1(__bfloat162float(kv_.e[i]));
                Vs[r][c8 + i] = __bfloat162float(vv_.e[i]);
            }
        }
        __syncthreads();
        for (int s = 0; s < 64; s++) {
            float a4[4], v4[4];
            #pragma unroll
            for (int i = 0; i < 4; i++) a4[i] = Ks[s][ty * 4 + i];
            #pragma unroll
            for (int j = 0; j < 4; j++) v4[j] = Vs[s][tx * 4 + j];
            #pragma unroll
            for (int i = 0; i < 4; i++)
                #pragma unroll
                for (int j = 0; j < 4; j++)
                    acc[i][j] += a4[i] * v4[j];
        }
        #pragma unroll
        for (int ii = 0; ii < 4; ii++) {
            int s = tx + ii * 16;
            #pragma unroll
            for (int i = 0; i < 4; i++) zacc[i] += Ks[s][ty * 4 + i];
        }
        __syncthreads();
    }
    const int slot = (seg * 4 + chunk) * 16 + bh;
    #pragma unroll
    for (int i = 0; i < 4; i++)
        #pragma unroll
        for (int j = 0; j < 4; j++)
            MP[(size_t)slot * 4096 + (ty * 4 + i) * 64 + tx * 4 + j] = acc[i][j];
    #pragma unroll
    for (int i = 0; i < 4; i++) {
        float zz = zacc[i];
        #pragma unroll
        for (int mk = 1; mk < 16; mk <<= 1) zz += __shfl_xor(zz, mk);
        if (tx == 0) ZP[slot * 64 + ty * 4 + i] = zz;
    }
}

// exclusive prefix -> per-seg start states: MST transposed bf16 [dv][dk], ZS f32
__global__ __launch_bounds__(256) void prefix_k(
    const float* __restrict__ MP, const float* __restrict__ ZP,
    bf16* __restrict__ MST, float* __restrict__ ZS)
{
    const int bh = blockIdx.x, t = threadIdx.x;
    for (int e = t; e < 4096; e += 256) {
        int dk = e >> 6, dv = e & 63;
        float s = 0.f;
        #pragma unroll
        for (int slot = 0; slot < 16; slot++) {
            if ((slot & 3) == 0)
                MST[(size_t)((slot >> 2) * 16 + bh) * 4096 + dv * 64 + dk] = __float2bfloat16(s);
            s += MP[(size_t)(slot * 16 + bh) * 4096 + e];
        }
    }
    if (t < 64) {
        float s = 1.0f / DK_;
        #pragma unroll
        for (int slot = 0; slot < 16; slot++) {
            if ((slot & 3) == 0) ZS[((slot >> 2) * 16 + bh) * 64 + t] = s;
            s += ZP[(slot * 16 + bh) * 64 + t];
        }
    }
}

// ---------------------------------------------------------------------------
// attn helpers: swizzled staging / reads (row stride 128B, XOR (row&7)<<4)
// ---------------------------------------------------------------------------
template <int NG>
__device__ __forceinline__ void stageT(const bf16* gsrc, size_t stride, bf16* lds,
                                       int wave, int lane)
{
    #pragma unroll
    for (int ii = 0; ii < NG; ii++) {
        int i = wave * NG + ii;
        gld_lds16(gsrc + (size_t)(8 * i + (lane >> 3)) * stride
                        + (size_t)(((lane & 7) ^ (lane >> 3)) * 8),
                  lds + i * 512);
    }
}

__device__ __forceinline__ bf16x8 ldsw128(const bf16* base, int row, int colE)
{
    int off = row * 128 + ((colE * 2) ^ ((row & 7) << 4));
    return *(const bf16x8*)((const char*)base + off);
}

// ---------------------------------------------------------------------------
// MFMA flash attention (swapped QK^T, swizzled LDS, double-buffered K/V,
// 1 barrier per kv-tile) + compressive-memory retrieval.
// grid (16 qt [reversed], 16 bh, 4 seg); block 256 = 4 waves x 32 q rows.
// ---------------------------------------------------------------------------
__global__ __launch_bounds__(256) void attn_k(
    const bf16* __restrict__ Qg, const bf16* __restrict__ Kg, const bf16* __restrict__ Vt,
    const bf16* __restrict__ MsT, const float* __restrict__ ZS,
    const float* __restrict__ betas, bf16* __restrict__ att)
{
    __shared__ bf16 KT[2][4096];
    __shared__ bf16 VTs[2][4096];
    __shared__ bf16 QP[8192];       // Q tile 128x64; per-wave rows reused as P
    __shared__ float Zsm[64];

    const int t    = threadIdx.x;
    const int lane = t & 63;
    const int w    = t >> 6;
    const int la   = lane & 15;
    const int g    = lane >> 4;
    const int qt   = (int)gridDim.x - 1 - (int)blockIdx.x;
    const int bh   = blockIdx.y;
    const int seg  = blockIdx.z;
    const int b    = bh >> 3, h = bh & 7;

    const size_t srow = (size_t)b * S_ + (size_t)seg * SEG_;
    const bf16* qp  = Qg + (srow + (size_t)qt * 128) * LDQKV + h * 64;
    const bf16* kp  = Kg + srow * LDQKV + h * 64;
    const bf16* vtp = Vt + (size_t)bh * 64 * (size_t)S_ + (size_t)seg * SEG_;

    stageT<4>(qp, LDQKV, QP, w, lane);
    stageT<2>(kp, LDQKV, KT[0], w, lane);
    stageT<2>(vtp, S_, VTs[0], w, lane);
    if (t < 64) Zsm[t] = ZS[(seg * 16 + bh) * 64 + t];
    __syncthreads();

    bf16x8 aq[2][2];
    #pragma unroll
    for (int st = 0; st < 2; st++)
        #pragma unroll
        for (int s = 0; s < 2; s++)
            aq[st][s] = ldsw128(QP, w * 32 + st * 16 + la, s * 32 + g * 8);

    float m_[2] = {-1e30f, -1e30f};
    float l_[2] = {0.f, 0.f};
    f32x4 Oa[2][4];
    #pragma unroll
    for (int st = 0; st < 2; st++)
        #pragma unroll
        for (int j = 0; j < 4; j++) { f32x4 z4 = {0.f,0.f,0.f,0.f}; Oa[st][j] = z4; }

    const int jtmax = 2 * qt + 1;
    int cur = 0;
    for (int jt = 0; jt <= jtmax; jt++, cur ^= 1) {
        if (jt < jtmax) {
            stageT<2>(kp + (size_t)(jt + 1) * 64 * LDQKV, LDQKV, KT[cur ^ 1], w, lane);
            stageT<2>(vtp + (size_t)(jt + 1) * 64, S_, VTs[cur ^ 1], w, lane);
        }

        bf16x8 kf[2][4];
        #pragma unroll
        for (int s = 0; s < 2; s++)
            #pragma unroll
            for (int j = 0; j < 4; j++)
                kf[s][j] = ldsw128(KT[cur], j * 16 + la, s * 32 + g * 8);

        const int jtkv = jt * 64;
        #pragma unroll
        for (int st = 0; st < 2; st++) {
            f32x4 sc[4];
            #pragma unroll
            for (int j = 0; j < 4; j++) { f32x4 z4 = {0.f,0.f,0.f,0.f}; sc[j] = z4; }
            #pragma unroll
            for (int j = 0; j < 4; j++) {
                sc[j] = __builtin_amdgcn_mfma_f32_16x16x32_bf16(kf[0][j], aq[st][0], sc[j], 0, 0, 0);
                sc[j] = __builtin_amdgcn_mfma_f32_16x16x32_bf16(kf[1][j], aq[st][1], sc[j], 0, 0, 0);
            }

            const int q_abs = qt * 128 + w * 32 + st * 16 + la;
            float sv[4][4];
            float mx = -1e30f;
            #pragma unroll
            for (int j = 0; j < 4; j++)
                #pragma unroll
                for (int r = 0; r < 4; r++) {
                    float v = sc[j][r] * 0.125f;
                    int kv = jtkv + j * 16 + g * 4 + r;
                    v = (kv <= q_abs) ? v : -1e30f;
                    sv[j][r] = v;
                    mx = fmaxf(mx, v);
                }
            mx = fmaxf(mx, __shfl_xor(mx, 16));
            mx = fmaxf(mx, __shfl_xor(mx, 32));
            float mnew = fmaxf(m_[st], mx);
            float corr = __expf(m_[st] - mnew);
            float rs = 0.f;
            #pragma unroll
            for (int j = 0; j < 4; j++)
                #pragma unroll
                for (int r = 0; r < 4; r++) {
                    float p = __expf(sv[j][r] - mnew);
                    sv[j][r] = p;
                    rs += p;
                }
            rs += __shfl_xor(rs, 16);
            rs += __shfl_xor(rs, 32);
            l_[st] = l_[st] * corr + rs;
            m_[st] = mnew;

            const int R = w * 32 + st * 16 + la;
            #pragma unroll
            for (int j = 0; j < 4; j++) {
                union { bf16 e[4]; uint2 u; } pk;
                #pragma unroll
                for (int r = 0; r < 4; r++) pk.e[r] = __float2bfloat16(sv[j][r]);
                int off = R * 128 + ((j * 32 + g * 8) ^ ((la & 7) << 4));
                *(uint2*)((char*)QP + off) = pk.u;
            }

            #pragma unroll
            for (int r = 0; r < 4; r++) {
                float corr_r = __shfl(corr, (lane & 48) | (g * 4 + r));
                #pragma unroll
                for (int j = 0; j < 4; j++) Oa[st][j][r] *= corr_r;
            }
        }

        asm volatile("s_waitcnt lgkmcnt(0)" ::: "memory");
        __builtin_amdgcn_sched_barrier(0);

        bf16x8 bv[2][4];
        #pragma unroll
        for (int s = 0; s < 2; s++)
            #pragma unroll
            for (int j = 0; j < 4; j++)
                bv[s][j] = ldsw128(VTs[cur], j * 16 + la, s * 32 + g * 8);
        #pragma unroll
        for (int st = 0; st < 2; st++) {
            bf16x8 ap0 = ldsw128(QP, w * 32 + st * 16 + la, g * 8);
            bf16x8 ap1 = ldsw128(QP, w * 32 + st * 16 + la, 32 + g * 8);
            #pragma unroll
            for (int j = 0; j < 4; j++) {
                Oa[st][j] = __builtin_amdgcn_mfma_f32_16x16x32_bf16(ap0, bv[0][j], Oa[st][j], 0, 0, 0);
                Oa[st][j] = __builtin_amdgcn_mfma_f32_16x16x32_bf16(ap1, bv[1][j], Oa[st][j], 0, 0, 0);
            }
        }
        __syncthreads();
    }

    // ---- retrieval ----
    stageT<2>(MsT + (size_t)(seg * 16 + bh) * 4096, 64, KT[0], w, lane);
    __syncthreads();

    bf16x8 sq[2][2];
    float den[2] = {0.f, 0.f};
    #pragma unroll
    for (int st = 0; st < 2; st++) {
        #pragma unroll
        for (int s = 0; s < 2; s++) {
            bvec in, outv;
            in.v = aq[st][s];
            #pragma unroll
            for (int e = 0; e < 8; e++) {
                float f = elu1(__bfloat162float(in.e[e]));
                outv.e[e] = __float2bfloat16(f);
                den[st] += f * Zsm[s * 32 + 8 * g + e];
            }
            sq[st][s] = outv.v;
        }
        den[st] += __shfl_xor(den[st], 16);
        den[st] += __shfl_xor(den[st], 32);
    }

    bf16x8 bm[2][4];
    #pragma unroll
    for (int s = 0; s < 2; s++)
        #pragma unroll
        for (int j = 0; j < 4; j++)
            bm[s][j] = ldsw128(KT[0], j * 16 + la, s * 32 + g * 8);

    float gate[4];
    #pragma unroll
    for (int j = 0; j < 4; j++)
        gate[j] = 1.f / (1.f + __expf(-betas[h * 64 + j * 16 + la]));

    #pragma unroll
    for (int st = 0; st < 2; st++) {
        f32x4 num[4];
        #pragma unroll
        for (int j = 0; j < 4; j++) { f32x4 z4 = {0.f,0.f,0.f,0.f}; num[j] = z4; }
        #pragma unroll
        for (int j = 0; j < 4; j++) {
            num[j] = __builtin_amdgcn_mfma_f32_16x16x32_bf16(sq[st][0], bm[0][j], num[j], 0, 0, 0);
            num[j] = __builtin_amdgcn_mfma_f32_16x16x32_bf16(sq[st][1], bm[1][j], num[j], 0, 0, 0);
        }
        #pragma unroll
        for (int r = 0; r < 4; r++) {
            float den_r = __shfl(den[st], (lane & 48) | (g * 4 + r));
            float l_r   = __shfl(l_[st],  (lane & 48) | (g * 4 + r));
            float linv  = 1.f / l_r;
            float dinv  = 1.f / den_r;
            size_t orow = srow + (size_t)qt * 128 + w * 32 + st * 16 + g * 4 + r;
            #pragma unroll
            for (int j = 0; j < 4; j++) {
                float am = num[j][r] * dinv;
                float ad = Oa[st][j][r] * linv;
                att[orow * 512 + h * 64 + j * 16 + la] =
                    __float2bfloat16(gate[j] * am + (1.f - gate[j]) * ad);
            }
        }
    }
}

// ---------------------------------------------------------------------------
// LayerNorm (in-place safe)
// ---------------------------------------------------------------------------
__global__ __launch_bounds__(256) void ln_k(
    const float* __restrict__ Y, const float* __restrict__ g,
    const float* __restrict__ bta, float* __restrict__ out)
{
    const int row = blockIdx.x;
    const float* yp = Y + (size_t)row * D_;
    const int t = threadIdx.x;
    float v[4];
    float s = 0.f, s2 = 0.f;
    #pragma unroll
    for (int i = 0; i < 4; i++) {
        v[i] = yp[t + i * 256];
        s += v[i]; s2 += v[i] * v[i];
    }
    #pragma unroll
    for (int mk = 1; mk < 64; mk <<= 1) {
        s  += __shfl_xor(s, mk);
        s2 += __shfl_xor(s2, mk);
    }
    __shared__ float ss[4], ss2[4];
    int w = t >> 6;
    if ((t & 63) == 0) { ss[w] = s; ss2[w] = s2; }
    __syncthreads();
    s  = ss[0] + ss[1] + ss[2] + ss[3];
    s2 = ss2[0] + ss2[1] + ss2[2] + ss2[3];
    float mu   = s / D_;
    float var  = s2 / D_ - mu * mu;
    float rstd = rsqrtf(var + EPS_);
    #pragma unroll
    for (int i = 0; i < 4; i++) {
        int c = t + i * 256;
        out[(size_t)row * D_ + c] = (v[i] - mu) * rstd * g[c] + bta[c];
    }
}

// ---------------------------------------------------------------------------
extern "C" void kernel_launch(void* const* d_in, const int* in_sizes, int n_in,
                              void* d_out, int out_size, void* d_ws, size_t ws_size,
                              hipStream_t stream)
{
    const float* x     = (const float*)d_in[0];
    const float* Wq    = (const float*)d_in[1];
    const float* Wk    = (const float*)d_in[2];
    const float* Wv    = (const float*)d_in[3];
    const float* Wo    = (const float*)d_in[4];
    const float* betas = (const float*)d_in[5];
    const float* W1    = (const float*)d_in[6];
    const float* b1    = (const float*)d_in[7];
    const float* W2    = (const float*)d_in[8];
    const float* b2    = (const float*)d_in[9];
    const float* lng   = (const float*)d_in[10];
    const float* lnb   = (const float*)d_in[11];
    float* out = (float*)d_out;

    const int M = B_ * S_;                    // 16384
    char* base = (char*)d_ws;
    const size_t MB = 1024 * 1024;

    bf16*  Ab    = (bf16*)(base);
    bf16*  Hb    = (bf16*)(base + 32 * MB);
    bf16*  Xbf   = (bf16*)(base + 32 * MB);
    bf16*  QKV   = (bf16*)(base + 64 * MB);   // [M][1536]
    bf16*  Vt    = (bf16*)(base + 112 * MB);
    bf16*  ATT   = (bf16*)(base + 128 * MB);  // [M][512]
    bf16*  WqkvT = (bf16*)(base + 160 * MB);  // [1536][1024] = 3MB
    bf16*  WoT   = (bf16*)(base + 163 * MB);
    bf16*  W1T   = (bf16*)(base + 164 * MB);  // 8MB
    bf16*  W2T   = (bf16*)(base + 172 * MB);  // 8MB
    float* MP    = (float*)(base + 180 * MB);
    bf16*  MST   = (bf16*)(base + 184 * MB);
    float* ZP    = (float*)(base + 185 * MB);
    float* ZS    = (float*)(base + 185 * MB + 256 * 1024);

    dim3 blk(256);
    dim3 blk512(512);

    castx_k<<<dim3((M * D_) / 1024), blk, 0, stream>>>(x, Xbf);
    transcast_k<<<dim3(512 / 32, 1024 / 32), blk, 0, stream>>>(Wq, WqkvT, 1024, 512);
    transcast_k<<<dim3(512 / 32, 1024 / 32), blk, 0, stream>>>(Wk, WqkvT + 512 * 1024, 1024, 512);
    transcast_k<<<dim3(512 / 32, 1024 / 32), blk, 0, stream>>>(Wv, WqkvT + 1024 * 1024, 1024, 512);
    transcast_k<<<dim3(1024 / 32, 512 / 32), blk, 0, stream>>>(Wo, WoT, 512, 1024);
    transcast_k<<<dim3(4096 / 32, 1024 / 32), blk, 0, stream>>>(W1, W1T, 1024, 4096);
    transcast_k<<<dim3(1024 / 32, 4096 / 32), blk, 0, stream>>>(W2, W2T, 4096, 1024);

    // fused QKV projection: [M][1536]
    gemm256<0, bf16><<<dim3(1536 / 256, M / 256), blk512, 0, stream>>>(
        Xbf, WqkvT, QKV, nullptr, nullptr, M, 1536, 1024);

    vtrans_k<<<dim3(256, 8), blk, 0, stream>>>(QKV + 1024, Vt);

    memseg_k<<<dim3(NSEG_ * 16, 4), blk, 0, stream>>>(QKV + 512, QKV + 1024, MP, ZP);
    prefix_k<<<dim3(16), blk, 0, stream>>>(MP, ZP, MST, ZS);

    attn_k<<<dim3(SEG_ / 128, 16, NSEG_), blk, 0, stream>>>(
        QKV, QKV + 512, Vt, MST, ZS, betas, ATT);

    gemm256<0, bf16><<<dim3(1024 / 256, M / 256), blk512, 0, stream>>>(
        ATT, WoT, Ab, nullptr, nullptr, M, 1024, 512);
    gemm256<2, bf16><<<dim3(4096 / 256, M / 256), blk512, 0, stream>>>(
        Ab, W1T, Hb, b1, nullptr, M, 4096, 1024);
    gemm256<3, float><<<dim3(1024 / 256, M / 256), blk512, 0, stream>>>(
        Hb, W2T, out, b2, x, M, 1024, 4096);

    ln_k<<<dim3(M), blk, 0, stream>>>(out, lng, lnb, out);
}

// Round 8
// 699.745 us; speedup vs baseline: 12.3296x; 1.0020x over previous
//
#include <hip/hip_runtime.h>
#include <hip/hip_bf16.h>
#include <math.h>

#define B_    2
#define S_    8192
#define D_    1024
#define H_N   8
#define DK_   64
#define DV_   64
#define DH_   4096
#define SEG_  2048
#define NSEG_ 4
#define EPS_  1e-5f
#define LDQKV 1536

typedef __hip_bfloat16 bf16;
typedef unsigned int u32;
typedef __attribute__((ext_vector_type(8))) short bf16x8;
typedef __attribute__((ext_vector_type(4))) float f32x4;

union bvec { bf16x8 v; bf16 e[8]; };

template <typename T> __device__ inline T from_f(float v);
template <> __device__ inline float from_f<float>(float v) { return v; }
template <> __device__ inline bf16  from_f<bf16>(float v)  { return __float2bfloat16(v); }

__device__ __forceinline__ void gld_lds16(const bf16* g, bf16* l) {
    __builtin_amdgcn_global_load_lds(
        (const __attribute__((address_space(1))) u32*)g,
        (__attribute__((address_space(3))) u32*)l, 16, 0, 0);
}

__device__ inline float elu1(float x) { return x > 0.f ? x + 1.f : __expf(x); }

// ---------------------------------------------------------------------------
// 256x256-tile GEMM, 8 waves, BK=64, 2 LDS buffers, 8-phase / 2-K-tile
// counted-vmcnt schedule (T3+T4+T5) with hoisted swizzled LDS base pointers
// (every ds_read_b128 = base + compile-time immediate).
// Stage unit q of tile t+1 during tile t's phases; at tile boundaries issue
// the next unit FIRST then s_waitcnt vmcnt(2) (in-order retire guarantees the
// previous tile's 8 loads have landed).  vmcnt(0) only at the last tile.
// ---------------------------------------------------------------------------
#define GP(APTR, BPTR, MH, LOADB)                                              \
    {                                                                          \
        if (LOADB) {                                                           \
            _Pragma("unroll")                                                  \
            for (int n = 0; n < 4; n++)                                        \
                bg[n] = *(const bf16x8*)((BPTR) + n * 2048);                   \
        }                                                                      \
        _Pragma("unroll")                                                      \
        for (int m = 0; m < 4; m++)                                            \
            af[m] = *(const bf16x8*)((APTR) + (MH) * 8192 + m * 2048);         \
        asm volatile("s_waitcnt lgkmcnt(0)" ::: "memory");                     \
        __builtin_amdgcn_sched_barrier(0);                                     \
        __builtin_amdgcn_s_setprio(1);                                         \
        _Pragma("unroll")                                                      \
        for (int m = 0; m < 4; m++)                                            \
            _Pragma("unroll")                                                  \
            for (int n = 0; n < 4; n++)                                        \
                acc[(MH) * 4 + m][n] = __builtin_amdgcn_mfma_f32_16x16x32_bf16(\
                    af[m], bg[n], acc[(MH) * 4 + m][n], 0, 0, 0);              \
        __builtin_amdgcn_s_setprio(0);                                         \
    }

template <int EPI, typename CT>
__global__ __launch_bounds__(512, 1) void gemm256(
    const bf16* __restrict__ A, const bf16* __restrict__ BT, CT* __restrict__ C,
    const float* __restrict__ bias, const float* __restrict__ resid,
    int M, int N, int K)
{
    __shared__ bf16 L0[32768];   // tile buffer 0: A [256][64] | B [256][64]
    __shared__ bf16 L1[32768];   // tile buffer 1
    const int t    = threadIdx.x;
    const int lane = t & 63;
    const int w    = t >> 6;          // 8 waves
    const int la   = lane & 15;
    const int g    = lane >> 4;

    // bijective XCD swizzle (all grids have nwg % 8 == 0)
    const int nx  = gridDim.x;
    const int nwg = nx * gridDim.y;
    const int lin = blockIdx.y * nx + blockIdx.x;
    const int swzb = (lin & 7) * (nwg >> 3) + (lin >> 3);
    const int by  = swzb / nx, bx = swzb - by * nx;

    const int m0 = by * 256, n0 = bx * 256;
    const int wm = w >> 2, wn = w & 3;   // wave tile: rows [wm*128,+128), cols [wn*64,+64)

    f32x4 acc[8][4];
    #pragma unroll
    for (int m = 0; m < 8; m++)
        #pragma unroll
        for (int n = 0; n < 4; n++) {
            f32x4 z4 = {0.f, 0.f, 0.f, 0.f};
            acc[m][n] = z4;
        }

    const int nt = K >> 6;   // even for all shapes used (K in {512,1024,4096})

    // stage unit q (A rows q*64..+64 and B rows q*64..+64) of tile kt
    const int rq = w * 8 + (lane >> 3);
    const int c8 = ((lane & 7) ^ (lane >> 3)) * 8;    // pre-swizzled col chunk
    auto stageQ = [&](int kt_, int q, bf16* Lb) {
        const size_t k0 = (size_t)kt_ << 6;
        gld_lds16(A  + (size_t)(m0 + q * 64 + rq) * K + k0 + c8,
                  Lb + q * 4096 + w * 512);
        gld_lds16(BT + (size_t)(n0 + q * 64 + rq) * K + k0 + c8,
                  Lb + 16384 + q * 4096 + w * 512);
    };

    // hoisted swizzled LDS base pointers: read = base + compile-time immediate
    const int sw0 = (g ^ (la & 7)) << 4;
    const int sw1 = ((4 + g) ^ (la & 7)) << 4;
    const int aoff = (wm * 128 + la) * 128;
    const int boff = 32768 + (wn * 64 + la) * 128;
    const char* a0k0 = (const char*)L0 + aoff + sw0;
    const char* a0k1 = (const char*)L0 + aoff + sw1;
    const char* b0k0 = (const char*)L0 + boff + sw0;
    const char* b0k1 = (const char*)L0 + boff + sw1;
    const char* a1k0 = (const char*)L1 + aoff + sw0;
    const char* a1k1 = (const char*)L1 + aoff + sw1;
    const char* b1k0 = (const char*)L1 + boff + sw0;
    const char* b1k1 = (const char*)L1 + boff + sw1;

    // prologue: tile 0 fully staged into L0
    stageQ(0, 0, L0); stageQ(0, 1, L0); stageQ(0, 2, L0); stageQ(0, 3, L0);

    bf16x8 af[4], bg[4];
    for (int tt = 0; tt < nt; tt += 2) {
        const bool more = (tt + 2 < nt);
        // ======== tile tt (L0); stage tile tt+1 -> L1 ========
        // ph0 (boundary: L1's prior readers done; then guarantee tile tt resident)
        __builtin_amdgcn_s_barrier();
        stageQ(tt + 1, 0, L1);
        asm volatile("s_waitcnt vmcnt(2)" ::: "memory");
        __builtin_amdgcn_sched_barrier(0);
        __builtin_amdgcn_s_barrier();
        GP(a0k0, b0k0, 0, true);
        // ph1
        __builtin_amdgcn_s_barrier();
        stageQ(tt + 1, 1, L1);
        GP(a0k0, b0k0, 1, false);
        // ph2
        __builtin_amdgcn_s_barrier();
        stageQ(tt + 1, 2, L1);
        GP(a0k1, b0k1, 0, true);
        // ph3
        __builtin_amdgcn_s_barrier();
        stageQ(tt + 1, 3, L1);
        GP(a0k1, b0k1, 1, false);
        // ======== tile tt+1 (L1); stage tile tt+2 -> L0 ========
        // ph4 (boundary)
        __builtin_amdgcn_s_barrier();
        if (more) {
            stageQ(tt + 2, 0, L0);
            asm volatile("s_waitcnt vmcnt(2)" ::: "memory");
        } else {
            asm volatile("s_waitcnt vmcnt(0)" ::: "memory");
        }
        __builtin_amdgcn_sched_barrier(0);
        __builtin_amdgcn_s_barrier();
        GP(a1k0, b1k0, 0, true);
        // ph5
        __builtin_amdgcn_s_barrier();
        if (more) stageQ(tt + 2, 1, L0);
        GP(a1k0, b1k0, 1, false);
        // ph6
        __builtin_amdgcn_s_barrier();
        if (more) stageQ(tt + 2, 2, L0);
        GP(a1k1, b1k1, 0, true);
        // ph7
        __builtin_amdgcn_s_barrier();
        if (more) stageQ(tt + 2, 3, L0);
        GP(a1k1, b1k1, 1, false);
    }

    // C/D layout: col = lane&15, row = (lane>>4)*4 + reg
    // line-friendly store order: the 4 n-chunks of a 128B row line back-to-back
    const int row0 = m0 + wm * 128 + g * 4;
    const int col0 = n0 + wn * 64 + la;
    float bj[4];
    if (EPI >= 2) {
        #pragma unroll
        for (int n = 0; n < 4; n++) bj[n] = bias[col0 + n * 16];
    }
    #pragma unroll
    for (int m = 0; m < 8; m++) {
        #pragma unroll
        for (int r = 0; r < 4; r++) {
            const int row = row0 + m * 16 + r;
            #pragma unroll
            for (int n = 0; n < 4; n++) {
                const int col = col0 + n * 16;
                float v = acc[m][n][r];
                if (EPI >= 2) v += bj[n];
                if (EPI == 2) v = 0.5f * v * (1.0f + erff(v * 0.70710678118654752f));
                if (EPI == 3) v += resid[(size_t)row * N + col];
                C[(size_t)row * N + col] = from_f<CT>(v);
            }
        }
    }
}

// ---------------------------------------------------------------------------
// casts
// ---------------------------------------------------------------------------
__global__ __launch_bounds__(256) void castx_k(const float* __restrict__ X,
                                               bf16* __restrict__ Y)
{
    size_t i = ((size_t)blockIdx.x * 256 + threadIdx.x) * 4;
    float4 v = *(const float4*)(X + i);
    union { bf16 b[4]; unsigned long long u; } o;
    o.b[0] = __float2bfloat16(v.x);
    o.b[1] = __float2bfloat16(v.y);
    o.b[2] = __float2bfloat16(v.z);
    o.b[3] = __float2bfloat16(v.w);
    *(unsigned long long*)(Y + i) = o.u;
}

__global__ __launch_bounds__(256) void transcast_k(const float* __restrict__ W,
                                                   bf16* __restrict__ WT, int K, int N)
{
    __shared__ float tile[32][33];
    const int n0 = blockIdx.x * 32, k0 = blockIdx.y * 32;
    const int tx = threadIdx.x & 31, ty = threadIdx.x >> 5;
    #pragma unroll
    for (int i = 0; i < 32; i += 8)
        tile[ty + i][tx] = W[(size_t)(k0 + ty + i) * N + n0 + tx];
    __syncthreads();
    #pragma unroll
    for (int i = 0; i < 32; i += 8)
        WT[(size_t)(n0 + ty + i) * K + k0 + tx] = __float2bfloat16(tile[tx][ty + i]);
}

// V (stride LDQKV) -> Vt [ (b*8+h)*64+dv ][ s ]
__global__ __launch_bounds__(256) void vtrans_k(const bf16* __restrict__ V,
                                                bf16* __restrict__ Vt)
{
    __shared__ bf16 t_[64 * 64];
    const int t = threadIdx.x;
    const int sblk = blockIdx.x & 127;
    const int b = blockIdx.x >> 7;
    const int h = blockIdx.y;
    const bf16* src = V + ((size_t)b * S_ + sblk * 64) * LDQKV + h * 64;
    #pragma unroll
    for (int k = 0; k < 2; k++) {
        int e = t + k * 256;
        int r = e >> 3, c8 = (e & 7) * 8;
        *(bf16x8*)&t_[r * 64 + c8] = *(const bf16x8*)&src[(size_t)r * LDQKV + c8];
    }
    __syncthreads();
    const int dv = t & 63, s0 = (t >> 6) * 16;
    bf16* dst = Vt + ((size_t)(b * 8 + h) * 64 + dv) * (size_t)S_ + sblk * 64 + s0;
    bvec o0, o1;
    #pragma unroll
    for (int i = 0; i < 8; i++) {
        o0.e[i] = t_[(s0 + i) * 64 + dv];
        o1.e[i] = t_[(s0 + 8 + i) * 64 + dv];
    }
    *(bf16x8*)dst = o0.v;
    *(bf16x8*)(dst + 8) = o1.v;
}

// ---------------------------------------------------------------------------
// Per-(segment,chunk) partial memory (bf16 in @ stride LDQKV, f32 accumulate)
// ---------------------------------------------------------------------------
__global__ __launch_bounds__(256) void memseg_k(
    const bf16* __restrict__ Kg, const bf16* __restrict__ Vg,
    float* __restrict__ MP, float* __restrict__ ZP)
{
    __shared__ float Ks[64][65];
    __shared__ float Vs[64][65];
    const int t = threadIdx.x, tx = t & 15, ty = t >> 4;
    const int sb = blockIdx.x;
    const int seg = sb >> 4, bh = sb & 15;
    const int b = bh >> 3, h = bh & 7;
    const int chunk = blockIdx.y;
    const size_t base = ((size_t)b * S_ + (size_t)seg * SEG_ + (size_t)chunk * 512) * LDQKV + h * 64;

    float acc[4][4] = {};
    float zacc[4]   = {};
    for (int st = 0; st < 8; st++) {
        #pragma unroll
        for (int kk = 0; kk < 2; kk++) {
            int e = t + kk * 256;
            int r = e >> 3, c8 = (e & 7) * 8;
            size_t go = base + ((size_t)st * 64 + r) * LDQKV + c8;
            bvec kv_, vv_;
            kv_.v = *(const bf16x8*)&Kg[go];
            vv_.v = *(const bf16x8*)&Vg[go];
            #pragma unroll
            for (int i = 0; i < 8; i++) {
                Ks[r][c8 + i] = elu1(__bfloat162float(kv_.e[i]));
                Vs[r][c8 + i] = __bfloat162float(vv_.e[i]);
            }
        }
        __syncthreads();
        for (int s = 0; s < 64; s++) {
            float a4[4], v4[4];
            #pragma unroll
            for (int i = 0; i < 4; i++) a4[i] = Ks[s][ty * 4 + i];
            #pragma unroll
            for (int j = 0; j < 4; j++) v4[j] = Vs[s][tx * 4 + j];
            #pragma unroll
            for (int i = 0; i < 4; i++)
                #pragma unroll
                for (int j = 0; j < 4; j++)
                    acc[i][j] += a4[i] * v4[j];
        }
        #pragma unroll
        for (int ii = 0; ii < 4; ii++) {
            int s = tx + ii * 16;
            #pragma unroll
            for (int i = 0; i < 4; i++) zacc[i] += Ks[s][ty * 4 + i];
        }
        __syncthreads();
    }
    const int slot = (seg * 4 + chunk) * 16 + bh;
    #pragma unroll
    for (int i = 0; i < 4; i++)
        #pragma unroll
        for (int j = 0; j < 4; j++)
            MP[(size_t)slot * 4096 + (ty * 4 + i) * 64 + tx * 4 + j] = acc[i][j];
    #pragma unroll
    for (int i = 0; i < 4; i++) {
        float zz = zacc[i];
        #pragma unroll
        for (int mk = 1; mk < 16; mk <<= 1) zz += __shfl_xor(zz, mk);
        if (tx == 0) ZP[slot * 64 + ty * 4 + i] = zz;
    }
}

// exclusive prefix -> per-seg start states: MST transposed bf16 [dv][dk], ZS f32
__global__ __launch_bounds__(256) void prefix_k(
    const float* __restrict__ MP, const float* __restrict__ ZP,
    bf16* __restrict__ MST, float* __restrict__ ZS)
{
    const int bh = blockIdx.x, t = threadIdx.x;
    for (int e = t; e < 4096; e += 256) {
        int dk = e >> 6, dv = e & 63;
        float s = 0.f;
        #pragma unroll
        for (int slot = 0; slot < 16; slot++) {
            if ((slot & 3) == 0)
                MST[(size_t)((slot >> 2) * 16 + bh) * 4096 + dv * 64 + dk] = __float2bfloat16(s);
            s += MP[(size_t)(slot * 16 + bh) * 4096 + e];
        }
    }
    if (t < 64) {
        float s = 1.0f / DK_;
        #pragma unroll
        for (int slot = 0; slot < 16; slot++) {
            if ((slot & 3) == 0) ZS[((slot >> 2) * 16 + bh) * 64 + t] = s;
            s += ZP[(slot * 16 + bh) * 64 + t];
        }
    }
}

// ---------------------------------------------------------------------------
// attn helpers: swizzled staging / reads (row stride 128B, XOR (row&7)<<4)
// ---------------------------------------------------------------------------
template <int NG>
__device__ __forceinline__ void stageT(const bf16* gsrc, size_t stride, bf16* lds,
                                       int wave, int lane)
{
    #pragma unroll
    for (int ii = 0; ii < NG; ii++) {
        int i = wave * NG + ii;
        gld_lds16(gsrc + (size_t)(8 * i + (lane >> 3)) * stride
                        + (size_t)(((lane & 7) ^ (lane >> 3)) * 8),
                  lds + i * 512);
    }
}

__device__ __forceinline__ bf16x8 ldsw128(const bf16* base, int row, int colE)
{
    int off = row * 128 + ((colE * 2) ^ ((row & 7) << 4));
    return *(const bf16x8*)((const char*)base + off);
}

// ---------------------------------------------------------------------------
// MFMA flash attention (swapped QK^T, swizzled LDS, double-buffered K/V,
// 1 barrier per kv-tile) + compressive-memory retrieval.
// grid (16 qt [reversed], 16 bh, 4 seg); block 256 = 4 waves x 32 q rows.
// ---------------------------------------------------------------------------
__global__ __launch_bounds__(256) void attn_k(
    const bf16* __restrict__ Qg, const bf16* __restrict__ Kg, const bf16* __restrict__ Vt,
    const bf16* __restrict__ MsT, const float* __restrict__ ZS,
    const float* __restrict__ betas, bf16* __restrict__ att)
{
    __shared__ bf16 KT[2][4096];
    __shared__ bf16 VTs[2][4096];
    __shared__ bf16 QP[8192];       // Q tile 128x64; per-wave rows reused as P
    __shared__ float Zsm[64];

    const int t    = threadIdx.x;
    const int lane = t & 63;
    const int w    = t >> 6;
    const int la   = lane & 15;
    const int g    = lane >> 4;
    const int qt   = (int)gridDim.x - 1 - (int)blockIdx.x;
    const int bh   = blockIdx.y;
    const int seg  = blockIdx.z;
    const int b    = bh >> 3, h = bh & 7;

    const size_t srow = (size_t)b * S_ + (size_t)seg * SEG_;
    const bf16* qp  = Qg + (srow + (size_t)qt * 128) * LDQKV + h * 64;
    const bf16* kp  = Kg + srow * LDQKV + h * 64;
    const bf16* vtp = Vt + (size_t)bh * 64 * (size_t)S_ + (size_t)seg * SEG_;

    stageT<4>(qp, LDQKV, QP, w, lane);
    stageT<2>(kp, LDQKV, KT[0], w, lane);
    stageT<2>(vtp, S_, VTs[0], w, lane);
    if (t < 64) Zsm[t] = ZS[(seg * 16 + bh) * 64 + t];
    __syncthreads();

    bf16x8 aq[2][2];
    #pragma unroll
    for (int st = 0; st < 2; st++)
        #pragma unroll
        for (int s = 0; s < 2; s++)
            aq[st][s] = ldsw128(QP, w * 32 + st * 16 + la, s * 32 + g * 8);

    float m_[2] = {-1e30f, -1e30f};
    float l_[2] = {0.f, 0.f};
    f32x4 Oa[2][4];
    #pragma unroll
    for (int st = 0; st < 2; st++)
        #pragma unroll
        for (int j = 0; j < 4; j++) { f32x4 z4 = {0.f,0.f,0.f,0.f}; Oa[st][j] = z4; }

    const int jtmax = 2 * qt + 1;
    int cur = 0;
    for (int jt = 0; jt <= jtmax; jt++, cur ^= 1) {
        if (jt < jtmax) {
            stageT<2>(kp + (size_t)(jt + 1) * 64 * LDQKV, LDQKV, KT[cur ^ 1], w, lane);
            stageT<2>(vtp + (size_t)(jt + 1) * 64, S_, VTs[cur ^ 1], w, lane);
        }

        bf16x8 kf[2][4];
        #pragma unroll
        for (int s = 0; s < 2; s++)
            #pragma unroll
            for (int j = 0; j < 4; j++)
                kf[s][j] = ldsw128(KT[cur], j * 16 + la, s * 32 + g * 8);

        const int jtkv = jt * 64;
        #pragma unroll
        for (int st = 0; st < 2; st++) {
            f32x4 sc[4];
            #pragma unroll
            for (int j = 0; j < 4; j++) { f32x4 z4 = {0.f,0.f,0.f,0.f}; sc[j] = z4; }
            #pragma unroll
            for (int j = 0; j < 4; j++) {
                sc[j] = __builtin_amdgcn_mfma_f32_16x16x32_bf16(kf[0][j], aq[st][0], sc[j], 0, 0, 0);
                sc[j] = __builtin_amdgcn_mfma_f32_16x16x32_bf16(kf[1][j], aq[st][1], sc[j], 0, 0, 0);
            }

            const int q_abs = qt * 128 + w * 32 + st * 16 + la;
            float sv[4][4];
            float mx = -1e30f;
            #pragma unroll
            for (int j = 0; j < 4; j++)
                #pragma unroll
                for (int r = 0; r < 4; r++) {
                    float v = sc[j][r] * 0.125f;
                    int kv = jtkv + j * 16 + g * 4 + r;
                    v = (kv <= q_abs) ? v : -1e30f;
                    sv[j][r] = v;
                    mx = fmaxf(mx, v);
                }
            mx = fmaxf(mx, __shfl_xor(mx, 16));
            mx = fmaxf(mx, __shfl_xor(mx, 32));
            float mnew = fmaxf(m_[st], mx);
            float corr = __expf(m_[st] - mnew);
            float rs = 0.f;
            #pragma unroll
            for (int j = 0; j < 4; j++)
                #pragma unroll
                for (int r = 0; r < 4; r++) {
                    float p = __expf(sv[j][r] - mnew);
                    sv[j][r] = p;
                    rs += p;
                }
            rs += __shfl_xor(rs, 16);
            rs += __shfl_xor(rs, 32);
            l_[st] = l_[st] * corr + rs;
            m_[st] = mnew;

            const int R = w * 32 + st * 16 + la;
            #pragma unroll
            for (int j = 0; j < 4; j++) {
                union { bf16 e[4]; uint2 u; } pk;
                #pragma unroll
                for (int r = 0; r < 4; r++) pk.e[r] = __float2bfloat16(sv[j][r]);
                int off = R * 128 + ((j * 32 + g * 8) ^ ((la & 7) << 4));
                *(uint2*)((char*)QP + off) = pk.u;
            }

            #pragma unroll
            for (int r = 0; r < 4; r++) {
                float corr_r = __shfl(corr, (lane & 48) | (g * 4 + r));
                #pragma unroll
                for (int j = 0; j < 4; j++) Oa[st][j][r] *= corr_r;
            }
        }

        asm volatile("s_waitcnt lgkmcnt(0)" ::: "memory");
        __builtin_amdgcn_sched_barrier(0);

        bf16x8 bv[2][4];
        #pragma unroll
        for (int s = 0; s < 2; s++)
            #pragma unroll
            for (int j = 0; j < 4; j++)
                bv[s][j] = ldsw128(VTs[cur], j * 16 + la, s * 32 + g * 8);
        #pragma unroll
        for (int st = 0; st < 2; st++) {
            bf16x8 ap0 = ldsw128(QP, w * 32 + st * 16 + la, g * 8);
            bf16x8 ap1 = ldsw128(QP, w * 32 + st * 16 + la, 32 + g * 8);
            #pragma unroll
            for (int j = 0; j < 4; j++) {
                Oa[st][j] = __builtin_amdgcn_mfma_f32_16x16x32_bf16(ap0, bv[0][j], Oa[st][j], 0, 0, 0);
                Oa[st][j] = __builtin_amdgcn_mfma_f32_16x16x32_bf16(ap1, bv[1][j], Oa[st][j], 0, 0, 0);
            }
        }
        __syncthreads();
    }

    // ---- retrieval ----
    stageT<2>(MsT + (size_t)(seg * 16 + bh) * 4096, 64, KT[0], w, lane);
    __syncthreads();

    bf16x8 sq[2][2];
    float den[2] = {0.f, 0.f};
    #pragma unroll
    for (int st = 0; st < 2; st++) {
        #pragma unroll
        for (int s = 0; s < 2; s++) {
            bvec in, outv;
            in.v = aq[st][s];
            #pragma unroll
            for (int e = 0; e < 8; e++) {
                float f = elu1(__bfloat162float(in.e[e]));
                outv.e[e] = __float2bfloat16(f);
                den[st] += f * Zsm[s * 32 + 8 * g + e];
            }
            sq[st][s] = outv.v;
        }
        den[st] += __shfl_xor(den[st], 16);
        den[st] += __shfl_xor(den[st], 32);
    }

    bf16x8 bm[2][4];
    #pragma unroll
    for (int s = 0; s < 2; s++)
        #pragma unroll
        for (int j = 0; j < 4; j++)
            bm[s][j] = ldsw128(KT[0], j * 16 + la, s * 32 + g * 8);

    float gate[4];
    #pragma unroll
    for (int j = 0; j < 4; j++)
        gate[j] = 1.f / (1.f + __expf(-betas[h * 64 + j * 16 + la]));

    #pragma unroll
    for (int st = 0; st < 2; st++) {
        f32x4 num[4];
        #pragma unroll
        for (int j = 0; j < 4; j++) { f32x4 z4 = {0.f,0.f,0.f,0.f}; num[j] = z4; }
        #pragma unroll
        for (int j = 0; j < 4; j++) {
            num[j] = __builtin_amdgcn_mfma_f32_16x16x32_bf16(sq[st][0], bm[0][j], num[j], 0, 0, 0);
            num[j] = __builtin_amdgcn_mfma_f32_16x16x32_bf16(sq[st][1], bm[1][j], num[j], 0, 0, 0);
        }
        #pragma unroll
        for (int r = 0; r < 4; r++) {
            float den_r = __shfl(den[st], (lane & 48) | (g * 4 + r));
            float l_r   = __shfl(l_[st],  (lane & 48) | (g * 4 + r));
            float linv  = 1.f / l_r;
            float dinv  = 1.f / den_r;
            size_t orow = srow + (size_t)qt * 128 + w * 32 + st * 16 + g * 4 + r;
            #pragma unroll
            for (int j = 0; j < 4; j++) {
                float am = num[j][r] * dinv;
                float ad = Oa[st][j][r] * linv;
                att[orow * 512 + h * 64 + j * 16 + la] =
                    __float2bfloat16(gate[j] * am + (1.f - gate[j]) * ad);
            }
        }
    }
}

// ---------------------------------------------------------------------------
// LayerNorm (in-place safe)
// ---------------------------------------------------------------------------
__global__ __launch_bounds__(256) void ln_k(
    const float* __restrict__ Y, const float* __restrict__ g,
    const float* __restrict__ bta, float* __restrict__ out)
{
    const int row = blockIdx.x;
    const float* yp = Y + (size_t)row * D_;
    const int t = threadIdx.x;
    float v[4];
    float s = 0.f, s2 = 0.f;
    #pragma unroll
    for (int i = 0; i < 4; i++) {
        v[i] = yp[t + i * 256];
        s += v[i]; s2 += v[i] * v[i];
    }
    #pragma unroll
    for (int mk = 1; mk < 64; mk <<= 1) {
        s  += __shfl_xor(s, mk);
        s2 += __shfl_xor(s2, mk);
    }
    __shared__ float ss[4], ss2[4];
    int w = t >> 6;
    if ((t & 63) == 0) { ss[w] = s; ss2[w] = s2; }
    __syncthreads();
    s  = ss[0] + ss[1] + ss[2] + ss[3];
    s2 = ss2[0] + ss2[1] + ss2[2] + ss2[3];
    float mu   = s / D_;
    float var  = s2 / D_ - mu * mu;
    float rstd = rsqrtf(var + EPS_);
    #pragma unroll
    for (int i = 0; i < 4; i++) {
        int c = t + i * 256;
        out[(size_t)row * D_ + c] = (v[i] - mu) * rstd * g[c] + bta[c];
    }
}

// ---------------------------------------------------------------------------
extern "C" void kernel_launch(void* const* d_in, const int* in_sizes, int n_in,
                              void* d_out, int out_size, void* d_ws, size_t ws_size,
                              hipStream_t stream)
{
    const float* x     = (const float*)d_in[0];
    const float* Wq    = (const float*)d_in[1];
    const float* Wk    = (const float*)d_in[2];
    const float* Wv    = (const float*)d_in[3];
    const float* Wo    = (const float*)d_in[4];
    const float* betas = (const float*)d_in[5];
    const float* W1    = (const float*)d_in[6];
    const float* b1    = (const float*)d_in[7];
    const float* W2    = (const float*)d_in[8];
    const float* b2    = (const float*)d_in[9];
    const float* lng   = (const float*)d_in[10];
    const float* lnb   = (const float*)d_in[11];
    float* out = (float*)d_out;

    const int M = B_ * S_;                    // 16384
    char* base = (char*)d_ws;
    const size_t MB = 1024 * 1024;

    bf16*  Ab    = (bf16*)(base);
    bf16*  Hb    = (bf16*)(base + 32 * MB);
    bf16*  Xbf   = (bf16*)(base + 32 * MB);
    bf16*  QKV   = (bf16*)(base + 64 * MB);   // [M][1536]
    bf16*  Vt    = (bf16*)(base + 112 * MB);
    bf16*  ATT   = (bf16*)(base + 128 * MB);  // [M][512]
    bf16*  WqkvT = (bf16*)(base + 160 * MB);  // [1536][1024] = 3MB
    bf16*  WoT   = (bf16*)(base + 163 * MB);
    bf16*  W1T   = (bf16*)(base + 164 * MB);  // 8MB
    bf16*  W2T   = (bf16*)(base + 172 * MB);  // 8MB
    float* MP    = (float*)(base + 180 * MB);
    bf16*  MST   = (bf16*)(base + 184 * MB);
    float* ZP    = (float*)(base + 185 * MB);
    float* ZS    = (float*)(base + 185 * MB + 256 * 1024);

    dim3 blk(256);
    dim3 blk512(512);

    castx_k<<<dim3((M * D_) / 1024), blk, 0, stream>>>(x, Xbf);
    transcast_k<<<dim3(512 / 32, 1024 / 32), blk, 0, stream>>>(Wq, WqkvT, 1024, 512);
    transcast_k<<<dim3(512 / 32, 1024 / 32), blk, 0, stream>>>(Wk, WqkvT + 512 * 1024, 1024, 512);
    transcast_k<<<dim3(512 / 32, 1024 / 32), blk, 0, stream>>>(Wv, WqkvT + 1024 * 1024, 1024, 512);
    transcast_k<<<dim3(1024 / 32, 512 / 32), blk, 0, stream>>>(Wo, WoT, 512, 1024);
    transcast_k<<<dim3(4096 / 32, 1024 / 32), blk, 0, stream>>>(W1, W1T, 1024, 4096);
    transcast_k<<<dim3(1024 / 32, 4096 / 32), blk, 0, stream>>>(W2, W2T, 4096, 1024);

    // fused QKV projection: [M][1536]
    gemm256<0, bf16><<<dim3(1536 / 256, M / 256), blk512, 0, stream>>>(
        Xbf, WqkvT, QKV, nullptr, nullptr, M, 1536, 1024);

    vtrans_k<<<dim3(256, 8), blk, 0, stream>>>(QKV + 1024, Vt);

    memseg_k<<<dim3(NSEG_ * 16, 4), blk, 0, stream>>>(QKV + 512, QKV + 1024, MP, ZP);
    prefix_k<<<dim3(16), blk, 0, stream>>>(MP, ZP, MST, ZS);

    attn_k<<<dim3(SEG_ / 128, 16, NSEG_), blk, 0, stream>>>(
        QKV, QKV + 512, Vt, MST, ZS, betas, ATT);

    gemm256<0, bf16><<<dim3(1024 / 256, M / 256), blk512, 0, stream>>>(
        ATT, WoT, Ab, nullptr, nullptr, M, 1024, 512);
    gemm256<2, bf16><<<dim3(4096 / 256, M / 256), blk512, 0, stream>>>(
        Ab, W1T, Hb, b1, nullptr, M, 4096, 1024);
    gemm256<3, float><<<dim3(1024 / 256, M / 256), blk512, 0, stream>>>(
        Hb, W2T, out, b2, x, M, 1024, 4096);

    ln_k<<<dim3(M), blk, 0, stream>>>(out, lng, lnb, out);
}